// Round 1
// baseline (2797.069 us; speedup 1.0000x reference)
//
#include <hip/hip_runtime.h>
#include <float.h>
#include <math.h>

// ---------------- problem constants ----------------
#define B_   2
#define N_   2048
#define D_   512
#define H_   8
#define DH_  64
#define NM_  2047            // n-1
#define SCALE_F 0.125f       // 64^-0.5
#define LP 66                // LDS row pad (f32)

// thread micro-tile mapping: ty=tid/16, tx=tid%16
// rows owned: ty*4+r (r=0..3); cols owned: tx+16*c (c=0..3)

__device__ __forceinline__ float wred64(float v){
  #pragma unroll
  for(int off=32; off; off>>=1) v += __shfl_down(v, off, 64);
  return v;
}

// ---------------- 1. RMSNorm ----------------
__global__ __launch_bounds__(256) void k_rmsnorm(const float* __restrict__ tok,
    const float* __restrict__ w, float* __restrict__ t){
  int row = blockIdx.x;                       // 0..4095  (b*2048+n)
  const float* x = tok + (size_t)row*D_;
  float* o = t + (size_t)row*D_;
  int tid = threadIdx.x;
  float v0 = x[tid], v1 = x[tid+256];
  float s = v0*v0 + v1*v1;
  s = wred64(s);
  __shared__ float red[4];
  if((tid&63)==0) red[tid>>6] = s;
  __syncthreads();
  float tot = red[0]+red[1]+red[2]+red[3];
  float sc = rsqrtf(tot*(1.f/512.f) + 1.1920929e-7f);
  o[tid]     = v0*sc*w[tid];
  o[tid+256] = v1*sc*w[tid+256];
}

// ---------------- 2. QKV projection ----------------
__global__ __launch_bounds__(256) void k_qkv(const float* __restrict__ t,
    const float* __restrict__ wq, const float* __restrict__ wk, const float* __restrict__ wv,
    float* __restrict__ q, float* __restrict__ k, float* __restrict__ v){
  int h = blockIdx.y;
  int b = blockIdx.x >> 5;
  int i0 = (blockIdx.x & 31) << 6;
  const float* trow = t + ((size_t)(b*N_ + i0))*D_;
  __shared__ float ts[64][LP], ws0[64][LP], ws1[64][LP], ws2[64][LP];
  int tid = threadIdx.x, ty = tid>>4, tx = tid&15;
  float aq[4][4]={{0}}, ak[4][4]={{0}}, av[4][4]={{0}};
  for(int d0=0; d0<D_; d0+=64){
    __syncthreads();
    for(int kk=0;kk<16;kk++){
      int idx=kk*256+tid; int rr=idx>>6, cc=idx&63;
      ts[rr][cc]  = trow[(size_t)rr*D_ + d0+cc];
      ws0[rr][cc] = wq[((size_t)h*D_ + d0+rr)*DH_ + cc];
      ws1[rr][cc] = wk[((size_t)h*D_ + d0+rr)*DH_ + cc];
      ws2[rr][cc] = wv[((size_t)h*D_ + d0+rr)*DH_ + cc];
    }
    __syncthreads();
    for(int kk=0;kk<64;kk++){
      float a[4], b0[4], b1[4], b2[4];
      #pragma unroll
      for(int r=0;r<4;r++) a[r]=ts[ty*4+r][kk];
      #pragma unroll
      for(int c=0;c<4;c++){ b0[c]=ws0[kk][tx+16*c]; b1[c]=ws1[kk][tx+16*c]; b2[c]=ws2[kk][tx+16*c]; }
      #pragma unroll
      for(int r=0;r<4;r++)
        #pragma unroll
        for(int c=0;c<4;c++){
          aq[r][c] += a[r]*b0[c];
          ak[r][c] += a[r]*b1[c];
          av[r][c] += a[r]*b2[c];
        }
    }
  }
  size_t base = ((size_t)(b*H_+h)*N_ + i0)*DH_;
  #pragma unroll
  for(int r=0;r<4;r++)
    #pragma unroll
    for(int c=0;c<4;c++){
      size_t idx = base + (size_t)(ty*4+r)*DH_ + tx+16*c;
      q[idx]=aq[r][c]; k[idx]=ak[r][c]; v[idx]=av[r][c];
    }
}

// ---------------- 3. flash attention forward ----------------
__global__ __launch_bounds__(256) void k_attn_fwd(const float* __restrict__ q,
    const float* __restrict__ kg, const float* __restrict__ vg,
    float* __restrict__ outb, float* __restrict__ lse){
  int bh = blockIdx.y; int b = bh>>3, h = bh&7;
  int it = blockIdx.x, i0 = it<<6;
  const float* qb = q  + (size_t)bh*N_*DH_;
  const float* kb = kg + (size_t)bh*N_*DH_;
  const float* vb = vg + (size_t)bh*N_*DH_;
  __shared__ float qs[64][LP], ks[64][LP], vs[64][LP], ps[64][LP];
  int tid=threadIdx.x, ty=tid>>4, tx=tid&15;
  for(int kk=0;kk<16;kk++){
    int idx=kk*256+tid; int rr=idx>>6, cc=idx&63;
    qs[rr][cc]=qb[(size_t)(i0+rr)*DH_+cc];
  }
  float m[4], l[4], acc[4][4]={{0}};
  #pragma unroll
  for(int r=0;r<4;r++){ m[r]=-FLT_MAX; l[r]=0.f; }
  for(int jt=0; jt<=it; ++jt){
    int j0 = jt<<6;
    __syncthreads();
    for(int kk=0;kk<16;kk++){
      int idx=kk*256+tid; int rr=idx>>6, cc=idx&63;
      ks[rr][cc]=kb[(size_t)(j0+rr)*DH_+cc];
      vs[rr][cc]=vb[(size_t)(j0+rr)*DH_+cc];
    }
    __syncthreads();
    float s[4][4]={{0}};
    for(int e=0;e<64;e++){
      float a[4], bb[4];
      #pragma unroll
      for(int r=0;r<4;r++) a[r]=qs[ty*4+r][e];
      #pragma unroll
      for(int c=0;c<4;c++) bb[c]=ks[tx+16*c][e];
      #pragma unroll
      for(int r=0;r<4;r++)
        #pragma unroll
        for(int c=0;c<4;c++) s[r][c]+=a[r]*bb[c];
    }
    #pragma unroll
    for(int r=0;r<4;r++)
      #pragma unroll
      for(int c=0;c<4;c++) s[r][c]*=SCALE_F;
    if(jt==it){
      #pragma unroll
      for(int r=0;r<4;r++)
        #pragma unroll
        for(int c=0;c<4;c++){
          int ii=i0+ty*4+r, jj=j0+tx+16*c;
          if(jj>ii) s[r][c]=-FLT_MAX;
        }
    }
    #pragma unroll
    for(int r=0;r<4;r++){
      float rm = fmaxf(fmaxf(s[r][0],s[r][1]),fmaxf(s[r][2],s[r][3]));
      rm = fmaxf(rm, __shfl_xor(rm,1,16));
      rm = fmaxf(rm, __shfl_xor(rm,2,16));
      rm = fmaxf(rm, __shfl_xor(rm,4,16));
      rm = fmaxf(rm, __shfl_xor(rm,8,16));
      float mn = fmaxf(m[r], rm);
      float p[4], rs=0.f;
      #pragma unroll
      for(int c=0;c<4;c++){ p[c]=__expf(s[r][c]-mn); rs+=p[c]; }
      rs += __shfl_xor(rs,1,16); rs += __shfl_xor(rs,2,16);
      rs += __shfl_xor(rs,4,16); rs += __shfl_xor(rs,8,16);
      float corr = __expf(m[r]-mn);
      l[r] = l[r]*corr + rs; m[r]=mn;
      #pragma unroll
      for(int c=0;c<4;c++){ acc[r][c]*=corr; ps[ty*4+r][tx+16*c]=p[c]; }
    }
    __syncthreads();
    for(int j=0;j<64;j++){
      float a[4], bb[4];
      #pragma unroll
      for(int r=0;r<4;r++) a[r]=ps[ty*4+r][j];
      #pragma unroll
      for(int c=0;c<4;c++) bb[c]=vs[j][tx+16*c];
      #pragma unroll
      for(int r=0;r<4;r++)
        #pragma unroll
        for(int c=0;c<4;c++) acc[r][c]+=a[r]*bb[c];
    }
  }
  #pragma unroll
  for(int r=0;r<4;r++){
    float inv = 1.f/l[r];
    #pragma unroll
    for(int c=0;c<4;c++)
      outb[((size_t)(b*N_+i0+ty*4+r))*D_ + h*DH_ + tx+16*c] = acc[r][c]*inv;
    if(tx==0) lse[(size_t)bh*N_ + i0+ty*4+r] = m[r] + logf(l[r]);
  }
}

// ---------------- 4. pred = outb @ wo_flat ----------------
__global__ __launch_bounds__(256) void k_pred(const float* __restrict__ A,
    const float* __restrict__ Bm, float* __restrict__ C){
  int r0 = blockIdx.x<<6, c0 = blockIdx.y<<6;
  __shared__ float as[64][LP], bs[64][LP];
  int tid=threadIdx.x, ty=tid>>4, tx=tid&15;
  float acc[4][4]={{0}};
  for(int k0=0;k0<D_;k0+=64){
    __syncthreads();
    for(int kk=0;kk<16;kk++){
      int idx=kk*256+tid; int rr=idx>>6, cc=idx&63;
      as[rr][cc]=A[(size_t)(r0+rr)*D_ + k0+cc];
      bs[rr][cc]=Bm[(size_t)(k0+rr)*D_ + c0+cc];
    }
    __syncthreads();
    for(int kk=0;kk<64;kk++){
      float a[4], bb[4];
      #pragma unroll
      for(int r=0;r<4;r++) a[r]=as[ty*4+r][kk];
      #pragma unroll
      for(int c=0;c<4;c++) bb[c]=bs[kk][tx+16*c];
      #pragma unroll
      for(int r=0;r<4;r++)
        #pragma unroll
        for(int c=0;c<4;c++) acc[r][c]+=a[r]*bb[c];
    }
  }
  #pragma unroll
  for(int r=0;r<4;r++)
    #pragma unroll
    for(int c=0;c<4;c++)
      C[(size_t)(r0+ty*4+r)*D_ + c0+tx+16*c]=acc[r][c];
}

// ---------------- 5. tv = t[:,1:] @ tv_w^T  (dense rows k=0..4093) ----------------
__global__ __launch_bounds__(256) void k_tv(const float* __restrict__ t,
    const float* __restrict__ tvw, float* __restrict__ er){
  int r0 = blockIdx.x<<6, c0 = blockIdx.y<<6;
  __shared__ float as[64][LP], bs[64][LP];
  int tid=threadIdx.x, ty=tid>>4, tx=tid&15;
  float acc[4][4]={{0}};
  for(int k0=0;k0<D_;k0+=64){
    __syncthreads();
    for(int kk=0;kk<16;kk++){
      int idx=kk*256+tid; int rr=idx>>6, cc=idx&63;
      int kr=r0+rr; float av=0.f;
      if(kr < B_*NM_){
        int b=kr/NM_, n=kr-b*NM_;
        av = t[((size_t)(b*N_+n+1))*D_ + k0+cc];
      }
      as[rr][cc]=av;
      bs[rr][cc]=tvw[(size_t)(c0+rr)*D_ + k0+cc];
    }
    __syncthreads();
    for(int kk=0;kk<64;kk++){
      float a[4], bb[4];
      #pragma unroll
      for(int r=0;r<4;r++) a[r]=as[ty*4+r][kk];
      #pragma unroll
      for(int c=0;c<4;c++) bb[c]=bs[tx+16*c][kk];
      #pragma unroll
      for(int r=0;r<4;r++)
        #pragma unroll
        for(int c=0;c<4;c++) acc[r][c]+=a[r]*bb[c];
    }
  }
  #pragma unroll
  for(int r=0;r<4;r++){
    int kr=r0+ty*4+r;
    if(kr < B_*NM_)
      #pragma unroll
      for(int c=0;c<4;c++)
        er[(size_t)kr*D_ + c0+tx+16*c]=acc[r][c];
  }
}

// ---------------- 6. layernorm target + lr + error (in place on er) ----------------
__global__ __launch_bounds__(256) void k_lnerr(float* __restrict__ er,
    const float* __restrict__ t, const float* __restrict__ pred,
    const float* __restrict__ lrw){
  int kr = blockIdx.x;
  int b = kr/NM_, n = kr-b*NM_;
  float* tv = er + (size_t)kr*D_;
  const float* tok = t    + ((size_t)(b*N_+n))*D_;
  const float* pr  = pred + ((size_t)(b*N_+n))*D_;
  int tid=threadIdx.x;
  float v0=tv[tid], v1=tv[tid+256];
  float s1=v0+v1, s2=v0*v0+v1*v1;
  float s3=tok[tid]*lrw[tid] + tok[tid+256]*lrw[tid+256];
  s1=wred64(s1); s2=wred64(s2); s3=wred64(s3);
  __shared__ float r1[4],r2[4],r3[4];
  if((tid&63)==0){ int w=tid>>6; r1[w]=s1; r2[w]=s2; r3[w]=s3; }
  __syncthreads();
  float S1=r1[0]+r1[1]+r1[2]+r1[3];
  float S2=r2[0]+r2[1]+r2[2]+r2[3];
  float S3=r3[0]+r3[1]+r3[2]+r3[3];
  float mu  = S1*(1.f/512.f);
  float var = S2*(1.f/512.f) - mu*mu;
  float rstd= rsqrtf(var + 1e-5f);
  float lr  = 0.01f/(1.f+__expf(-S3));
  tv[tid]     = ((v0-mu)*rstd - pr[tid])*lr;
  tv[tid+256] = ((v1-mu)*rstd - pr[tid+256])*lr;
}

// ---------------- 7. dout = err @ wo^T ----------------
__global__ __launch_bounds__(256) void k_dout(const float* __restrict__ er,
    const float* __restrict__ wo, float* __restrict__ doutb){
  int r0 = blockIdx.x<<6, c0 = blockIdx.y<<6;
  __shared__ float as[64][LP], bs[64][LP];
  int tid=threadIdx.x, ty=tid>>4, tx=tid&15;
  float acc[4][4]={{0}};
  for(int k0=0;k0<D_;k0+=64){
    __syncthreads();
    for(int kk=0;kk<16;kk++){
      int idx=kk*256+tid; int rr=idx>>6, cc=idx&63;
      int kr=r0+rr;
      as[rr][cc] = (kr < B_*NM_) ? er[(size_t)kr*D_ + k0+cc] : 0.f;
      bs[rr][cc] = wo[(size_t)(c0+rr)*D_ + k0+cc];
    }
    __syncthreads();
    for(int kk=0;kk<64;kk++){
      float a[4], bb[4];
      #pragma unroll
      for(int r=0;r<4;r++) a[r]=as[ty*4+r][kk];
      #pragma unroll
      for(int c=0;c<4;c++) bb[c]=bs[tx+16*c][kk];
      #pragma unroll
      for(int r=0;r<4;r++)
        #pragma unroll
        for(int c=0;c<4;c++) acc[r][c]+=a[r]*bb[c];
    }
  }
  #pragma unroll
  for(int r=0;r<4;r++){
    int kr=r0+ty*4+r;
    if(kr < B_*NM_)
      #pragma unroll
      for(int c=0;c<4;c++)
        doutb[(size_t)kr*D_ + c0+tx+16*c]=acc[r][c];
  }
}

// ---------------- 8. delta = sum_e dout*out ----------------
__global__ __launch_bounds__(256) void k_delta(const float* __restrict__ doutb,
    const float* __restrict__ outb, float* __restrict__ delta){
  int rid = blockIdx.x*4 + (threadIdx.x>>6);
  int lane = threadIdx.x&63;
  if(rid >= B_*H_*NM_) return;
  int b = rid/(H_*NM_); int rem = rid - b*H_*NM_;
  int h = rem/NM_; int i = rem - h*NM_;
  float v = doutb[((size_t)(b*NM_+i))*D_ + h*DH_ + lane]
          * outb [((size_t)(b*N_ +i))*D_ + h*DH_ + lane];
  v = wred64(v);
  if(lane==0) delta[((size_t)(b*H_+h))*N_ + i] = v;
}

// ---------------- 9. flash backward: dq ----------------
__global__ __launch_bounds__(256) void k_dq(const float* __restrict__ q,
    const float* __restrict__ kg, const float* __restrict__ vg,
    const float* __restrict__ doutb, const float* __restrict__ lse,
    const float* __restrict__ delta, float* __restrict__ dq){
  int bh = blockIdx.y; int b=bh>>3, h=bh&7;
  int it = blockIdx.x, i0 = it<<6;
  const float* qb = q  + (size_t)bh*N_*DH_;
  const float* kb = kg + (size_t)bh*N_*DH_;
  const float* vb = vg + (size_t)bh*N_*DH_;
  __shared__ float qs[64][LP], dos[64][LP], ks[64][LP], vs[64][LP], ps[64][LP];
  int tid=threadIdx.x, ty=tid>>4, tx=tid&15;
  for(int kk=0;kk<16;kk++){
    int idx=kk*256+tid; int rr=idx>>6, cc=idx&63;
    int ii=i0+rr;
    qs[rr][cc]=qb[(size_t)ii*DH_+cc];
    dos[rr][cc]=(ii<NM_) ? doutb[((size_t)(b*NM_+ii))*D_ + h*DH_+cc] : 0.f;
  }
  float L[4], dl[4];
  #pragma unroll
  for(int r=0;r<4;r++){
    int ii=i0+ty*4+r;
    L[r]=lse[(size_t)bh*N_+ii];
    dl[r]=(ii<NM_) ? delta[(size_t)bh*N_+ii] : 0.f;
  }
  float acc[4][4]={{0}};
  for(int jt=0;jt<=it;++jt){
    int j0=jt<<6;
    __syncthreads();
    for(int kk=0;kk<16;kk++){
      int idx=kk*256+tid; int rr=idx>>6, cc=idx&63;
      ks[rr][cc]=kb[(size_t)(j0+rr)*DH_+cc];
      vs[rr][cc]=vb[(size_t)(j0+rr)*DH_+cc];
    }
    __syncthreads();
    float sd[4][4]={{0}}, da[4][4]={{0}};
    for(int e=0;e<64;e++){
      float a[4], ad[4], bb[4], bd[4];
      #pragma unroll
      for(int r=0;r<4;r++){ a[r]=qs[ty*4+r][e]; ad[r]=dos[ty*4+r][e]; }
      #pragma unroll
      for(int c=0;c<4;c++){ bb[c]=ks[tx+16*c][e]; bd[c]=vs[tx+16*c][e]; }
      #pragma unroll
      for(int r=0;r<4;r++)
        #pragma unroll
        for(int c=0;c<4;c++){ sd[r][c]+=a[r]*bb[c]; da[r][c]+=ad[r]*bd[c]; }
    }
    #pragma unroll
    for(int r=0;r<4;r++)
      #pragma unroll
      for(int c=0;c<4;c++){
        int ii=i0+ty*4+r, jj=j0+tx+16*c;
        float p = __expf(sd[r][c]*SCALE_F - L[r]);
        float ds = SCALE_F*p*(da[r][c]-dl[r]);
        if(jj>ii || ii>=NM_ || jj>=NM_) ds=0.f;
        ps[ty*4+r][tx+16*c]=ds;
      }
    __syncthreads();
    for(int j=0;j<64;j++){
      float a[4], bb[4];
      #pragma unroll
      for(int r=0;r<4;r++) a[r]=ps[ty*4+r][j];
      #pragma unroll
      for(int c=0;c<4;c++) bb[c]=ks[j][tx+16*c];
      #pragma unroll
      for(int r=0;r<4;r++)
        #pragma unroll
        for(int c=0;c<4;c++) acc[r][c]+=a[r]*bb[c];
    }
  }
  #pragma unroll
  for(int r=0;r<4;r++)
    #pragma unroll
    for(int c=0;c<4;c++)
      dq[((size_t)bh*N_ + i0+ty*4+r)*DH_ + tx+16*c]=acc[r][c];
}

// ---------------- 10. flash backward: dk, dv ----------------
__global__ __launch_bounds__(256) void k_dkv(const float* __restrict__ q,
    const float* __restrict__ kg, const float* __restrict__ vg,
    const float* __restrict__ doutb, const float* __restrict__ lse,
    const float* __restrict__ delta, float* __restrict__ dk, float* __restrict__ dv){
  int bh = blockIdx.y; int b=bh>>3, h=bh&7;
  int jt = blockIdx.x, j0 = jt<<6;
  const float* qb = q  + (size_t)bh*N_*DH_;
  const float* kb = kg + (size_t)bh*N_*DH_;
  const float* vb = vg + (size_t)bh*N_*DH_;
  __shared__ float ks[64][LP], vs[64][LP], qs[64][LP], dos[64][LP], ps[64][LP], dss[64][LP];
  __shared__ float Ls[64], dls[64];
  int tid=threadIdx.x, ty=tid>>4, tx=tid&15;
  for(int kk=0;kk<16;kk++){
    int idx=kk*256+tid; int rr=idx>>6, cc=idx&63;
    ks[rr][cc]=kb[(size_t)(j0+rr)*DH_+cc];
    vs[rr][cc]=vb[(size_t)(j0+rr)*DH_+cc];
  }
  float av[4][4]={{0}}, ak[4][4]={{0}};
  for(int it=jt;it<32;++it){
    int i0=it<<6;
    __syncthreads();
    for(int kk=0;kk<16;kk++){
      int idx=kk*256+tid; int rr=idx>>6, cc=idx&63;
      int ii=i0+rr;
      qs[rr][cc]=qb[(size_t)ii*DH_+cc];
      dos[rr][cc]=(ii<NM_) ? doutb[((size_t)(b*NM_+ii))*D_ + h*DH_+cc] : 0.f;
    }
    if(tid<64){
      int ii=i0+tid;
      Ls[tid]=lse[(size_t)bh*N_+ii];
      dls[tid]=(ii<NM_) ? delta[(size_t)bh*N_+ii] : 0.f;
    }
    __syncthreads();
    float sd[4][4]={{0}}, da[4][4]={{0}};
    for(int e=0;e<64;e++){
      float a[4], ad[4], bb[4], bd[4];
      #pragma unroll
      for(int r=0;r<4;r++){ a[r]=qs[ty*4+r][e]; ad[r]=dos[ty*4+r][e]; }
      #pragma unroll
      for(int c=0;c<4;c++){ bb[c]=ks[tx+16*c][e]; bd[c]=vs[tx+16*c][e]; }
      #pragma unroll
      for(int r=0;r<4;r++)
        #pragma unroll
        for(int c=0;c<4;c++){ sd[r][c]+=a[r]*bb[c]; da[r][c]+=ad[r]*bd[c]; }
    }
    #pragma unroll
    for(int r=0;r<4;r++)
      #pragma unroll
      for(int c=0;c<4;c++){
        int ii=i0+ty*4+r, jj=j0+tx+16*c;
        float p = __expf(sd[r][c]*SCALE_F - Ls[ty*4+r]);
        bool msk = (jj>ii)||(ii>=NM_)||(jj>=NM_);
        float pm = msk?0.f:p;
        float ds = msk?0.f:(SCALE_F*p*(da[r][c]-dls[ty*4+r]));
        ps[ty*4+r][tx+16*c]=pm;
        dss[ty*4+r][tx+16*c]=ds;
      }
    __syncthreads();
    for(int ii=0;ii<64;ii++){
      float a1[4], b1[4], a2[4], b2[4];
      #pragma unroll
      for(int r=0;r<4;r++){ a1[r]=ps[ii][ty*4+r]; a2[r]=dss[ii][ty*4+r]; }
      #pragma unroll
      for(int c=0;c<4;c++){ b1[c]=dos[ii][tx+16*c]; b2[c]=qs[ii][tx+16*c]; }
      #pragma unroll
      for(int r=0;r<4;r++)
        #pragma unroll
        for(int c=0;c<4;c++){ av[r][c]+=a1[r]*b1[c]; ak[r][c]+=a2[r]*b2[c]; }
    }
  }
  #pragma unroll
  for(int r=0;r<4;r++)
    #pragma unroll
    for(int c=0;c<4;c++){
      size_t idx = ((size_t)bh*N_ + j0+ty*4+r)*DH_ + tx+16*c;
      dv[idx]=av[r][c]; dk[idx]=ak[r][c];
    }
}

// ---------------- 11. weight grads: dwq/dwk/dwv (A^T B, split-K) ----------------
__global__ __launch_bounds__(256) void k_wgrad_qkv(const float* __restrict__ t,
    const float* __restrict__ g, float* __restrict__ par){
  int dt=blockIdx.x, h=blockIdx.y, sp=blockIdx.z;
  int k0=sp*512, kend=min(k0+512, B_*NM_);
  __shared__ float as[64][LP], bs[64][LP];
  int tid=threadIdx.x, ty=tid>>4, tx=tid&15;
  float acc[4][4]={{0}};
  for(int kb=k0;kb<kend;kb+=64){
    __syncthreads();
    for(int kk=0;kk<16;kk++){
      int idx=kk*256+tid; int rr=idx>>6, cc=idx&63;
      int kr=kb+rr; float av=0.f, bv=0.f;
      if(kr<kend){
        int b=kr/NM_, i=kr-b*NM_;
        av = t[((size_t)(b*N_+i))*D_ + dt*64+cc];
        bv = g[(((size_t)(b*H_+h))*N_+i)*DH_ + cc];
      }
      as[rr][cc]=av; bs[rr][cc]=bv;
    }
    __syncthreads();
    for(int kk=0;kk<64;kk++){
      float a[4], bb[4];
      #pragma unroll
      for(int r=0;r<4;r++) a[r]=as[kk][ty*4+r];
      #pragma unroll
      for(int c=0;c<4;c++) bb[c]=bs[kk][tx+16*c];
      #pragma unroll
      for(int r=0;r<4;r++)
        #pragma unroll
        for(int c=0;c<4;c++) acc[r][c]+=a[r]*bb[c];
    }
  }
  // par[sp][h][d][e]
  #pragma unroll
  for(int r=0;r<4;r++)
    #pragma unroll
    for(int c=0;c<4;c++)
      par[(size_t)sp*262144 + (size_t)h*32768 + (size_t)(dt*64+ty*4+r)*64 + tx+16*c]=acc[r][c];
}

// dwo: C[e][d] = sum_k out[k][h*64+e] * err[k][d]
__global__ __launch_bounds__(256) void k_wgrad_o(const float* __restrict__ outb,
    const float* __restrict__ er, float* __restrict__ par){
  int dt=blockIdx.x, h=blockIdx.y, sp=blockIdx.z;
  int k0=sp*512, kend=min(k0+512, B_*NM_);
  __shared__ float as[64][LP], bs[64][LP];
  int tid=threadIdx.x, ty=tid>>4, tx=tid&15;
  float acc[4][4]={{0}};
  for(int kb=k0;kb<kend;kb+=64){
    __syncthreads();
    for(int kk=0;kk<16;kk++){
      int idx=kk*256+tid; int rr=idx>>6, cc=idx&63;
      int kr=kb+rr; float av=0.f, bv=0.f;
      if(kr<kend){
        int b=kr/NM_, i=kr-b*NM_;
        av = outb[((size_t)(b*N_+i))*D_ + h*DH_ + cc];
        bv = er[(size_t)kr*D_ + dt*64+cc];
      }
      as[rr][cc]=av; bs[rr][cc]=bv;
    }
    __syncthreads();
    for(int kk=0;kk<64;kk++){
      float a[4], bb[4];
      #pragma unroll
      for(int r=0;r<4;r++) a[r]=as[kk][ty*4+r];
      #pragma unroll
      for(int c=0;c<4;c++) bb[c]=bs[kk][tx+16*c];
      #pragma unroll
      for(int r=0;r<4;r++)
        #pragma unroll
        for(int c=0;c<4;c++) acc[r][c]+=a[r]*bb[c];
    }
  }
  // par[sp][h][e][d]
  #pragma unroll
  for(int r=0;r<4;r++)
    #pragma unroll
    for(int c=0;c<4;c++)
      par[(size_t)sp*262144 + (size_t)h*32768 + (size_t)(ty*4+r)*512 + dt*64+tx+16*c]=acc[r][c];
}

__global__ __launch_bounds__(256) void k_wred_direct(const float* __restrict__ par,
    float* __restrict__ dst){
  int idx = blockIdx.x*256 + threadIdx.x;       // 0..262143
  float s=0.f;
  #pragma unroll
  for(int sp=0;sp<8;sp++) s += par[(size_t)sp*262144 + idx];
  dst[idx]=s;
}

// dwv partial [h][d][e] -> X0[m=h][e][d] (transposed into NS input)
__global__ __launch_bounds__(256) void k_wred_xv(const float* __restrict__ par,
    float* __restrict__ X0){
  int idx = blockIdx.x*256 + threadIdx.x;
  float s=0.f;
  #pragma unroll
  for(int sp=0;sp<8;sp++) s += par[(size_t)sp*262144 + idx];
  int h=idx>>15, rem=idx&32767, d=rem>>6, e=rem&63;
  X0[(size_t)h*32768 + (size_t)e*512 + d]=s;
}

// dwo partial [h][e][d] -> X0[8+h][e][d]
__global__ __launch_bounds__(256) void k_wred_xo(const float* __restrict__ par,
    float* __restrict__ X0){
  int idx = blockIdx.x*256 + threadIdx.x;
  float s=0.f;
  #pragma unroll
  for(int sp=0;sp<8;sp++) s += par[(size_t)sp*262144 + idx];
  X0[262144 + idx]=s;
}

// ---------------- 12. Newton-Schulz ----------------
__global__ __launch_bounds__(256) void k_ns_scale(float* __restrict__ X){
  float* Xm = X + (size_t)blockIdx.x*32768;
  int tid=threadIdx.x;
  float ss=0.f;
  for(int i=tid;i<32768;i+=256){ float v=Xm[i]; ss+=v*v; }
  ss=wred64(ss);
  __shared__ float r[4];
  if((tid&63)==0) r[tid>>6]=ss;
  __syncthreads();
  float tot=r[0]+r[1]+r[2]+r[3];
  float sc = 1.f/fmaxf(sqrtf(tot), 1e-7f);
  for(int i=tid;i<32768;i+=256) Xm[i]*=sc;
}

__global__ __launch_bounds__(256) void k_ns_A(const float* __restrict__ X,
    float* __restrict__ A){
  const float* Xm = X + (size_t)blockIdx.x*32768;
  __shared__ float xs[64][LP];
  int tid=threadIdx.x, ty=tid>>4, tx=tid&15;
  float acc[4][4]={{0}};
  for(int d0=0;d0<512;d0+=64){
    __syncthreads();
    for(int kk=0;kk<16;kk++){
      int idx=kk*256+tid; int rr=idx>>6, cc=idx&63;
      xs[rr][cc]=Xm[(size_t)rr*512 + d0+cc];
    }
    __syncthreads();
    for(int kk=0;kk<64;kk++){
      float a[4], bb[4];
      #pragma unroll
      for(int r=0;r<4;r++) a[r]=xs[ty*4+r][kk];
      #pragma unroll
      for(int c=0;c<4;c++) bb[c]=xs[tx+16*c][kk];
      #pragma unroll
      for(int r=0;r<4;r++)
        #pragma unroll
        for(int c=0;c<4;c++) acc[r][c]+=a[r]*bb[c];
    }
  }
  #pragma unroll
  for(int r=0;r<4;r++)
    #pragma unroll
    for(int c=0;c<4;c++)
      A[(size_t)blockIdx.x*4096 + (size_t)(ty*4+r)*64 + tx+16*c]=acc[r][c];
}

__global__ __launch_bounds__(256) void k_ns_B(const float* __restrict__ A,
    float* __restrict__ Bm){
  __shared__ float as[64][LP];
  int tid=threadIdx.x, ty=tid>>4, tx=tid&15;
  for(int kk=0;kk<16;kk++){
    int idx=kk*256+tid; int rr=idx>>6, cc=idx&63;
    as[rr][cc]=A[(size_t)blockIdx.x*4096 + rr*64 + cc];
  }
  __syncthreads();
  float acc[4][4]={{0}};
  for(int kk=0;kk<64;kk++){
    float a[4], bb[4];
    #pragma unroll
    for(int r=0;r<4;r++) a[r]=as[ty*4+r][kk];
    #pragma unroll
    for(int c=0;c<4;c++) bb[c]=as[kk][tx+16*c];
    #pragma unroll
    for(int r=0;r<4;r++)
      #pragma unroll
      for(int c=0;c<4;c++) acc[r][c]+=a[r]*bb[c];
  }
  #pragma unroll
  for(int r=0;r<4;r++)
    #pragma unroll
    for(int c=0;c<4;c++)
      Bm[(size_t)blockIdx.x*4096 + (size_t)(ty*4+r)*64 + tx+16*c]
        = -4.775f*as[ty*4+r][tx+16*c] + 2.0315f*acc[r][c];
}

__global__ __launch_bounds__(256) void k_ns_update(const float* __restrict__ Xold,
    const float* __restrict__ Bm, float* __restrict__ Xnew){
  int ct=blockIdx.x, m=blockIdx.y;
  __shared__ float bs[64][LP], xs[64][LP];
  int tid=threadIdx.x, ty=tid>>4, tx=tid&15;
  for(int kk=0;kk<16;kk++){
    int idx=kk*256+tid; int rr=idx>>6, cc=idx&63;
    bs[rr][cc]=Bm[(size_t)m*4096 + rr*64 + cc];
    xs[rr][cc]=Xold[(size_t)m*32768 + (size_t)rr*512 + ct*64+cc];
  }
  __syncthreads();
  float acc[4][4]={{0}};
  for(int kk=0;kk<64;kk++){
    float a[4], bb[4];
    #pragma unroll
    for(int r=0;r<4;r++) a[r]=bs[ty*4+r][kk];
    #pragma unroll
    for(int c=0;c<4;c++) bb[c]=xs[kk][tx+16*c];
    #pragma unroll
    for(int r=0;r<4;r++)
      #pragma unroll
      for(int c=0;c<4;c++) acc[r][c]+=a[r]*bb[c];
  }
  #pragma unroll
  for(int r=0;r<4;r++)
    #pragma unroll
    for(int c=0;c<4;c++)
      Xnew[(size_t)m*32768 + (size_t)(ty*4+r)*512 + ct*64+tx+16*c]
        = 3.4445f*xs[ty*4+r][tx+16*c] + acc[r][c];
}

__global__ __launch_bounds__(256) void k_ns_final(const float* __restrict__ X,
    float* __restrict__ dwv, float* __restrict__ dwo){
  int idx = blockIdx.x*256 + threadIdx.x;       // 0..524287
  int m = idx>>15, rem = idx&32767, e = rem>>9, d = rem&511;
  float v = X[idx];
  if(m<8) dwv[(size_t)m*32768 + (size_t)d*64 + e] = v;     // (h,d,e) from X (h,e,d)
  else    dwo[(size_t)(m-8)*32768 + (size_t)e*512 + d] = v; // (h,e,d) direct
}

// ---------------- launch ----------------
extern "C" void kernel_launch(void* const* d_in, const int* in_sizes, int n_in,
                              void* d_out, int out_size, void* d_ws, size_t ws_size,
                              hipStream_t stream) {
  const float* tokens=(const float*)d_in[0];
  const float* rmsw =(const float*)d_in[1];
  const float* wq   =(const float*)d_in[2];
  const float* wk   =(const float*)d_in[3];
  const float* wv   =(const float*)d_in[4];
  const float* wo   =(const float*)d_in[5];
  const float* lrw  =(const float*)d_in[6];
  const float* tvw  =(const float*)d_in[7];
  float* out = (float*)d_out;
  float* ws  = (float*)d_ws;

  float* t_   = ws;
  float* q_   = t_   + 2097152;
  float* kk_  = q_   + 2097152;
  float* v_   = kk_  + 2097152;
  float* ob_  = v_   + 2097152;
  float* lse_ = ob_  + 2097152;
  float* dlt_ = lse_ + 32768;
  float* do_  = dlt_ + 32768;
  float* er_  = do_  + 2096128;
  float* dq_  = er_  + 2096128;
  float* dk_  = dq_  + 2097152;
  float* dv_  = dk_  + 2097152;
  float* par_ = dv_  + 2097152;
  float* X0_  = par_ + 2097152;
  float* X1_  = X0_  + 524288;
  float* Am_  = X1_  + 524288;
  float* Bm_  = Am_  + 65536;

  float* OUT_PRED = out;
  float* OUT_DWQ  = out + 2097152;
  float* OUT_DWK  = out + 2359296;
  float* OUT_DWV  = out + 2621440;
  float* OUT_DWO  = out + 2883584;

  k_rmsnorm<<<4096,256,0,stream>>>(tokens, rmsw, t_);
  k_qkv<<<dim3(64,8),256,0,stream>>>(t_, wq, wk, wv, q_, kk_, v_);
  k_attn_fwd<<<dim3(32,16),256,0,stream>>>(q_, kk_, v_, ob_, lse_);
  k_pred<<<dim3(64,8),256,0,stream>>>(ob_, wo, OUT_PRED);

  if(out_size < 3145728) return;   // forward-only variant

  k_tv<<<dim3(64,8),256,0,stream>>>(t_, tvw, er_);
  k_lnerr<<<4094,256,0,stream>>>(er_, t_, OUT_PRED, lrw);
  k_dout<<<dim3(64,8),256,0,stream>>>(er_, wo, do_);
  k_delta<<<8188,256,0,stream>>>(do_, ob_, dlt_);
  k_dq<<<dim3(32,16),256,0,stream>>>(q_, kk_, v_, do_, lse_, dlt_, dq_);
  k_dkv<<<dim3(32,16),256,0,stream>>>(q_, kk_, v_, do_, lse_, dlt_, dk_, dv_);

  k_wgrad_qkv<<<dim3(8,8,8),256,0,stream>>>(t_, dq_, par_);
  k_wred_direct<<<1024,256,0,stream>>>(par_, OUT_DWQ);
  k_wgrad_qkv<<<dim3(8,8,8),256,0,stream>>>(t_, dk_, par_);
  k_wred_direct<<<1024,256,0,stream>>>(par_, OUT_DWK);
  k_wgrad_qkv<<<dim3(8,8,8),256,0,stream>>>(t_, dv_, par_);
  k_wred_xv<<<1024,256,0,stream>>>(par_, X0_);
  k_wgrad_o<<<dim3(8,8,8),256,0,stream>>>(ob_, er_, par_);
  k_wred_xo<<<1024,256,0,stream>>>(par_, X0_);

  k_ns_scale<<<16,256,0,stream>>>(X0_);
  float* xa = X0_; float* xb = X1_;
  for(int itr=0; itr<5; ++itr){
    k_ns_A<<<16,256,0,stream>>>(xa, Am_);
    k_ns_B<<<16,256,0,stream>>>(Am_, Bm_);
    k_ns_update<<<dim3(8,16),256,0,stream>>>(xa, Bm_, xb);
    float* tmp = xa; xa = xb; xb = tmp;
  }
  k_ns_final<<<2048,256,0,stream>>>(xa, OUT_DWV, OUT_DWO);
}

// Round 3
// 1096.606 us; speedup vs baseline: 2.5507x; 2.5507x over previous
//
#include <hip/hip_runtime.h>
#include <float.h>
#include <math.h>

// ---------------- problem constants ----------------
#define B_   2
#define N_   2048
#define D_   512
#define H_   8
#define DH_  64
#define NM_  2047            // n-1
#define SCALE_F 0.125f       // 64^-0.5
#define LP 66                // LDS row pad (f32 tiles)
#define LBK 72               // LDS row pad (bf16 tiles), 144B: 16B-aligned rows

typedef __attribute__((ext_vector_type(8))) short bf16x8;
typedef __attribute__((ext_vector_type(4))) float f32x4;
#define MFMA_B16(a,b,c) __builtin_amdgcn_mfma_f32_16x16x32_bf16(a,b,c,0,0,0)

__device__ __forceinline__ short f2bf(float f){
  unsigned u = __float_as_uint(f);
  unsigned r = u + 0x7fffu + ((u>>16)&1u);
  return (short)(r>>16);
}
__device__ __forceinline__ float bf2f(short s){
  return __uint_as_float(((unsigned)(unsigned short)s)<<16);
}
// within-wave LDS write->read turnaround (rule #18: waitcnt + sched_barrier)
__device__ __forceinline__ void lds_fence(){
  asm volatile("s_waitcnt lgkmcnt(0)" ::: "memory");
  __builtin_amdgcn_sched_barrier(0);
}
// stage a 64x64 bf16 tile (8 KB) into LDS [64][LBK]; 256 threads x 32 B each.
// BUGFIX (round 2): was one int4/thread = half the tile; second half of every
// row was uninitialized LDS -> NaN through MFMA. Now two int4 per thread.
__device__ __forceinline__ void stage64(const short* __restrict__ src, int stride,
                                        short (*dst)[LBK], int tid){
  int rr = tid>>2, cc = (tid&3)<<4;
  *(int4*)&dst[rr][cc]     = *(const int4*)&src[(size_t)rr*stride + cc];
  *(int4*)&dst[rr][cc+8]   = *(const int4*)&src[(size_t)rr*stride + cc + 8];
}
// read 8 contiguous f32 from LDS, convert to bf16x8 A-fragment
__device__ __forceinline__ bf16x8 cvt8(const float* p){
  float4 a = *(const float4*)p;
  float4 b = *(const float4*)(p+4);
  bf16x8 r;
  r[0]=f2bf(a.x); r[1]=f2bf(a.y); r[2]=f2bf(a.z); r[3]=f2bf(a.w);
  r[4]=f2bf(b.x); r[5]=f2bf(b.y); r[6]=f2bf(b.z); r[7]=f2bf(b.w);
  return r;
}

__device__ __forceinline__ float wred64(float v){
  #pragma unroll
  for(int off=32; off; off>>=1) v += __shfl_down(v, off, 64);
  return v;
}

// ---------------- 1. RMSNorm ----------------
__global__ __launch_bounds__(256) void k_rmsnorm(const float* __restrict__ tok,
    const float* __restrict__ w, float* __restrict__ t){
  int row = blockIdx.x;
  const float* x = tok + (size_t)row*D_;
  float* o = t + (size_t)row*D_;
  int tid = threadIdx.x;
  float v0 = x[tid], v1 = x[tid+256];
  float s = v0*v0 + v1*v1;
  s = wred64(s);
  __shared__ float red[4];
  if((tid&63)==0) red[tid>>6] = s;
  __syncthreads();
  float tot = red[0]+red[1]+red[2]+red[3];
  float sc = rsqrtf(tot*(1.f/512.f) + 1.1920929e-7f);
  o[tid]     = v0*sc*w[tid];
  o[tid+256] = v1*sc*w[tid+256];
}

// ---------------- 2. QKV projection (f32 compute, bf16 outputs + transposes) ----------------
__global__ __launch_bounds__(256) void k_qkv(const float* __restrict__ t,
    const float* __restrict__ wq, const float* __restrict__ wk, const float* __restrict__ wv,
    short* __restrict__ qh, short* __restrict__ kh, short* __restrict__ vh,
    short* __restrict__ qt, short* __restrict__ kt, short* __restrict__ vt){
  int h = blockIdx.y;
  int b = blockIdx.x >> 5;
  int i0 = (blockIdx.x & 31) << 6;
  const float* trow = t + ((size_t)(b*N_ + i0))*D_;
  __shared__ float ts[64][LP], ws0[64][LP], ws1[64][LP], ws2[64][LP];
  int tid = threadIdx.x, ty = tid>>4, tx = tid&15;
  float aq[4][4]={{0}}, ak[4][4]={{0}}, av[4][4]={{0}};
  for(int d0=0; d0<D_; d0+=64){
    __syncthreads();
    for(int kk=0;kk<16;kk++){
      int idx=kk*256+tid; int rr=idx>>6, cc=idx&63;
      ts[rr][cc]  = trow[(size_t)rr*D_ + d0+cc];
      ws0[rr][cc] = wq[((size_t)h*D_ + d0+rr)*DH_ + cc];
      ws1[rr][cc] = wk[((size_t)h*D_ + d0+rr)*DH_ + cc];
      ws2[rr][cc] = wv[((size_t)h*D_ + d0+rr)*DH_ + cc];
    }
    __syncthreads();
    for(int kk=0;kk<64;kk++){
      float a[4], b0[4], b1[4], b2[4];
      #pragma unroll
      for(int r=0;r<4;r++) a[r]=ts[ty*4+r][kk];
      #pragma unroll
      for(int c=0;c<4;c++){ b0[c]=ws0[kk][tx+16*c]; b1[c]=ws1[kk][tx+16*c]; b2[c]=ws2[kk][tx+16*c]; }
      #pragma unroll
      for(int r=0;r<4;r++)
        #pragma unroll
        for(int c=0;c<4;c++){
          aq[r][c] += a[r]*b0[c];
          ak[r][c] += a[r]*b1[c];
          av[r][c] += a[r]*b2[c];
        }
    }
  }
  size_t bh = (size_t)(b*H_+h);
  #pragma unroll
  for(int r=0;r<4;r++)
    #pragma unroll
    for(int c=0;c<4;c++){
      int i = i0+ty*4+r, e = tx+16*c;
      short bq=f2bf(aq[r][c]), bk=f2bf(ak[r][c]), bv=f2bf(av[r][c]);
      qh[(bh*N_+i)*DH_+e]=bq; kh[(bh*N_+i)*DH_+e]=bk; vh[(bh*N_+i)*DH_+e]=bv;
      qt[(bh*DH_+e)*N_+i]=bq; kt[(bh*DH_+e)*N_+i]=bk; vt[(bh*DH_+e)*N_+i]=bv;
    }
}

// ---------------- 3. flash attention forward (MFMA bf16) ----------------
// grid (16 pair, 16 bh); block 256 = 4 waves; pair p handles i-tiles p and 31-p
__global__ __launch_bounds__(256) void k_fa_fwd(const short* __restrict__ qh,
    const short* __restrict__ kh, const short* __restrict__ vt,
    float* __restrict__ outb, float* __restrict__ lse){
  int p = blockIdx.x, bh = blockIdx.y;
  int b = bh>>3, h = bh&7;
  int ia = p, ib = 31-p;
  const short* qhb = qh + (size_t)bh*N_*DH_;
  const short* khb = kh + (size_t)bh*N_*DH_;
  const short* vtb = vt + (size_t)bh*DH_*N_;
  __shared__ __attribute__((aligned(16))) short ks[64][LBK];
  __shared__ __attribute__((aligned(16))) short vts[64][LBK];
  __shared__ __attribute__((aligned(16))) float ps[4][16][68];
  int tid=threadIdx.x, w=tid>>6, lane=tid&63;
  int lg=lane>>4, ln=lane&15;
  bf16x8 aq[2][2];
  #pragma unroll
  for(int sd=0; sd<2; sd++){
    int i0 = (sd? ib:ia)<<6;
    #pragma unroll
    for(int s=0;s<2;s++)
      aq[sd][s] = *(const bf16x8*)&qhb[(size_t)(i0+w*16+ln)*DH_ + 32*s + lg*8];
  }
  f32x4 acc[2][4];
  float mrow[2][4], lrow[2][4];
  #pragma unroll
  for(int sd=0;sd<2;sd++){
    #pragma unroll
    for(int nb=0;nb<4;nb++) acc[sd][nb]=(f32x4){0.f,0.f,0.f,0.f};
    #pragma unroll
    for(int r=0;r<4;r++){ mrow[sd][r]=-FLT_MAX; lrow[sd][r]=0.f; }
  }
  for(int jt=0;jt<=ib;++jt){
    int j0 = jt<<6;
    __syncthreads();
    stage64(khb + (size_t)j0*DH_, DH_, ks, tid);
    stage64(vtb + j0, N_, vts, tid);
    __syncthreads();
    #pragma unroll
    for(int sd=1;sd>=0;--sd){
      if(sd==0 && jt>ia) continue;          // block-uniform
      int i0 = (sd? ib:ia)<<6;
      f32x4 sv[4];
      #pragma unroll
      for(int nb=0;nb<4;nb++){
        f32x4 z = {0.f,0.f,0.f,0.f};
        #pragma unroll
        for(int s=0;s<2;s++){
          bf16x8 bk = *(const bf16x8*)&ks[nb*16+ln][32*s + lg*8];
          z = MFMA_B16(aq[sd][s], bk, z);
        }
        sv[nb]=z;
      }
      int iiB = i0 + w*16 + lg*4;
      #pragma unroll
      for(int r=0;r<4;r++){
        int ii = iiB + r;
        float srow[4]; float mx = -FLT_MAX;
        #pragma unroll
        for(int nb=0;nb<4;nb++){
          float x = sv[nb][r]*SCALE_F;
          if(j0+nb*16+ln > ii) x = -FLT_MAX;
          srow[nb]=x; mx=fmaxf(mx,x);
        }
        mx=fmaxf(mx,__shfl_xor(mx,1)); mx=fmaxf(mx,__shfl_xor(mx,2));
        mx=fmaxf(mx,__shfl_xor(mx,4)); mx=fmaxf(mx,__shfl_xor(mx,8));
        float mn = fmaxf(mrow[sd][r], mx);
        float rs = 0.f;
        #pragma unroll
        for(int nb=0;nb<4;nb++){
          float pv = __expf(srow[nb]-mn);
          ps[w][lg*4+r][ln+16*nb]=pv; rs+=pv;
        }
        rs+=__shfl_xor(rs,1); rs+=__shfl_xor(rs,2);
        rs+=__shfl_xor(rs,4); rs+=__shfl_xor(rs,8);
        float corr = __expf(mrow[sd][r]-mn);
        lrow[sd][r]=lrow[sd][r]*corr+rs; mrow[sd][r]=mn;
        #pragma unroll
        for(int nb=0;nb<4;nb++) acc[sd][nb][r]*=corr;
      }
      lds_fence();
      #pragma unroll
      for(int nb=0;nb<4;nb++){
        #pragma unroll
        for(int s=0;s<2;s++){
          bf16x8 pa = cvt8(&ps[w][ln][32*s + lg*8]);
          bf16x8 bv = *(const bf16x8*)&vts[nb*16+ln][32*s + lg*8];
          acc[sd][nb] = MFMA_B16(pa, bv, acc[sd][nb]);
        }
      }
      lds_fence();
    }
  }
  #pragma unroll
  for(int sd=0;sd<2;sd++){
    int i0 = (sd? ib:ia)<<6;
    #pragma unroll
    for(int r=0;r<4;r++){
      int ii = i0 + w*16 + lg*4 + r;
      float inv = 1.f/lrow[sd][r];
      #pragma unroll
      for(int nb=0;nb<4;nb++)
        outb[((size_t)(b*N_+ii))*D_ + h*DH_ + nb*16+ln] = acc[sd][nb][r]*inv;
      if(ln==0) lse[(size_t)bh*N_ + ii] = mrow[sd][r] + logf(lrow[sd][r]);
    }
  }
}

// ---------------- 4. pred = outb @ wo_flat ----------------
__global__ __launch_bounds__(256) void k_pred(const float* __restrict__ A,
    const float* __restrict__ Bm, float* __restrict__ C){
  int r0 = blockIdx.x<<6, c0 = blockIdx.y<<6;
  __shared__ float as[64][LP], bs[64][LP];
  int tid=threadIdx.x, ty=tid>>4, tx=tid&15;
  float acc[4][4]={{0}};
  for(int k0=0;k0<D_;k0+=64){
    __syncthreads();
    for(int kk=0;kk<16;kk++){
      int idx=kk*256+tid; int rr=idx>>6, cc=idx&63;
      as[rr][cc]=A[(size_t)(r0+rr)*D_ + k0+cc];
      bs[rr][cc]=Bm[(size_t)(k0+rr)*D_ + c0+cc];
    }
    __syncthreads();
    for(int kk=0;kk<64;kk++){
      float a[4], bb[4];
      #pragma unroll
      for(int r=0;r<4;r++) a[r]=as[ty*4+r][kk];
      #pragma unroll
      for(int c=0;c<4;c++) bb[c]=bs[kk][tx+16*c];
      #pragma unroll
      for(int r=0;r<4;r++)
        #pragma unroll
        for(int c=0;c<4;c++) acc[r][c]+=a[r]*bb[c];
    }
  }
  #pragma unroll
  for(int r=0;r<4;r++)
    #pragma unroll
    for(int c=0;c<4;c++)
      C[(size_t)(r0+ty*4+r)*D_ + c0+tx+16*c]=acc[r][c];
}

// ---------------- 5. tv = t[:,1:] @ tv_w^T ----------------
__global__ __launch_bounds__(256) void k_tv(const float* __restrict__ t,
    const float* __restrict__ tvw, float* __restrict__ er){
  int r0 = blockIdx.x<<6, c0 = blockIdx.y<<6;
  __shared__ float as[64][LP], bs[64][LP];
  int tid=threadIdx.x, ty=tid>>4, tx=tid&15;
  float acc[4][4]={{0}};
  for(int k0=0;k0<D_;k0+=64){
    __syncthreads();
    for(int kk=0;kk<16;kk++){
      int idx=kk*256+tid; int rr=idx>>6, cc=idx&63;
      int kr=r0+rr; float av=0.f;
      if(kr < B_*NM_){
        int b=kr/NM_, n=kr-b*NM_;
        av = t[((size_t)(b*N_+n+1))*D_ + k0+cc];
      }
      as[rr][cc]=av;
      bs[rr][cc]=tvw[(size_t)(c0+rr)*D_ + k0+cc];
    }
    __syncthreads();
    for(int kk=0;kk<64;kk++){
      float a[4], bb[4];
      #pragma unroll
      for(int r=0;r<4;r++) a[r]=as[ty*4+r][kk];
      #pragma unroll
      for(int c=0;c<4;c++) bb[c]=bs[tx+16*c][kk];
      #pragma unroll
      for(int r=0;r<4;r++)
        #pragma unroll
        for(int c=0;c<4;c++) acc[r][c]+=a[r]*bb[c];
    }
  }
  #pragma unroll
  for(int r=0;r<4;r++){
    int kr=r0+ty*4+r;
    if(kr < B_*NM_)
      #pragma unroll
      for(int c=0;c<4;c++)
        er[(size_t)kr*D_ + c0+tx+16*c]=acc[r][c];
  }
}

// ---------------- 6. layernorm target + lr + error (in place on er) ----------------
__global__ __launch_bounds__(256) void k_lnerr(float* __restrict__ er,
    const float* __restrict__ t, const float* __restrict__ pred,
    const float* __restrict__ lrw){
  int kr = blockIdx.x;
  int b = kr/NM_, n = kr-b*NM_;
  float* tv = er + (size_t)kr*D_;
  const float* tok = t    + ((size_t)(b*N_+n))*D_;
  const float* pr  = pred + ((size_t)(b*N_+n))*D_;
  int tid=threadIdx.x;
  float v0=tv[tid], v1=tv[tid+256];
  float s1=v0+v1, s2=v0*v0+v1*v1;
  float s3=tok[tid]*lrw[tid] + tok[tid+256]*lrw[tid+256];
  s1=wred64(s1); s2=wred64(s2); s3=wred64(s3);
  __shared__ float r1[4],r2[4],r3[4];
  if((tid&63)==0){ int w=tid>>6; r1[w]=s1; r2[w]=s2; r3[w]=s3; }
  __syncthreads();
  float S1=r1[0]+r1[1]+r1[2]+r1[3];
  float S2=r2[0]+r2[1]+r2[2]+r2[3];
  float S3=r3[0]+r3[1]+r3[2]+r3[3];
  float mu  = S1*(1.f/512.f);
  float var = S2*(1.f/512.f) - mu*mu;
  float rstd= rsqrtf(var + 1e-5f);
  float lr  = 0.01f/(1.f+__expf(-S3));
  tv[tid]     = ((v0-mu)*rstd - pr[tid])*lr;
  tv[tid+256] = ((v1-mu)*rstd - pr[tid+256])*lr;
}

// ---------------- 7. dout = err @ wo^T  (writes bf16 doh + dot) ----------------
__global__ __launch_bounds__(256) void k_dout(const float* __restrict__ er,
    const float* __restrict__ wo, short* __restrict__ doh, short* __restrict__ dot){
  int r0 = blockIdx.x<<6, c0 = blockIdx.y<<6;
  __shared__ float as[64][LP], bs[64][LP];
  int tid=threadIdx.x, ty=tid>>4, tx=tid&15;
  float acc[4][4]={{0}};
  for(int k0=0;k0<D_;k0+=64){
    __syncthreads();
    for(int kk=0;kk<16;kk++){
      int idx=kk*256+tid; int rr=idx>>6, cc=idx&63;
      int kr=r0+rr;
      as[rr][cc] = (kr < B_*NM_) ? er[(size_t)kr*D_ + k0+cc] : 0.f;
      bs[rr][cc] = wo[(size_t)(c0+rr)*D_ + k0+cc];
    }
    __syncthreads();
    for(int kk=0;kk<64;kk++){
      float a[4], bb[4];
      #pragma unroll
      for(int r=0;r<4;r++) a[r]=as[ty*4+r][kk];
      #pragma unroll
      for(int c=0;c<4;c++) bb[c]=bs[tx+16*c][kk];
      #pragma unroll
      for(int r=0;r<4;r++)
        #pragma unroll
        for(int c=0;c<4;c++) acc[r][c]+=a[r]*bb[c];
    }
  }
  #pragma unroll
  for(int r=0;r<4;r++){
    int kr=r0+ty*4+r;
    if(kr < B_*NM_){
      int b=kr/NM_, i=kr-b*NM_;
      #pragma unroll
      for(int c=0;c<4;c++){
        int col=c0+tx+16*c; int h=col>>6, e=col&63;
        short bd=f2bf(acc[r][c]);
        size_t bh=(size_t)(b*H_+h);
        doh[(bh*N_+i)*DH_+e]=bd;
        dot[(bh*DH_+e)*N_+i]=bd;
      }
    }
  }
}

// pad row i = 2047 of doh/dot with zeros (read by attention bwd tiles)
__global__ __launch_bounds__(256) void k_pad(short* __restrict__ doh, short* __restrict__ dot){
  int tid = blockIdx.x*256 + threadIdx.x;   // 0..1023
  if(tid<1024){
    int bh=tid>>6, e=tid&63;
    doh[((size_t)bh*N_+NM_)*DH_+e]=0;
    dot[((size_t)bh*DH_+e)*N_+NM_]=0;
  }
}

// ---------------- 8. delta = sum_e dout*out ----------------
__global__ __launch_bounds__(256) void k_delta(const short* __restrict__ doh,
    const float* __restrict__ outb, float* __restrict__ delta){
  int rid = blockIdx.x*4 + (threadIdx.x>>6);
  int lane = threadIdx.x&63;
  if(rid >= B_*H_*NM_) return;
  int b = rid/(H_*NM_); int rem = rid - b*H_*NM_;
  int h = rem/NM_; int i = rem - h*NM_;
  float v = bf2f(doh[((size_t)(b*H_+h)*N_ + i)*DH_ + lane])
          * outb[((size_t)(b*N_ +i))*D_ + h*DH_ + lane];
  v = wred64(v);
  if(lane==0) delta[((size_t)(b*H_+h))*N_ + i] = v;
}

// ---------------- 9. flash backward dq (MFMA bf16) ----------------
__global__ __launch_bounds__(256) void k_fa_dq(const short* __restrict__ qh,
    const short* __restrict__ kh, const short* __restrict__ vh,
    const short* __restrict__ kt, const short* __restrict__ doh,
    const float* __restrict__ lse, const float* __restrict__ delta,
    float* __restrict__ dqo){
  int p=blockIdx.x, bh=blockIdx.y;
  int ia=p, ib=31-p;
  const short* qhb = qh + (size_t)bh*N_*DH_;
  const short* khb = kh + (size_t)bh*N_*DH_;
  const short* vhb = vh + (size_t)bh*N_*DH_;
  const short* ktb = kt + (size_t)bh*DH_*N_;
  const short* dohb= doh+ (size_t)bh*N_*DH_;
  __shared__ __attribute__((aligned(16))) short ks[64][LBK], vs[64][LBK], kts[64][LBK];
  __shared__ __attribute__((aligned(16))) float ps[4][16][68];
  int tid=threadIdx.x, w=tid>>6, lane=tid&63, lg=lane>>4, ln=lane&15;
  bf16x8 aq[2][2], ad[2][2];
  float Lr[2][4], dl[2][4];
  #pragma unroll
  for(int sd=0;sd<2;sd++){
    int i0=(sd?ib:ia)<<6;
    #pragma unroll
    for(int s=0;s<2;s++){
      aq[sd][s]=*(const bf16x8*)&qhb[(size_t)(i0+w*16+ln)*DH_+32*s+lg*8];
      ad[sd][s]=*(const bf16x8*)&dohb[(size_t)(i0+w*16+ln)*DH_+32*s+lg*8];
    }
    #pragma unroll
    for(int r=0;r<4;r++){
      int ii=i0+w*16+lg*4+r;
      Lr[sd][r]=lse[(size_t)bh*N_+ii];
      dl[sd][r]=(ii<NM_)?delta[(size_t)bh*N_+ii]:0.f;
    }
  }
  f32x4 acc[2][4];
  #pragma unroll
  for(int sd=0;sd<2;sd++)
    #pragma unroll
    for(int nb=0;nb<4;nb++) acc[sd][nb]=(f32x4){0.f,0.f,0.f,0.f};
  for(int jt=0;jt<=ib;++jt){
    int j0=jt<<6;
    __syncthreads();
    stage64(khb+(size_t)j0*DH_, DH_, ks, tid);
    stage64(vhb+(size_t)j0*DH_, DH_, vs, tid);
    stage64(ktb+j0, N_, kts, tid);
    __syncthreads();
    #pragma unroll
    for(int sd=1;sd>=0;--sd){
      if(sd==0 && jt>ia) continue;
      int i0=(sd?ib:ia)<<6;
      f32x4 sv[4], dav[4];
      #pragma unroll
      for(int nb=0;nb<4;nb++){
        f32x4 z={0.f,0.f,0.f,0.f}, zd={0.f,0.f,0.f,0.f};
        #pragma unroll
        for(int s=0;s<2;s++){
          bf16x8 bk=*(const bf16x8*)&ks[nb*16+ln][32*s+lg*8];
          bf16x8 bv=*(const bf16x8*)&vs[nb*16+ln][32*s+lg*8];
          z = MFMA_B16(aq[sd][s], bk, z);
          zd= MFMA_B16(ad[sd][s], bv, zd);
        }
        sv[nb]=z; dav[nb]=zd;
      }
      #pragma unroll
      for(int r=0;r<4;r++){
        int ii=i0+w*16+lg*4+r;
        #pragma unroll
        for(int nb=0;nb<4;nb++){
          int jj=j0+nb*16+ln;
          float pv=__expf(sv[nb][r]*SCALE_F - Lr[sd][r]);
          float dsv=SCALE_F*pv*(dav[nb][r]-dl[sd][r]);
          if(jj>ii || ii>=NM_ || jj>=NM_) dsv=0.f;
          ps[w][lg*4+r][ln+16*nb]=dsv;
        }
      }
      lds_fence();
      #pragma unroll
      for(int nb=0;nb<4;nb++){
        #pragma unroll
        for(int s=0;s<2;s++){
          bf16x8 pa = cvt8(&ps[w][ln][32*s+lg*8]);
          bf16x8 bk = *(const bf16x8*)&kts[nb*16+ln][32*s+lg*8];
          acc[sd][nb]=MFMA_B16(pa,bk,acc[sd][nb]);
        }
      }
      lds_fence();
    }
  }
  #pragma unroll
  for(int sd=0;sd<2;sd++){
    int i0=(sd?ib:ia)<<6;
    #pragma unroll
    for(int r=0;r<4;r++)
      #pragma unroll
      for(int nb=0;nb<4;nb++)
        dqo[((size_t)bh*N_ + i0+w*16+lg*4+r)*DH_ + nb*16+ln]=acc[sd][nb][r];
  }
}

// ---------------- 10. flash backward dk,dv (MFMA bf16, S^T formulation) ----------------
__global__ __launch_bounds__(256) void k_fa_dkv(const short* __restrict__ kh,
    const short* __restrict__ vh, const short* __restrict__ qh,
    const short* __restrict__ qt, const short* __restrict__ doh,
    const short* __restrict__ dot,
    const float* __restrict__ lse, const float* __restrict__ delta,
    float* __restrict__ dko, float* __restrict__ dvo){
  int p=blockIdx.x, bh=blockIdx.y;
  int ja=p, jb=31-p;
  const short* khb = kh + (size_t)bh*N_*DH_;
  const short* vhb = vh + (size_t)bh*N_*DH_;
  const short* qhb = qh + (size_t)bh*N_*DH_;
  const short* qtb = qt + (size_t)bh*DH_*N_;
  const short* dohb= doh+ (size_t)bh*N_*DH_;
  const short* dotb= dot+ (size_t)bh*DH_*N_;
  __shared__ __attribute__((aligned(16))) short qs[64][LBK], dos[64][LBK], qts[64][LBK], dots[64][LBK];
  __shared__ __attribute__((aligned(16))) float ps[4][16][68];
  __shared__ float Ls[64], dls[64];
  int tid=threadIdx.x, w=tid>>6, lane=tid&63, lg=lane>>4, ln=lane&15;
  bf16x8 akf[2][2], avf[2][2];
  #pragma unroll
  for(int sd=0;sd<2;sd++){
    int j0=(sd?jb:ja)<<6;
    #pragma unroll
    for(int s=0;s<2;s++){
      akf[sd][s]=*(const bf16x8*)&khb[(size_t)(j0+w*16+ln)*DH_+32*s+lg*8];
      avf[sd][s]=*(const bf16x8*)&vhb[(size_t)(j0+w*16+ln)*DH_+32*s+lg*8];
    }
  }
  f32x4 accv[2][4], acck[2][4];
  #pragma unroll
  for(int sd=0;sd<2;sd++)
    #pragma unroll
    for(int nb=0;nb<4;nb++){
      accv[sd][nb]=(f32x4){0.f,0.f,0.f,0.f};
      acck[sd][nb]=(f32x4){0.f,0.f,0.f,0.f};
    }
  for(int it=ja; it<32; ++it){
    int i0=it<<6;
    __syncthreads();
    stage64(qhb+(size_t)i0*DH_, DH_, qs, tid);
    stage64(dohb+(size_t)i0*DH_, DH_, dos, tid);
    stage64(qtb+i0, N_, qts, tid);
    stage64(dotb+i0, N_, dots, tid);
    if(tid<64){
      int ii=i0+tid;
      Ls[tid]=lse[(size_t)bh*N_+ii];
      dls[tid]=(ii<NM_)?delta[(size_t)bh*N_+ii]:0.f;
    }
    __syncthreads();
    #pragma unroll
    for(int sd=0;sd<2;sd++){
      if(sd==1 && it<jb) continue;
      int j0=(sd?jb:ja)<<6;
      f32x4 sv[4], dav[4];
      #pragma unroll
      for(int nb=0;nb<4;nb++){
        f32x4 z={0.f,0.f,0.f,0.f}, zd={0.f,0.f,0.f,0.f};
        #pragma unroll
        for(int s=0;s<2;s++){
          bf16x8 bq=*(const bf16x8*)&qs[nb*16+ln][32*s+lg*8];
          bf16x8 bd=*(const bf16x8*)&dos[nb*16+ln][32*s+lg*8];
          z = MFMA_B16(akf[sd][s], bq, z);
          zd= MFMA_B16(avf[sd][s], bd, zd);
        }
        sv[nb]=z; dav[nb]=zd;
      }
      float dsk[4][4];
      #pragma unroll
      for(int nb=0;nb<4;nb++){
        float Lc=Ls[nb*16+ln], dlc=dls[nb*16+ln];
        int ii=i0+nb*16+ln;
        #pragma unroll
        for(int r=0;r<4;r++){
          int jj=j0+w*16+lg*4+r;
          float pv=__expf(sv[nb][r]*SCALE_F - Lc);
          bool msk=(jj>ii)||(ii>=NM_)||(jj>=NM_);
          if(msk) pv=0.f;
          ps[w][lg*4+r][ln+16*nb]=pv;
          dsk[nb][r]= msk?0.f: SCALE_F*pv*(dav[nb][r]-dlc);
        }
      }
      lds_fence();
      #pragma unroll
      for(int nb=0;nb<4;nb++){
        #pragma unroll
        for(int s=0;s<2;s++){
          bf16x8 pa = cvt8(&ps[w][ln][32*s+lg*8]);
          bf16x8 bd = *(const bf16x8*)&dots[nb*16+ln][32*s+lg*8];
          accv[sd][nb]=MFMA_B16(pa,bd,accv[sd][nb]);
        }
      }
      lds_fence();
      #pragma unroll
      for(int nb=0;nb<4;nb++)
        #pragma unroll
        for(int r=0;r<4;r++)
          ps[w][lg*4+r][ln+16*nb]=dsk[nb][r];
      lds_fence();
      #pragma unroll
      for(int nb=0;nb<4;nb++){
        #pragma unroll
        for(int s=0;s<2;s++){
          bf16x8 pa = cvt8(&ps[w][ln][32*s+lg*8]);
          bf16x8 bq = *(const bf16x8*)&qts[nb*16+ln][32*s+lg*8];
          acck[sd][nb]=MFMA_B16(pa,bq,acck[sd][nb]);
        }
      }
      lds_fence();
    }
  }
  #pragma unroll
  for(int sd=0;sd<2;sd++){
    int j0=(sd?jb:ja)<<6;
    #pragma unroll
    for(int r=0;r<4;r++)
      #pragma unroll
      for(int nb=0;nb<4;nb++){
        size_t idx=((size_t)bh*N_ + j0+w*16+lg*4+r)*DH_ + nb*16+ln;
        dvo[idx]=accv[sd][nb][r];
        dko[idx]=acck[sd][nb][r];
      }
  }
}

// ---------------- 11. weight grads (f32, unchanged) ----------------
__global__ __launch_bounds__(256) void k_wgrad_qkv(const float* __restrict__ t,
    const float* __restrict__ g, float* __restrict__ par){
  int dt=blockIdx.x, h=blockIdx.y, sp=blockIdx.z;
  int k0=sp*512, kend=min(k0+512, B_*NM_);
  __shared__ float as[64][LP], bs[64][LP];
  int tid=threadIdx.x, ty=tid>>4, tx=tid&15;
  float acc[4][4]={{0}};
  for(int kb=k0;kb<kend;kb+=64){
    __syncthreads();
    for(int kk=0;kk<16;kk++){
      int idx=kk*256+tid; int rr=idx>>6, cc=idx&63;
      int kr=kb+rr; float av=0.f, bv=0.f;
      if(kr<kend){
        int b=kr/NM_, i=kr-b*NM_;
        av = t[((size_t)(b*N_+i))*D_ + dt*64+cc];
        bv = g[(((size_t)(b*H_+h))*N_+i)*DH_ + cc];
      }
      as[rr][cc]=av; bs[rr][cc]=bv;
    }
    __syncthreads();
    for(int kk=0;kk<64;kk++){
      float a[4], bb[4];
      #pragma unroll
      for(int r=0;r<4;r++) a[r]=as[kk][ty*4+r];
      #pragma unroll
      for(int c=0;c<4;c++) bb[c]=bs[kk][tx+16*c];
      #pragma unroll
      for(int r=0;r<4;r++)
        #pragma unroll
        for(int c=0;c<4;c++) acc[r][c]+=a[r]*bb[c];
    }
  }
  #pragma unroll
  for(int r=0;r<4;r++)
    #pragma unroll
    for(int c=0;c<4;c++)
      par[(size_t)sp*262144 + (size_t)h*32768 + (size_t)(dt*64+ty*4+r)*64 + tx+16*c]=acc[r][c];
}

__global__ __launch_bounds__(256) void k_wgrad_o(const float* __restrict__ outb,
    const float* __restrict__ er, float* __restrict__ par){
  int dt=blockIdx.x, h=blockIdx.y, sp=blockIdx.z;
  int k0=sp*512, kend=min(k0+512, B_*NM_);
  __shared__ float as[64][LP], bs[64][LP];
  int tid=threadIdx.x, ty=tid>>4, tx=tid&15;
  float acc[4][4]={{0}};
  for(int kb=k0;kb<kend;kb+=64){
    __syncthreads();
    for(int kk=0;kk<16;kk++){
      int idx=kk*256+tid; int rr=idx>>6, cc=idx&63;
      int kr=kb+rr; float av=0.f, bv=0.f;
      if(kr<kend){
        int b=kr/NM_, i=kr-b*NM_;
        av = outb[((size_t)(b*N_+i))*D_ + h*DH_ + cc];
        bv = er[(size_t)kr*D_ + dt*64+cc];
      }
      as[rr][cc]=av; bs[rr][cc]=bv;
    }
    __syncthreads();
    for(int kk=0;kk<64;kk++){
      float a[4], bb[4];
      #pragma unroll
      for(int r=0;r<4;r++) a[r]=as[kk][ty*4+r];
      #pragma unroll
      for(int c=0;c<4;c++) bb[c]=bs[kk][tx+16*c];
      #pragma unroll
      for(int r=0;r<4;r++)
        #pragma unroll
        for(int c=0;c<4;c++) acc[r][c]+=a[r]*bb[c];
    }
  }
  #pragma unroll
  for(int r=0;r<4;r++)
    #pragma unroll
    for(int c=0;c<4;c++)
      par[(size_t)sp*262144 + (size_t)h*32768 + (size_t)(ty*4+r)*512 + dt*64+tx+16*c]=acc[r][c];
}

__global__ __launch_bounds__(256) void k_wred_direct(const float* __restrict__ par,
    float* __restrict__ dst){
  int idx = blockIdx.x*256 + threadIdx.x;
  float s=0.f;
  #pragma unroll
  for(int sp=0;sp<8;sp++) s += par[(size_t)sp*262144 + idx];
  dst[idx]=s;
}

__global__ __launch_bounds__(256) void k_wred_xv(const float* __restrict__ par,
    float* __restrict__ X0){
  int idx = blockIdx.x*256 + threadIdx.x;
  float s=0.f;
  #pragma unroll
  for(int sp=0;sp<8;sp++) s += par[(size_t)sp*262144 + idx];
  int h=idx>>15, rem=idx&32767, d=rem>>6, e=rem&63;
  X0[(size_t)h*32768 + (size_t)e*512 + d]=s;
}

__global__ __launch_bounds__(256) void k_wred_xo(const float* __restrict__ par,
    float* __restrict__ X0){
  int idx = blockIdx.x*256 + threadIdx.x;
  float s=0.f;
  #pragma unroll
  for(int sp=0;sp<8;sp++) s += par[(size_t)sp*262144 + idx];
  X0[262144 + idx]=s;
}

// ---------------- 12. Newton-Schulz (f32, unchanged) ----------------
__global__ __launch_bounds__(256) void k_ns_scale(float* __restrict__ X){
  float* Xm = X + (size_t)blockIdx.x*32768;
  int tid=threadIdx.x;
  float ss=0.f;
  for(int i=tid;i<32768;i+=256){ float v=Xm[i]; ss+=v*v; }
  ss=wred64(ss);
  __shared__ float r[4];
  if((tid&63)==0) r[tid>>6]=ss;
  __syncthreads();
  float tot=r[0]+r[1]+r[2]+r[3];
  float sc = 1.f/fmaxf(sqrtf(tot), 1e-7f);
  for(int i=tid;i<32768;i+=256) Xm[i]*=sc;
}

__global__ __launch_bounds__(256) void k_ns_A(const float* __restrict__ X,
    float* __restrict__ A){
  const float* Xm = X + (size_t)blockIdx.x*32768;
  __shared__ float xs[64][LP];
  int tid=threadIdx.x, ty=tid>>4, tx=tid&15;
  float acc[4][4]={{0}};
  for(int d0=0;d0<512;d0+=64){
    __syncthreads();
    for(int kk=0;kk<16;kk++){
      int idx=kk*256+tid; int rr=idx>>6, cc=idx&63;
      xs[rr][cc]=Xm[(size_t)rr*512 + d0+cc];
    }
    __syncthreads();
    for(int kk=0;kk<64;kk++){
      float a[4], bb[4];
      #pragma unroll
      for(int r=0;r<4;r++) a[r]=xs[ty*4+r][kk];
      #pragma unroll
      for(int c=0;c<4;c++) bb[c]=xs[tx+16*c][kk];
      #pragma unroll
      for(int r=0;r<4;r++)
        #pragma unroll
        for(int c=0;c<4;c++) acc[r][c]+=a[r]*bb[c];
    }
  }
  #pragma unroll
  for(int r=0;r<4;r++)
    #pragma unroll
    for(int c=0;c<4;c++)
      A[(size_t)blockIdx.x*4096 + (size_t)(ty*4+r)*64 + tx+16*c]=acc[r][c];
}

__global__ __launch_bounds__(256) void k_ns_B(const float* __restrict__ A,
    float* __restrict__ Bm){
  __shared__ float as[64][LP];
  int tid=threadIdx.x, ty=tid>>4, tx=tid&15;
  for(int kk=0;kk<16;kk++){
    int idx=kk*256+tid; int rr=idx>>6, cc=idx&63;
    as[rr][cc]=A[(size_t)blockIdx.x*4096 + rr*64 + cc];
  }
  __syncthreads();
  float acc[4][4]={{0}};
  for(int kk=0;kk<64;kk++){
    float a[4], bb[4];
    #pragma unroll
    for(int r=0;r<4;r++) a[r]=as[ty*4+r][kk];
    #pragma unroll
    for(int c=0;c<4;c++) bb[c]=as[kk][tx+16*c];
    #pragma unroll
    for(int r=0;r<4;r++)
      #pragma unroll
      for(int c=0;c<4;c++) acc[r][c]+=a[r]*bb[c];
  }
  #pragma unroll
  for(int r=0;r<4;r++)
    #pragma unroll
    for(int c=0;c<4;c++)
      Bm[(size_t)blockIdx.x*4096 + (size_t)(ty*4+r)*64 + tx+16*c]
        = -4.775f*as[ty*4+r][tx+16*c] + 2.0315f*acc[r][c];
}

__global__ __launch_bounds__(256) void k_ns_update(const float* __restrict__ Xold,
    const float* __restrict__ Bm, float* __restrict__ Xnew){
  int ct=blockIdx.x, m=blockIdx.y;
  __shared__ float bs[64][LP], xs[64][LP];
  int tid=threadIdx.x, ty=tid>>4, tx=tid&15;
  for(int kk=0;kk<16;kk++){
    int idx=kk*256+tid; int rr=idx>>6, cc=idx&63;
    bs[rr][cc]=Bm[(size_t)m*4096 + rr*64 + cc];
    xs[rr][cc]=Xold[(size_t)m*32768 + (size_t)rr*512 + ct*64+cc];
  }
  __syncthreads();
  float acc[4][4]={{0}};
  for(int kk=0;kk<64;kk++){
    float a[4], bb[4];
    #pragma unroll
    for(int r=0;r<4;r++) a[r]=bs[ty*4+r][kk];
    #pragma unroll
    for(int c=0;c<4;c++) bb[c]=xs[kk][tx+16*c];
    #pragma unroll
    for(int r=0;r<4;r++)
      #pragma unroll
      for(int c=0;c<4;c++) acc[r][c]+=a[r]*bb[c];
  }
  #pragma unroll
  for(int r=0;r<4;r++)
    #pragma unroll
    for(int c=0;c<4;c++)
      Xnew[(size_t)m*32768 + (size_t)(ty*4+r)*512 + ct*64+tx+16*c]
        = 3.4445f*xs[ty*4+r][tx+16*c] + acc[r][c];
}

__global__ __launch_bounds__(256) void k_ns_final(const float* __restrict__ X,
    float* __restrict__ dwv, float* __restrict__ dwo){
  int idx = blockIdx.x*256 + threadIdx.x;
  int m = idx>>15, rem = idx&32767, e = rem>>9, d = rem&511;
  float v = X[idx];
  if(m<8) dwv[(size_t)m*32768 + (size_t)d*64 + e] = v;
  else    dwo[(size_t)(m-8)*32768 + (size_t)e*512 + d] = v;
}

// ---------------- launch ----------------
extern "C" void kernel_launch(void* const* d_in, const int* in_sizes, int n_in,
                              void* d_out, int out_size, void* d_ws, size_t ws_size,
                              hipStream_t stream) {
  const float* tokens=(const float*)d_in[0];
  const float* rmsw =(const float*)d_in[1];
  const float* wq   =(const float*)d_in[2];
  const float* wk   =(const float*)d_in[3];
  const float* wv   =(const float*)d_in[4];
  const float* wo   =(const float*)d_in[5];
  const float* lrw  =(const float*)d_in[6];
  const float* tvw  =(const float*)d_in[7];
  float* out = (float*)d_out;
  float* ws  = (float*)d_ws;

  float* t_  = ws;
  short* qh  = (short*)(ws + 2097152);
  short* kh  = (short*)(ws + 3145728);
  short* vh  = (short*)(ws + 4194304);
  short* qt  = (short*)(ws + 5242880);
  short* kt  = (short*)(ws + 6291456);
  short* vt  = (short*)(ws + 7340032);
  float* ob_ = ws + 8388608;
  float* lse_= ws + 10485760;
  float* dlt_= ws + 10518528;
  short* doh = (short*)(ws + 10551296);
  short* dot = (short*)(ws + 11599872);
  float* er_ = ws + 12648448;
  float* dq_ = ws + 14744576;
  float* dk_ = ws + 16841728;
  float* dv_ = ws + 18938880;
  float* par_= ws + 10551296;   // aliases doh+dot (dead before wgrad phase)
  float* X0_ = ws + 21036032;
  float* X1_ = ws + 21560320;
  float* Am_ = ws + 22084608;
  float* Bm_ = ws + 22150144;

  float* OUT_PRED = out;
  float* OUT_DWQ  = out + 2097152;
  float* OUT_DWK  = out + 2359296;
  float* OUT_DWV  = out + 2621440;
  float* OUT_DWO  = out + 2883584;

  k_rmsnorm<<<4096,256,0,stream>>>(tokens, rmsw, t_);
  k_qkv<<<dim3(64,8),256,0,stream>>>(t_, wq, wk, wv, qh, kh, vh, qt, kt, vt);
  k_fa_fwd<<<dim3(16,16),256,0,stream>>>(qh, kh, vt, ob_, lse_);
  k_pred<<<dim3(64,8),256,0,stream>>>(ob_, wo, OUT_PRED);

  if(out_size < 3145728) return;   // forward-only variant

  k_tv<<<dim3(64,8),256,0,stream>>>(t_, tvw, er_);
  k_lnerr<<<4094,256,0,stream>>>(er_, t_, OUT_PRED, lrw);
  k_dout<<<dim3(64,8),256,0,stream>>>(er_, wo, doh, dot);
  k_pad<<<4,256,0,stream>>>(doh, dot);
  k_delta<<<8188,256,0,stream>>>(doh, ob_, dlt_);
  k_fa_dq<<<dim3(16,16),256,0,stream>>>(qh, kh, vh, kt, doh, lse_, dlt_, dq_);
  k_fa_dkv<<<dim3(16,16),256,0,stream>>>(kh, vh, qh, qt, doh, dot, lse_, dlt_, dk_, dv_);

  k_wgrad_qkv<<<dim3(8,8,8),256,0,stream>>>(t_, dq_, par_);
  k_wred_direct<<<1024,256,0,stream>>>(par_, OUT_DWQ);
  k_wgrad_qkv<<<dim3(8,8,8),256,0,stream>>>(t_, dk_, par_);
  k_wred_direct<<<1024,256,0,stream>>>(par_, OUT_DWK);
  k_wgrad_qkv<<<dim3(8,8,8),256,0,stream>>>(t_, dv_, par_);
  k_wred_xv<<<1024,256,0,stream>>>(par_, X0_);
  k_wgrad_o<<<dim3(8,8,8),256,0,stream>>>(ob_, er_, par_);
  k_wred_xo<<<1024,256,0,stream>>>(par_, X0_);

  k_ns_scale<<<16,256,0,stream>>>(X0_);
  float* xa = X0_; float* xb = X1_;
  for(int itr=0; itr<5; ++itr){
    k_ns_A<<<16,256,0,stream>>>(xa, Am_);
    k_ns_B<<<16,256,0,stream>>>(Am_, Bm_);
    k_ns_update<<<dim3(8,16),256,0,stream>>>(xa, Bm_, xb);
    float* tmp = xa; xa = xb; xb = tmp;
  }
  k_ns_final<<<2048,256,0,stream>>>(xa, OUT_DWV, OUT_DWO);
}

// Round 4
// 598.177 us; speedup vs baseline: 4.6760x; 1.8332x over previous
//
#include <hip/hip_runtime.h>
#include <float.h>
#include <math.h>

// ---------------- problem constants ----------------
#define B_   2
#define N_   2048
#define D_   512
#define H_   8
#define DH_  64
#define NM_  2047            // n-1
#define SCALE_F 0.125f       // 64^-0.5
#define LBK 72               // LDS row pad (bf16 tiles), 144B: 16B-aligned rows

typedef __attribute__((ext_vector_type(8))) short bf16x8;
typedef __attribute__((ext_vector_type(4))) float f32x4;
#define MFMA_B16(a,b,c) __builtin_amdgcn_mfma_f32_16x16x32_bf16(a,b,c,0,0,0)

__device__ __forceinline__ short f2bf(float f){
  unsigned u = __float_as_uint(f);
  unsigned r = u + 0x7fffu + ((u>>16)&1u);
  return (short)(r>>16);
}
__device__ __forceinline__ float bf2f(short s){
  return __uint_as_float(((unsigned)(unsigned short)s)<<16);
}
__device__ __forceinline__ void lds_fence(){
  asm volatile("s_waitcnt lgkmcnt(0)" ::: "memory");
  __builtin_amdgcn_sched_barrier(0);
}
// stage a 64x64 bf16 tile (8 KB) into LDS [64][LBK]; 256 threads x 32 B each
__device__ __forceinline__ void stage64(const short* __restrict__ src, size_t stride,
                                        short (*dst)[LBK], int tid){
  int rr = tid>>2, cc = (tid&3)<<4;
  *(int4*)&dst[rr][cc]   = *(const int4*)&src[(size_t)rr*stride + cc];
  *(int4*)&dst[rr][cc+8] = *(const int4*)&src[(size_t)rr*stride + cc + 8];
}
// read 8 contiguous f32 from LDS, convert to bf16x8 A-fragment
__device__ __forceinline__ bf16x8 cvt8(const float* p){
  float4 a = *(const float4*)p;
  float4 b = *(const float4*)(p+4);
  bf16x8 r;
  r[0]=f2bf(a.x); r[1]=f2bf(a.y); r[2]=f2bf(a.z); r[3]=f2bf(a.w);
  r[4]=f2bf(b.x); r[5]=f2bf(b.y); r[6]=f2bf(b.z); r[7]=f2bf(b.w);
  return r;
}
__device__ __forceinline__ float wred64(float v){
  #pragma unroll
  for(int off=32; off; off>>=1) v += __shfl_down(v, off, 64);
  return v;
}

// 64x64 MFMA GEMM mainloop: C += A[64][K] * Bt[64][K]^T.  4 waves, wave w owns
// C rows w*16..+15.  A,Bt bf16 row-major with k contiguous.  acc[nb] covers
// cols nb*16+ln, rows lg*4+r (verified C/D layout).
__device__ __forceinline__ void gemm64(const short* __restrict__ A, size_t lda,
    const short* __restrict__ Bt, size_t ldb, int nk,
    short (*as)[LBK], short (*bs)[LBK], f32x4* acc){
  int tid=threadIdx.x, w=tid>>6, lane=tid&63, lg=lane>>4, ln=lane&15;
  for(int kt=0;kt<nk;++kt){
    __syncthreads();
    stage64(A + (size_t)kt*64, lda, as, tid);
    stage64(Bt + (size_t)kt*64, ldb, bs, tid);
    __syncthreads();
    #pragma unroll
    for(int s=0;s<2;s++){
      bf16x8 a = *(const bf16x8*)&as[w*16+ln][32*s+lg*8];
      #pragma unroll
      for(int nb=0;nb<4;nb++){
        bf16x8 b = *(const bf16x8*)&bs[nb*16+ln][32*s+lg*8];
        acc[nb]=MFMA_B16(a,b,acc[nb]);
      }
    }
  }
}

// ---------------- 1. RMSNorm -> tb (bf16, padded to 4160 rows) ----------------
__global__ __launch_bounds__(256) void k_rmsnorm(const float* __restrict__ tok,
    const float* __restrict__ w, short* __restrict__ tb){
  int row = blockIdx.x;                 // 0..4159
  int tid = threadIdx.x;
  if(row>=4096){ tb[(size_t)row*D_+tid]=0; tb[(size_t)row*D_+tid+256]=0; return; }
  const float* x = tok + (size_t)row*D_;
  float v0 = x[tid], v1 = x[tid+256];
  float s = v0*v0 + v1*v1;
  s = wred64(s);
  __shared__ float red[4];
  if((tid&63)==0) red[tid>>6] = s;
  __syncthreads();
  float tot = red[0]+red[1]+red[2]+red[3];
  float sc = rsqrtf(tot*(1.f/512.f) + 1.1920929e-7f);
  tb[(size_t)row*D_+tid]     = f2bf(v0*sc*w[tid]);
  tb[(size_t)row*D_+tid+256] = f2bf(v1*sc*w[tid+256]);
}

// ---------------- 2. weight prep: bf16 copies + transposes ----------------
// blocks 0..63 wq^T, 64..127 wk^T, 128..191 wv^T (per-h [e][d]),
// 192..255 wo^T ([d][he]), 256..263 wob copy ([he][d]), 264..271 tvwb copy
__global__ __launch_bounds__(256) void k_wprep(const float* __restrict__ wq,
    const float* __restrict__ wk, const float* __restrict__ wv,
    const float* __restrict__ wo, const float* __restrict__ tvw,
    short* __restrict__ wqt, short* __restrict__ wkt, short* __restrict__ wvt,
    short* __restrict__ wob, short* __restrict__ wot, short* __restrict__ tvwb){
  __shared__ short l[64][66];
  int bx=blockIdx.x, tid=threadIdx.x;
  if(bx<192){
    const float* w = (bx<64)? wq : (bx<128)? wk : wv;
    short* wt      = (bx<64)? wqt: (bx<128)? wkt: wvt;
    int lb=bx&63, h=lb>>3, d0=(lb&7)*64;
    for(int kk=0;kk<16;kk++){
      int idx=kk*256+tid, rr=idx>>6, cc=idx&63;          // rr=d-local, cc=e
      l[cc][rr] = f2bf(w[((size_t)h*512 + d0+rr)*64 + cc]);
    }
    __syncthreads();
    for(int kk=0;kk<16;kk++){
      int idx=kk*256+tid, rr=idx>>6, cc=idx&63;          // rr=e, cc=d-local
      wt[((size_t)h*64+rr)*512 + d0+cc] = l[rr][cc];
    }
  } else if(bx<256){
    int lb=bx-192, r0=(lb>>3)*64, c0=(lb&7)*64;          // r=he, c=d
    for(int kk=0;kk<16;kk++){
      int idx=kk*256+tid, rr=idx>>6, cc=idx&63;
      l[cc][rr] = f2bf(wo[(size_t)(r0+rr)*512 + c0+cc]);
    }
    __syncthreads();
    for(int kk=0;kk<16;kk++){
      int idx=kk*256+tid, rr=idx>>6, cc=idx&63;
      wot[(size_t)(c0+rr)*512 + r0+cc] = l[rr][cc];
    }
  } else if(bx<264){
    size_t base=(size_t)(bx-256)*32768;
    for(int kk=0;kk<128;kk++) wob[base+kk*256+tid]=f2bf(wo[base+kk*256+tid]);
  } else {
    size_t base=(size_t)(bx-264)*32768;
    for(int kk=0;kk<128;kk++) tvwb[base+kk*256+tid]=f2bf(tvw[base+kk*256+tid]);
  }
}

// ---------------- 3. transposes (4096x512) ----------------
__global__ __launch_bounds__(256) void k_trans_b(const short* __restrict__ in,
    short* __restrict__ outt){
  __shared__ short l[64][66];
  int r0=blockIdx.x<<6, c0=blockIdx.y<<6, tid=threadIdx.x;
  for(int kk=0;kk<16;kk++){
    int idx=kk*256+tid, rr=idx>>6, cc=idx&63;
    l[cc][rr]=in[(size_t)(r0+rr)*512 + c0+cc];
  }
  __syncthreads();
  for(int kk=0;kk<16;kk++){
    int idx=kk*256+tid, rr=idx>>6, cc=idx&63;
    outt[(size_t)(c0+rr)*4096 + r0+cc]=l[rr][cc];
  }
}
__global__ __launch_bounds__(256) void k_trans_f(const float* __restrict__ in,
    short* __restrict__ outn, short* __restrict__ outt){
  __shared__ short l[64][66];
  int r0=blockIdx.x<<6, c0=blockIdx.y<<6, tid=threadIdx.x;
  for(int kk=0;kk<16;kk++){
    int idx=kk*256+tid, rr=idx>>6, cc=idx&63;
    short v=f2bf(in[(size_t)(r0+rr)*512 + c0+cc]);
    outn[(size_t)(r0+rr)*512 + c0+cc]=v;
    l[cc][rr]=v;
  }
  __syncthreads();
  for(int kk=0;kk<16;kk++){
    int idx=kk*256+tid, rr=idx>>6, cc=idx&63;
    outt[(size_t)(c0+rr)*4096 + r0+cc]=l[rr][cc];
  }
}

// ---------------- 4. QKV projection (MFMA) ----------------
// grid (64 row-tiles, 24 = 3 which x 8 h)
__global__ __launch_bounds__(256) void k_gemm_qkv(const short* __restrict__ tb,
    const short* __restrict__ wqt, const short* __restrict__ wkt, const short* __restrict__ wvt,
    short* __restrict__ qh, short* __restrict__ kh, short* __restrict__ vh,
    short* __restrict__ qt, short* __restrict__ kt, short* __restrict__ vt){
  __shared__ __attribute__((aligned(16))) short as[64][LBK], bs[64][LBK];
  int r0=blockIdx.x<<6, ct=blockIdx.y, which=ct>>3, h=ct&7;
  const short* Bt=(which==0?wqt:which==1?wkt:wvt)+(size_t)h*32768;
  f32x4 acc[4];
  #pragma unroll
  for(int nb=0;nb<4;nb++) acc[nb]=(f32x4){0.f,0.f,0.f,0.f};
  gemm64(tb+(size_t)r0*512, 512, Bt, 512, 8, as, bs, acc);
  short* on=(which==0?qh:which==1?kh:vh);
  short* ot=(which==0?qt:which==1?kt:vt);
  int tid=threadIdx.x, w=tid>>6, lane=tid&63, lg=lane>>4, ln=lane&15;
  size_t bh=(size_t)(r0>>11)*8+h;
  int n0=(r0&2047)+w*16+lg*4;
  #pragma unroll
  for(int nb=0;nb<4;nb++){
    int e=nb*16+ln;
    short4 s4;
    s4.x=f2bf(acc[nb][0]); s4.y=f2bf(acc[nb][1]);
    s4.z=f2bf(acc[nb][2]); s4.w=f2bf(acc[nb][3]);
    on[(bh*2048+n0  )*64+e]=s4.x;
    on[(bh*2048+n0+1)*64+e]=s4.y;
    on[(bh*2048+n0+2)*64+e]=s4.z;
    on[(bh*2048+n0+3)*64+e]=s4.w;
    *(short4*)&ot[(bh*64+e)*2048+n0]=s4;
  }
}

// ---------------- 5. flash attention forward (unchanged mainloop) ----------------
__global__ __launch_bounds__(256) void k_fa_fwd(const short* __restrict__ qh,
    const short* __restrict__ kh, const short* __restrict__ vt,
    float* __restrict__ outb, float* __restrict__ lse){
  int p = blockIdx.x, bh = blockIdx.y;
  int b = bh>>3, h = bh&7;
  int ia = p, ib = 31-p;
  const short* qhb = qh + (size_t)bh*N_*DH_;
  const short* khb = kh + (size_t)bh*N_*DH_;
  const short* vtb = vt + (size_t)bh*DH_*N_;
  __shared__ __attribute__((aligned(16))) short ks[64][LBK];
  __shared__ __attribute__((aligned(16))) short vts[64][LBK];
  __shared__ __attribute__((aligned(16))) float ps[4][16][68];
  int tid=threadIdx.x, w=tid>>6, lane=tid&63;
  int lg=lane>>4, ln=lane&15;
  bf16x8 aq[2][2];
  #pragma unroll
  for(int sd=0; sd<2; sd++){
    int i0 = (sd? ib:ia)<<6;
    #pragma unroll
    for(int s=0;s<2;s++)
      aq[sd][s] = *(const bf16x8*)&qhb[(size_t)(i0+w*16+ln)*DH_ + 32*s + lg*8];
  }
  f32x4 acc[2][4];
  float mrow[2][4], lrow[2][4];
  #pragma unroll
  for(int sd=0;sd<2;sd++){
    #pragma unroll
    for(int nb=0;nb<4;nb++) acc[sd][nb]=(f32x4){0.f,0.f,0.f,0.f};
    #pragma unroll
    for(int r=0;r<4;r++){ mrow[sd][r]=-FLT_MAX; lrow[sd][r]=0.f; }
  }
  for(int jt=0;jt<=ib;++jt){
    int j0 = jt<<6;
    __syncthreads();
    stage64(khb + (size_t)j0*DH_, DH_, ks, tid);
    stage64(vtb + j0, N_, vts, tid);
    __syncthreads();
    #pragma unroll
    for(int sd=1;sd>=0;--sd){
      if(sd==0 && jt>ia) continue;
      int i0 = (sd? ib:ia)<<6;
      f32x4 sv[4];
      #pragma unroll
      for(int nb=0;nb<4;nb++){
        f32x4 z = {0.f,0.f,0.f,0.f};
        #pragma unroll
        for(int s=0;s<2;s++){
          bf16x8 bk = *(const bf16x8*)&ks[nb*16+ln][32*s + lg*8];
          z = MFMA_B16(aq[sd][s], bk, z);
        }
        sv[nb]=z;
      }
      int iiB = i0 + w*16 + lg*4;
      #pragma unroll
      for(int r=0;r<4;r++){
        int ii = iiB + r;
        float srow[4]; float mx = -FLT_MAX;
        #pragma unroll
        for(int nb=0;nb<4;nb++){
          float x = sv[nb][r]*SCALE_F;
          if(j0+nb*16+ln > ii) x = -FLT_MAX;
          srow[nb]=x; mx=fmaxf(mx,x);
        }
        mx=fmaxf(mx,__shfl_xor(mx,1)); mx=fmaxf(mx,__shfl_xor(mx,2));
        mx=fmaxf(mx,__shfl_xor(mx,4)); mx=fmaxf(mx,__shfl_xor(mx,8));
        float mn = fmaxf(mrow[sd][r], mx);
        float rs = 0.f;
        #pragma unroll
        for(int nb=0;nb<4;nb++){
          float pv = __expf(srow[nb]-mn);
          ps[w][lg*4+r][ln+16*nb]=pv; rs+=pv;
        }
        rs+=__shfl_xor(rs,1); rs+=__shfl_xor(rs,2);
        rs+=__shfl_xor(rs,4); rs+=__shfl_xor(rs,8);
        float corr = __expf(mrow[sd][r]-mn);
        lrow[sd][r]=lrow[sd][r]*corr+rs; mrow[sd][r]=mn;
        #pragma unroll
        for(int nb=0;nb<4;nb++) acc[sd][nb][r]*=corr;
      }
      lds_fence();
      #pragma unroll
      for(int nb=0;nb<4;nb++){
        #pragma unroll
        for(int s=0;s<2;s++){
          bf16x8 pa = cvt8(&ps[w][ln][32*s + lg*8]);
          bf16x8 bv = *(const bf16x8*)&vts[nb*16+ln][32*s + lg*8];
          acc[sd][nb] = MFMA_B16(pa, bv, acc[sd][nb]);
        }
      }
      lds_fence();
    }
  }
  #pragma unroll
  for(int sd=0;sd<2;sd++){
    int i0 = (sd? ib:ia)<<6;
    #pragma unroll
    for(int r=0;r<4;r++){
      int ii = i0 + w*16 + lg*4 + r;
      float inv = 1.f/lrow[sd][r];
      #pragma unroll
      for(int nb=0;nb<4;nb++)
        outb[((size_t)(b*N_+ii))*D_ + h*DH_ + nb*16+ln] = acc[sd][nb][r]*inv;
      if(ln==0) lse[(size_t)bh*N_ + ii] = mrow[sd][r] + logf(lrow[sd][r]);
    }
  }
}

// ---------------- 6. pred = obb @ wot^T (MFMA), f32 out ----------------
__global__ __launch_bounds__(256) void k_gemm_pred(const short* __restrict__ obb,
    const short* __restrict__ wot, float* __restrict__ pred){
  __shared__ __attribute__((aligned(16))) short as[64][LBK], bs[64][LBK];
  int r0=blockIdx.x<<6, c0=blockIdx.y<<6;
  f32x4 acc[4];
  #pragma unroll
  for(int nb=0;nb<4;nb++) acc[nb]=(f32x4){0.f,0.f,0.f,0.f};
  gemm64(obb+(size_t)r0*512, 512, wot+(size_t)c0*512, 512, 8, as, bs, acc);
  int tid=threadIdx.x, w=tid>>6, lane=tid&63, lg=lane>>4, ln=lane&15;
  int row=r0+w*16+lg*4;
  #pragma unroll
  for(int nb=0;nb<4;nb++)
    #pragma unroll
    for(int r=0;r<4;r++)
      pred[(size_t)(row+r)*512 + c0+nb*16+ln]=acc[nb][r];
}

// ---------------- 7. tv = tb(shift+1) @ tvwb^T (MFMA), f32 out, zero n=2047 ----------------
__global__ __launch_bounds__(256) void k_gemm_tv(const short* __restrict__ tb,
    const short* __restrict__ tvwb, float* __restrict__ er){
  __shared__ __attribute__((aligned(16))) short as[64][LBK], bs[64][LBK];
  int r0=blockIdx.x<<6, c0=blockIdx.y<<6;
  f32x4 acc[4];
  #pragma unroll
  for(int nb=0;nb<4;nb++) acc[nb]=(f32x4){0.f,0.f,0.f,0.f};
  gemm64(tb+(size_t)(r0+1)*512, 512, tvwb+(size_t)c0*512, 512, 8, as, bs, acc);
  int tid=threadIdx.x, w=tid>>6, lane=tid&63, lg=lane>>4, ln=lane&15;
  int row=r0+w*16+lg*4;
  #pragma unroll
  for(int nb=0;nb<4;nb++)
    #pragma unroll
    for(int r=0;r<4;r++){
      float v=(((row+r)&2047)==2047)?0.f:acc[nb][r];
      er[(size_t)(row+r)*512 + c0+nb*16+ln]=v;
    }
}

// ---------------- 8. layernorm target + lr + error (in place, padded rows) ----------------
__global__ __launch_bounds__(256) void k_lnerr(float* __restrict__ er,
    const short* __restrict__ tb, const float* __restrict__ pred,
    const float* __restrict__ lrw){
  int kr = blockIdx.x;
  int b = kr/NM_, n = kr-b*NM_;
  size_t row=(size_t)b*2048+n;
  float* tv = er + row*512;
  const short* tok = tb + row*512;
  const float* pr  = pred + row*512;
  int tid=threadIdx.x;
  float v0=tv[tid], v1=tv[tid+256];
  float s1=v0+v1, s2=v0*v0+v1*v1;
  float s3=bf2f(tok[tid])*lrw[tid] + bf2f(tok[tid+256])*lrw[tid+256];
  s1=wred64(s1); s2=wred64(s2); s3=wred64(s3);
  __shared__ float r1[4],r2[4],r3[4];
  if((tid&63)==0){ int w=tid>>6; r1[w]=s1; r2[w]=s2; r3[w]=s3; }
  __syncthreads();
  float S1=r1[0]+r1[1]+r1[2]+r1[3];
  float S2=r2[0]+r2[1]+r2[2]+r2[3];
  float S3=r3[0]+r3[1]+r3[2]+r3[3];
  float mu  = S1*(1.f/512.f);
  float var = S2*(1.f/512.f) - mu*mu;
  float rstd= rsqrtf(var + 1e-5f);
  float lr  = 0.01f/(1.f+__expf(-S3));
  tv[tid]     = ((v0-mu)*rstd - pr[tid])*lr;
  tv[tid+256] = ((v1-mu)*rstd - pr[tid+256])*lr;
}

// ---------------- 9. dout = erb @ wob^T (MFMA) -> doh + dot bf16 ----------------
__global__ __launch_bounds__(256) void k_gemm_dout(const short* __restrict__ erb,
    const short* __restrict__ wob, short* __restrict__ doh, short* __restrict__ dot){
  __shared__ __attribute__((aligned(16))) short as[64][LBK], bs[64][LBK];
  int r0=blockIdx.x<<6, h=blockIdx.y;
  f32x4 acc[4];
  #pragma unroll
  for(int nb=0;nb<4;nb++) acc[nb]=(f32x4){0.f,0.f,0.f,0.f};
  gemm64(erb+(size_t)r0*512, 512, wob+(size_t)h*32768, 512, 8, as, bs, acc);
  int tid=threadIdx.x, w=tid>>6, lane=tid&63, lg=lane>>4, ln=lane&15;
  size_t bh=(size_t)(r0>>11)*8+h;
  int n0=(r0&2047)+w*16+lg*4;
  #pragma unroll
  for(int nb=0;nb<4;nb++){
    int e=nb*16+ln;
    short4 s4;
    s4.x=f2bf(acc[nb][0]); s4.y=f2bf(acc[nb][1]);
    s4.z=f2bf(acc[nb][2]); s4.w=f2bf(acc[nb][3]);
    doh[(bh*2048+n0  )*64+e]=s4.x;
    doh[(bh*2048+n0+1)*64+e]=s4.y;
    doh[(bh*2048+n0+2)*64+e]=s4.z;
    doh[(bh*2048+n0+3)*64+e]=s4.w;
    *(short4*)&dot[(bh*64+e)*2048+n0]=s4;
  }
}

// ---------------- 10. delta = sum_e dout*out ----------------
__global__ __launch_bounds__(256) void k_delta(const short* __restrict__ doh,
    const short* __restrict__ obb, float* __restrict__ delta){
  int rid = blockIdx.x*4 + (threadIdx.x>>6);
  int lane = threadIdx.x&63;
  if(rid >= B_*H_*NM_) return;
  int b = rid/(H_*NM_); int rem = rid - b*H_*NM_;
  int h = rem/NM_; int i = rem - h*NM_;
  float v = bf2f(doh[((size_t)(b*H_+h)*N_ + i)*DH_ + lane])
          * bf2f(obb[((size_t)(b*N_+i))*D_ + h*DH_ + lane]);
  v = wred64(v);
  if(lane==0) delta[((size_t)(b*H_+h))*N_ + i] = v;
}

// ---------------- 11. flash backward dq (MFMA) -> dqt bf16 transposed ----------------
__global__ __launch_bounds__(256) void k_fa_dq(const short* __restrict__ qh,
    const short* __restrict__ kh, const short* __restrict__ vh,
    const short* __restrict__ kt, const short* __restrict__ doh,
    const float* __restrict__ lse, const float* __restrict__ delta,
    short* __restrict__ dqt){
  int p=blockIdx.x, bh=blockIdx.y;
  int ia=p, ib=31-p;
  const short* qhb = qh + (size_t)bh*N_*DH_;
  const short* khb = kh + (size_t)bh*N_*DH_;
  const short* vhb = vh + (size_t)bh*N_*DH_;
  const short* ktb = kt + (size_t)bh*DH_*N_;
  const short* dohb= doh+ (size_t)bh*N_*DH_;
  __shared__ __attribute__((aligned(16))) short ks[64][LBK], vs[64][LBK], kts[64][LBK];
  __shared__ __attribute__((aligned(16))) float ps[4][16][68];
  int tid=threadIdx.x, w=tid>>6, lane=tid&63, lg=lane>>4, ln=lane&15;
  bf16x8 aq[2][2], ad[2][2];
  float Lr[2][4], dl[2][4];
  #pragma unroll
  for(int sd=0;sd<2;sd++){
    int i0=(sd?ib:ia)<<6;
    #pragma unroll
    for(int s=0;s<2;s++){
      aq[sd][s]=*(const bf16x8*)&qhb[(size_t)(i0+w*16+ln)*DH_+32*s+lg*8];
      ad[sd][s]=*(const bf16x8*)&dohb[(size_t)(i0+w*16+ln)*DH_+32*s+lg*8];
    }
    #pragma unroll
    for(int r=0;r<4;r++){
      int ii=i0+w*16+lg*4+r;
      Lr[sd][r]=lse[(size_t)bh*N_+ii];
      dl[sd][r]=(ii<NM_)?delta[(size_t)bh*N_+ii]:0.f;
    }
  }
  f32x4 acc[2][4];
  #pragma unroll
  for(int sd=0;sd<2;sd++)
    #pragma unroll
    for(int nb=0;nb<4;nb++) acc[sd][nb]=(f32x4){0.f,0.f,0.f,0.f};
  for(int jt=0;jt<=ib;++jt){
    int j0=jt<<6;
    __syncthreads();
    stage64(khb+(size_t)j0*DH_, DH_, ks, tid);
    stage64(vhb+(size_t)j0*DH_, DH_, vs, tid);
    stage64(ktb+j0, N_, kts, tid);
    __syncthreads();
    #pragma unroll
    for(int sd=1;sd>=0;--sd){
      if(sd==0 && jt>ia) continue;
      int i0=(sd?ib:ia)<<6;
      f32x4 sv[4], dav[4];
      #pragma unroll
      for(int nb=0;nb<4;nb++){
        f32x4 z={0.f,0.f,0.f,0.f}, zd={0.f,0.f,0.f,0.f};
        #pragma unroll
        for(int s=0;s<2;s++){
          bf16x8 bk=*(const bf16x8*)&ks[nb*16+ln][32*s+lg*8];
          bf16x8 bv=*(const bf16x8*)&vs[nb*16+ln][32*s+lg*8];
          z = MFMA_B16(aq[sd][s], bk, z);
          zd= MFMA_B16(ad[sd][s], bv, zd);
        }
        sv[nb]=z; dav[nb]=zd;
      }
      #pragma unroll
      for(int r=0;r<4;r++){
        int ii=i0+w*16+lg*4+r;
        #pragma unroll
        for(int nb=0;nb<4;nb++){
          int jj=j0+nb*16+ln;
          float pv=__expf(sv[nb][r]*SCALE_F - Lr[sd][r]);
          float dsv=SCALE_F*pv*(dav[nb][r]-dl[sd][r]);
          if(jj>ii || ii>=NM_ || jj>=NM_) dsv=0.f;
          ps[w][lg*4+r][ln+16*nb]=dsv;
        }
      }
      lds_fence();
      #pragma unroll
      for(int nb=0;nb<4;nb++){
        #pragma unroll
        for(int s=0;s<2;s++){
          bf16x8 pa = cvt8(&ps[w][ln][32*s+lg*8]);
          bf16x8 bk = *(const bf16x8*)&kts[nb*16+ln][32*s+lg*8];
          acc[sd][nb]=MFMA_B16(pa,bk,acc[sd][nb]);
        }
      }
      lds_fence();
    }
  }
  #pragma unroll
  for(int sd=0;sd<2;sd++){
    int i0=(sd?ib:ia)<<6;
    #pragma unroll
    for(int nb=0;nb<4;nb++){
      short4 s4;
      s4.x=f2bf(acc[sd][nb][0]); s4.y=f2bf(acc[sd][nb][1]);
      s4.z=f2bf(acc[sd][nb][2]); s4.w=f2bf(acc[sd][nb][3]);
      *(short4*)&dqt[((size_t)bh*64 + nb*16+ln)*2048 + i0+w*16+lg*4]=s4;
    }
  }
}

// ---------------- 12. flash backward dk,dv (MFMA) -> dkt,dvt bf16 transposed ----------------
__global__ __launch_bounds__(256) void k_fa_dkv(const short* __restrict__ kh,
    const short* __restrict__ vh, const short* __restrict__ qh,
    const short* __restrict__ qt, const short* __restrict__ doh,
    const short* __restrict__ dot,
    const float* __restrict__ lse, const float* __restrict__ delta,
    short* __restrict__ dkt, short* __restrict__ dvt){
  int p=blockIdx.x, bh=blockIdx.y;
  int ja=p, jb=31-p;
  const short* khb = kh + (size_t)bh*N_*DH_;
  const short* vhb = vh + (size_t)bh*N_*DH_;
  const short* qhb = qh + (size_t)bh*N_*DH_;
  const short* qtb = qt + (size_t)bh*DH_*N_;
  const short* dohb= doh+ (size_t)bh*N_*DH_;
  const short* dotb= dot+ (size_t)bh*DH_*N_;
  __shared__ __attribute__((aligned(16))) short qs[64][LBK], dos[64][LBK], qts[64][LBK], dots[64][LBK];
  __shared__ __attribute__((aligned(16))) float ps[4][16][68];
  __shared__ float Ls[64], dls[64];
  int tid=threadIdx.x, w=tid>>6, lane=tid&63, lg=lane>>4, ln=lane&15;
  bf16x8 akf[2][2], avf[2][2];
  #pragma unroll
  for(int sd=0;sd<2;sd++){
    int j0=(sd?jb:ja)<<6;
    #pragma unroll
    for(int s=0;s<2;s++){
      akf[sd][s]=*(const bf16x8*)&khb[(size_t)(j0+w*16+ln)*DH_+32*s+lg*8];
      avf[sd][s]=*(const bf16x8*)&vhb[(size_t)(j0+w*16+ln)*DH_+32*s+lg*8];
    }
  }
  f32x4 accv[2][4], acck[2][4];
  #pragma unroll
  for(int sd=0;sd<2;sd++)
    #pragma unroll
    for(int nb=0;nb<4;nb++){
      accv[sd][nb]=(f32x4){0.f,0.f,0.f,0.f};
      acck[sd][nb]=(f32x4){0.f,0.f,0.f,0.f};
    }
  for(int it=ja; it<32; ++it){
    int i0=it<<6;
    __syncthreads();
    stage64(qhb+(size_t)i0*DH_, DH_, qs, tid);
    stage64(dohb+(size_t)i0*DH_, DH_, dos, tid);
    stage64(qtb+i0, N_, qts, tid);
    stage64(dotb+i0, N_, dots, tid);
    if(tid<64){
      int ii=i0+tid;
      Ls[tid]=lse[(size_t)bh*N_+ii];
      dls[tid]=(ii<NM_)?delta[(size_t)bh*N_+ii]:0.f;
    }
    __syncthreads();
    #pragma unroll
    for(int sd=0;sd<2;sd++){
      if(sd==1 && it<jb) continue;
      int j0=(sd?jb:ja)<<6;
      f32x4 sv[4], dav[4];
      #pragma unroll
      for(int nb=0;nb<4;nb++){
        f32x4 z={0.f,0.f,0.f,0.f}, zd={0.f,0.f,0.f,0.f};
        #pragma unroll
        for(int s=0;s<2;s++){
          bf16x8 bq=*(const bf16x8*)&qs[nb*16+ln][32*s+lg*8];
          bf16x8 bd=*(const bf16x8*)&dos[nb*16+ln][32*s+lg*8];
          z = MFMA_B16(akf[sd][s], bq, z);
          zd= MFMA_B16(avf[sd][s], bd, zd);
        }
        sv[nb]=z; dav[nb]=zd;
      }
      float dsk[4][4];
      #pragma unroll
      for(int nb=0;nb<4;nb++){
        float Lc=Ls[nb*16+ln], dlc=dls[nb*16+ln];
        int ii=i0+nb*16+ln;
        #pragma unroll
        for(int r=0;r<4;r++){
          int jj=j0+w*16+lg*4+r;
          float pv=__expf(sv[nb][r]*SCALE_F - Lc);
          bool msk=(jj>ii)||(ii>=NM_)||(jj>=NM_);
          if(msk) pv=0.f;
          ps[w][lg*4+r][ln+16*nb]=pv;
          dsk[nb][r]= msk?0.f: SCALE_F*pv*(dav[nb][r]-dlc);
        }
      }
      lds_fence();
      #pragma unroll
      for(int nb=0;nb<4;nb++){
        #pragma unroll
        for(int s=0;s<2;s++){
          bf16x8 pa = cvt8(&ps[w][ln][32*s+lg*8]);
          bf16x8 bd = *(const bf16x8*)&dots[nb*16+ln][32*s+lg*8];
          accv[sd][nb]=MFMA_B16(pa,bd,accv[sd][nb]);
        }
      }
      lds_fence();
      #pragma unroll
      for(int nb=0;nb<4;nb++)
        #pragma unroll
        for(int r=0;r<4;r++)
          ps[w][lg*4+r][ln+16*nb]=dsk[nb][r];
      lds_fence();
      #pragma unroll
      for(int nb=0;nb<4;nb++){
        #pragma unroll
        for(int s=0;s<2;s++){
          bf16x8 pa = cvt8(&ps[w][ln][32*s+lg*8]);
          bf16x8 bq = *(const bf16x8*)&qts[nb*16+ln][32*s+lg*8];
          acck[sd][nb]=MFMA_B16(pa,bq,acck[sd][nb]);
        }
      }
      lds_fence();
    }
  }
  #pragma unroll
  for(int sd=0;sd<2;sd++){
    int j0=(sd?jb:ja)<<6;
    #pragma unroll
    for(int nb=0;nb<4;nb++){
      int e=nb*16+ln, n0=j0+w*16+lg*4;
      short4 s4;
      s4.x=f2bf(accv[sd][nb][0]); s4.y=f2bf(accv[sd][nb][1]);
      s4.z=f2bf(accv[sd][nb][2]); s4.w=f2bf(accv[sd][nb][3]);
      *(short4*)&dvt[((size_t)bh*64+e)*2048 + n0]=s4;
      s4.x=f2bf(acck[sd][nb][0]); s4.y=f2bf(acck[sd][nb][1]);
      s4.z=f2bf(acck[sd][nb][2]); s4.w=f2bf(acck[sd][nb][3]);
      *(short4*)&dkt[((size_t)bh*64+e)*2048 + n0]=s4;
    }
  }
}

// ---------------- 13. weight grads (MFMA, split-K=8) ----------------
// dwq/dwk/dwv: par[sp][h][d 512][e 64] = sum_k tt[d][k] g_t[bh][e][k]
__global__ __launch_bounds__(256) void k_gemm_wgq(const short* __restrict__ tt,
    const short* __restrict__ g, float* __restrict__ par){
  __shared__ __attribute__((aligned(16))) short as[64][LBK], bs[64][LBK];
  int dt=blockIdx.x, h=blockIdx.y, sp=blockIdx.z;
  int b=sp>>2, n0b=(sp&3)*512;
  f32x4 acc[4];
  #pragma unroll
  for(int nb=0;nb<4;nb++) acc[nb]=(f32x4){0.f,0.f,0.f,0.f};
  gemm64(tt + (size_t)(dt*64)*4096 + sp*512, 4096,
         g  + ((size_t)(b*8+h)*64)*2048 + n0b, 2048, 8, as, bs, acc);
  int tid=threadIdx.x, w=tid>>6, lane=tid&63, lg=lane>>4, ln=lane&15;
  int row=w*16+lg*4;
  #pragma unroll
  for(int nb=0;nb<4;nb++)
    #pragma unroll
    for(int r=0;r<4;r++)
      par[(size_t)sp*262144 + (size_t)h*32768 + (size_t)(dt*64+row+r)*64 + nb*16+ln]=acc[nb][r];
}

// dwo: par[sp][h][e 64][d 512] = sum_k outt[he][k] ert[d][k]
__global__ __launch_bounds__(256) void k_gemm_wgo(const short* __restrict__ outt,
    const short* __restrict__ ert, float* __restrict__ par){
  __shared__ __attribute__((aligned(16))) short as[64][LBK], bs[64][LBK];
  int ct=blockIdx.x, h=blockIdx.y, sp=blockIdx.z;
  f32x4 acc[4];
  #pragma unroll
  for(int nb=0;nb<4;nb++) acc[nb]=(f32x4){0.f,0.f,0.f,0.f};
  gemm64(outt + (size_t)(h*64)*4096 + sp*512, 4096,
         ert  + (size_t)(ct*64)*4096 + sp*512, 4096, 8, as, bs, acc);
  int tid=threadIdx.x, w=tid>>6, lane=tid&63, lg=lane>>4, ln=lane&15;
  int row=w*16+lg*4;
  #pragma unroll
  for(int nb=0;nb<4;nb++)
    #pragma unroll
    for(int r=0;r<4;r++)
      par[(size_t)sp*262144 + (size_t)h*32768 + (size_t)(row+r)*512 + ct*64+nb*16+ln]=acc[nb][r];
}

__global__ __launch_bounds__(256) void k_wred_direct(const float* __restrict__ par,
    float* __restrict__ dst){
  int idx = blockIdx.x*256 + threadIdx.x;
  float s=0.f;
  #pragma unroll
  for(int sp=0;sp<8;sp++) s += par[(size_t)sp*262144 + idx];
  dst[idx]=s;
}
__global__ __launch_bounds__(256) void k_wred_xv(const float* __restrict__ par,
    float* __restrict__ X0){
  int idx = blockIdx.x*256 + threadIdx.x;
  float s=0.f;
  #pragma unroll
  for(int sp=0;sp<8;sp++) s += par[(size_t)sp*262144 + idx];
  int h=idx>>15, rem=idx&32767, d=rem>>6, e=rem&63;
  X0[(size_t)h*32768 + (size_t)e*512 + d]=s;
}
__global__ __launch_bounds__(256) void k_wred_xo(const float* __restrict__ par,
    float* __restrict__ X0){
  int idx = blockIdx.x*256 + threadIdx.x;
  float s=0.f;
  #pragma unroll
  for(int sp=0;sp<8;sp++) s += par[(size_t)sp*262144 + idx];
  X0[262144 + idx]=s;
}

// ---------------- 14. Newton-Schulz (f32, unchanged) ----------------
#define LP 66
__global__ __launch_bounds__(256) void k_ns_scale(float* __restrict__ X){
  float* Xm = X + (size_t)blockIdx.x*32768;
  int tid=threadIdx.x;
  float ss=0.f;
  for(int i=tid;i<32768;i+=256){ float v=Xm[i]; ss+=v*v; }
  ss=wred64(ss);
  __shared__ float r[4];
  if((tid&63)==0) r[tid>>6]=ss;
  __syncthreads();
  float tot=r[0]+r[1]+r[2]+r[3];
  float sc = 1.f/fmaxf(sqrtf(tot), 1e-7f);
  for(int i=tid;i<32768;i+=256) Xm[i]*=sc;
}
__global__ __launch_bounds__(256) void k_ns_A(const float* __restrict__ X,
    float* __restrict__ A){
  const float* Xm = X + (size_t)blockIdx.x*32768;
  __shared__ float xs[64][LP];
  int tid=threadIdx.x, ty=tid>>4, tx=tid&15;
  float acc[4][4]={{0}};
  for(int d0=0;d0<512;d0+=64){
    __syncthreads();
    for(int kk=0;kk<16;kk++){
      int idx=kk*256+tid; int rr=idx>>6, cc=idx&63;
      xs[rr][cc]=Xm[(size_t)rr*512 + d0+cc];
    }
    __syncthreads();
    for(int kk=0;kk<64;kk++){
      float a[4], bb[4];
      #pragma unroll
      for(int r=0;r<4;r++) a[r]=xs[ty*4+r][kk];
      #pragma unroll
      for(int c=0;c<4;c++) bb[c]=xs[tx+16*c][kk];
      #pragma unroll
      for(int r=0;r<4;r++)
        #pragma unroll
        for(int c=0;c<4;c++) acc[r][c]+=a[r]*bb[c];
    }
  }
  #pragma unroll
  for(int r=0;r<4;r++)
    #pragma unroll
    for(int c=0;c<4;c++)
      A[(size_t)blockIdx.x*4096 + (size_t)(ty*4+r)*64 + tx+16*c]=acc[r][c];
}
__global__ __launch_bounds__(256) void k_ns_B(const float* __restrict__ A,
    float* __restrict__ Bm){
  __shared__ float as[64][LP];
  int tid=threadIdx.x, ty=tid>>4, tx=tid&15;
  for(int kk=0;kk<16;kk++){
    int idx=kk*256+tid; int rr=idx>>6, cc=idx&63;
    as[rr][cc]=A[(size_t)blockIdx.x*4096 + rr*64 + cc];
  }
  __syncthreads();
  float acc[4][4]={{0}};
  for(int kk=0;kk<64;kk++){
    float a[4], bb[4];
    #pragma unroll
    for(int r=0;r<4;r++) a[r]=as[ty*4+r][kk];
    #pragma unroll
    for(int c=0;c<4;c++) bb[c]=as[kk][tx+16*c];
    #pragma unroll
    for(int r=0;r<4;r++)
      #pragma unroll
      for(int c=0;c<4;c++) acc[r][c]+=a[r]*bb[c];
  }
  #pragma unroll
  for(int r=0;r<4;r++)
    #pragma unroll
    for(int c=0;c<4;c++)
      Bm[(size_t)blockIdx.x*4096 + (size_t)(ty*4+r)*64 + tx+16*c]
        = -4.775f*as[ty*4+r][tx+16*c] + 2.0315f*acc[r][c];
}
__global__ __launch_bounds__(256) void k_ns_update(const float* __restrict__ Xold,
    const float* __restrict__ Bm, float* __restrict__ Xnew){
  int ct=blockIdx.x, m=blockIdx.y;
  __shared__ float bs[64][LP], xs[64][LP];
  int tid=threadIdx.x, ty=tid>>4, tx=tid&15;
  for(int kk=0;kk<16;kk++){
    int idx=kk*256+tid; int rr=idx>>6, cc=idx&63;
    bs[rr][cc]=Bm[(size_t)m*4096 + rr*64 + cc];
    xs[rr][cc]=Xold[(size_t)m*32768 + (size_t)rr*512 + ct*64+cc];
  }
  __syncthreads();
  float acc[4][4]={{0}};
  for(int kk=0;kk<64;kk++){
    float a[4], bb[4];
    #pragma unroll
    for(int r=0;r<4;r++) a[r]=bs[ty*4+r][kk];
    #pragma unroll
    for(int c=0;c<4;c++) bb[c]=xs[kk][tx+16*c];
    #pragma unroll
    for(int r=0;r<4;r++)
      #pragma unroll
      for(int c=0;c<4;c++) acc[r][c]+=a[r]*bb[c];
  }
  #pragma unroll
  for(int r=0;r<4;r++)
    #pragma unroll
    for(int c=0;c<4;c++)
      Xnew[(size_t)m*32768 + (size_t)(ty*4+r)*512 + ct*64+tx+16*c]
        = 3.4445f*xs[ty*4+r][tx+16*c] + acc[r][c];
}
__global__ __launch_bounds__(256) void k_ns_final(const float* __restrict__ X,
    float* __restrict__ dwv, float* __restrict__ dwo){
  int idx = blockIdx.x*256 + threadIdx.x;
  int m = idx>>15, rem = idx&32767, e = rem>>9, d = rem&511;
  float v = X[idx];
  if(m<8) dwv[(size_t)m*32768 + (size_t)d*64 + e] = v;
  else    dwo[(size_t)(m-8)*32768 + (size_t)e*512 + d] = v;
}

// ---------------- launch ----------------
extern "C" void kernel_launch(void* const* d_in, const int* in_sizes, int n_in,
                              void* d_out, int out_size, void* d_ws, size_t ws_size,
                              hipStream_t stream) {
  const float* tokens=(const float*)d_in[0];
  const float* rmsw =(const float*)d_in[1];
  const float* wq   =(const float*)d_in[2];
  const float* wk   =(const float*)d_in[3];
  const float* wv   =(const float*)d_in[4];
  const float* wo   =(const float*)d_in[5];
  const float* lrw  =(const float*)d_in[6];
  const float* tvw  =(const float*)d_in[7];
  float* out = (float*)d_out;
  float* ws  = (float*)d_ws;

  short* tb   = (short*)(ws);            // [4160][512] bf16 (pad rows zero)
  short* tt   = (short*)(ws + 1064960);  // [512][4096]
  short* qh   = (short*)(ws + 2113536);  // [16bh][2048][64]
  short* kh   = (short*)(ws + 3162112);
  short* vh   = (short*)(ws + 4210688);
  short* qt   = (short*)(ws + 5259264);  // [16bh][64][2048]
  short* kt   = (short*)(ws + 6307840);
  short* vt   = (short*)(ws + 7356416);
  float* ob_  = ws + 8404992;            // f32 [4096][512]; er_ aliases after trans
  float* er_  = ws + 8404992;
  short* obb  = (short*)(ws + 10502144); // bf16 [4096][512]
  short* outt = (short*)(ws + 11550720); // bf16 [512][4096]
  short* erb  = (short*)(ws + 12599296);
  short* ert  = (short*)(ws + 13647872);
  short* doh  = (short*)(ws + 14696448); // [16bh][2048][64]
  short* dot  = (short*)(ws + 15745024); // [16bh][64][2048]
  float* par_ = ws + 14696448;           // aliases doh+dot (dead before wgrad)
  short* dqt  = (short*)(ws + 16793600); // [16bh][64][2048]
  short* dkt  = (short*)(ws + 17842176);
  short* dvt  = (short*)(ws + 18890752);
  short* wqt  = (short*)(ws + 19939328); // [8h][64][512]
  short* wkt  = (short*)(ws + 20070400);
  short* wvt  = (short*)(ws + 20201472);
  short* wob  = (short*)(ws + 20332544); // [512 he][512 d]
  short* wot  = (short*)(ws + 20463616); // [512 d][512 he]
  short* tvwb = (short*)(ws + 20594688); // [512 o][512 d]
  float* lse_ = ws + 20725760;
  float* dlt_ = ws + 20758528;
  float* X0_  = ws + 20791296;
  float* X1_  = ws + 21315584;
  float* Am_  = ws + 21839872;
  float* Bm_  = ws + 21905408;

  float* OUT_PRED = out;
  float* OUT_DWQ  = out + 2097152;
  float* OUT_DWK  = out + 2359296;
  float* OUT_DWV  = out + 2621440;
  float* OUT_DWO  = out + 2883584;

  k_rmsnorm<<<4160,256,0,stream>>>(tokens, rmsw, tb);
  k_wprep<<<272,256,0,stream>>>(wq,wk,wv,wo,tvw, wqt,wkt,wvt,wob,wot,tvwb);
  k_gemm_qkv<<<dim3(64,24),256,0,stream>>>(tb, wqt,wkt,wvt, qh,kh,vh, qt,kt,vt);
  k_fa_fwd<<<dim3(16,16),256,0,stream>>>(qh, kh, vt, ob_, lse_);
  k_trans_f<<<dim3(64,8),256,0,stream>>>(ob_, obb, outt);
  k_gemm_pred<<<dim3(64,8),256,0,stream>>>(obb, wot, OUT_PRED);

  if(out_size < 3145728) return;   // forward-only variant

  k_trans_b<<<dim3(64,8),256,0,stream>>>(tb, tt);
  k_gemm_tv<<<dim3(64,8),256,0,stream>>>(tb, tvwb, er_);
  k_lnerr<<<4094,256,0,stream>>>(er_, tb, OUT_PRED, lrw);
  k_trans_f<<<dim3(64,8),256,0,stream>>>(er_, erb, ert);
  k_gemm_dout<<<dim3(64,8),256,0,stream>>>(erb, wob, doh, dot);
  k_delta<<<8188,256,0,stream>>>(doh, obb, dlt_);
  k_fa_dq<<<dim3(16,16),256,0,stream>>>(qh, kh, vh, kt, doh, lse_, dlt_, dqt);
  k_fa_dkv<<<dim3(16,16),256,0,stream>>>(kh, vh, qh, qt, doh, dot, lse_, dlt_, dkt, dvt);

  k_gemm_wgq<<<dim3(8,8,8),256,0,stream>>>(tt, dqt, par_);
  k_wred_direct<<<1024,256,0,stream>>>(par_, OUT_DWQ);
  k_gemm_wgq<<<dim3(8,8,8),256,0,stream>>>(tt, dkt, par_);
  k_wred_direct<<<1024,256,0,stream>>>(par_, OUT_DWK);
  k_gemm_wgq<<<dim3(8,8,8),256,0,stream>>>(tt, dvt, par_);
  k_wred_xv<<<1024,256,0,stream>>>(par_, X0_);
  k_gemm_wgo<<<dim3(8,8,8),256,0,stream>>>(outt, ert, par_);
  k_wred_xo<<<1024,256,0,stream>>>(par_, X0_);

  k_ns_scale<<<16,256,0,stream>>>(X0_);
  float* xa = X0_; float* xb = X1_;
  for(int itr=0; itr<5; ++itr){
    k_ns_A<<<16,256,0,stream>>>(xa, Am_);
    k_ns_B<<<16,256,0,stream>>>(Am_, Bm_);
    k_ns_update<<<dim3(8,16),256,0,stream>>>(xa, Bm_, xb);
    float* tmp = xa; xa = xb; xb = tmp;
  }
  k_ns_final<<<2048,256,0,stream>>>(xa, OUT_DWV, OUT_DWO);
}

// Round 5
// 555.048 us; speedup vs baseline: 5.0393x; 1.0777x over previous
//
#include <hip/hip_runtime.h>
#include <float.h>
#include <math.h>

// ---------------- problem constants ----------------
#define B_   2
#define N_   2048
#define D_   512
#define H_   8
#define DH_  64
#define NM_  2047            // n-1
#define SCALE_F 0.125f       // 64^-0.5
#define LBK 72               // LDS row pad (bf16 tiles), 144B: 16B-aligned rows

typedef __attribute__((ext_vector_type(8))) short bf16x8;
typedef __attribute__((ext_vector_type(4))) float f32x4;
#define MFMA_B16(a,b,c) __builtin_amdgcn_mfma_f32_16x16x32_bf16(a,b,c,0,0,0)

__device__ __forceinline__ short f2bf(float f){
  unsigned u = __float_as_uint(f);
  unsigned r = u + 0x7fffu + ((u>>16)&1u);
  return (short)(r>>16);
}
__device__ __forceinline__ float bf2f(short s){
  return __uint_as_float(((unsigned)(unsigned short)s)<<16);
}
__device__ __forceinline__ void lds_fence(){
  asm volatile("s_waitcnt lgkmcnt(0)" ::: "memory");
  __builtin_amdgcn_sched_barrier(0);
}
// stage a 64x64 bf16 tile (8 KB) into LDS [64][LBK]; 256 threads x 32 B each
__device__ __forceinline__ void stage64(const short* __restrict__ src, size_t stride,
                                        short (*dst)[LBK], int tid){
  int rr = tid>>2, cc = (tid&3)<<4;
  *(int4*)&dst[rr][cc]   = *(const int4*)&src[(size_t)rr*stride + cc];
  *(int4*)&dst[rr][cc+8] = *(const int4*)&src[(size_t)rr*stride + cc + 8];
}
// read 8 contiguous f32 from LDS, convert to bf16x8 A-fragment
__device__ __forceinline__ bf16x8 cvt8(const float* p){
  float4 a = *(const float4*)p;
  float4 b = *(const float4*)(p+4);
  bf16x8 r;
  r[0]=f2bf(a.x); r[1]=f2bf(a.y); r[2]=f2bf(a.z); r[3]=f2bf(a.w);
  r[4]=f2bf(b.x); r[5]=f2bf(b.y); r[6]=f2bf(b.z); r[7]=f2bf(b.w);
  return r;
}
__device__ __forceinline__ float wred64(float v){
  #pragma unroll
  for(int off=32; off; off>>=1) v += __shfl_down(v, off, 64);
  return v;
}

// 64x64 MFMA GEMM mainloop: C += A[64][K] * Bt[64][K]^T.
__device__ __forceinline__ void gemm64(const short* __restrict__ A, size_t lda,
    const short* __restrict__ Bt, size_t ldb, int nk,
    short (*as)[LBK], short (*bs)[LBK], f32x4* acc){
  int tid=threadIdx.x, w=tid>>6, lane=tid&63, lg=lane>>4, ln=lane&15;
  for(int kt=0;kt<nk;++kt){
    __syncthreads();
    stage64(A + (size_t)kt*64, lda, as, tid);
    stage64(Bt + (size_t)kt*64, ldb, bs, tid);
    __syncthreads();
    #pragma unroll
    for(int s=0;s<2;s++){
      bf16x8 a = *(const bf16x8*)&as[w*16+ln][32*s+lg*8];
      #pragma unroll
      for(int nb=0;nb<4;nb++){
        bf16x8 b = *(const bf16x8*)&bs[nb*16+ln][32*s+lg*8];
        acc[nb]=MFMA_B16(a,b,acc[nb]);
      }
    }
  }
}

// ---------------- 1. RMSNorm -> tb (bf16, padded to 4160 rows) ----------------
__global__ __launch_bounds__(256) void k_rmsnorm(const float* __restrict__ tok,
    const float* __restrict__ w, short* __restrict__ tb){
  int row = blockIdx.x;
  int tid = threadIdx.x;
  if(row>=4096){ tb[(size_t)row*D_+tid]=0; tb[(size_t)row*D_+tid+256]=0; return; }
  const float* x = tok + (size_t)row*D_;
  float v0 = x[tid], v1 = x[tid+256];
  float s = v0*v0 + v1*v1;
  s = wred64(s);
  __shared__ float red[4];
  if((tid&63)==0) red[tid>>6] = s;
  __syncthreads();
  float tot = red[0]+red[1]+red[2]+red[3];
  float sc = rsqrtf(tot*(1.f/512.f) + 1.1920929e-7f);
  tb[(size_t)row*D_+tid]     = f2bf(v0*sc*w[tid]);
  tb[(size_t)row*D_+tid+256] = f2bf(v1*sc*w[tid+256]);
}

// ---------------- 2. weight prep ----------------
__global__ __launch_bounds__(256) void k_wprep(const float* __restrict__ wq,
    const float* __restrict__ wk, const float* __restrict__ wv,
    const float* __restrict__ wo, const float* __restrict__ tvw,
    short* __restrict__ wqt, short* __restrict__ wkt, short* __restrict__ wvt,
    short* __restrict__ wob, short* __restrict__ wot, short* __restrict__ tvwb){
  __shared__ short l[64][66];
  int bx=blockIdx.x, tid=threadIdx.x;
  if(bx<192){
    const float* w = (bx<64)? wq : (bx<128)? wk : wv;
    short* wt      = (bx<64)? wqt: (bx<128)? wkt: wvt;
    int lb=bx&63, h=lb>>3, d0=(lb&7)*64;
    for(int kk=0;kk<16;kk++){
      int idx=kk*256+tid, rr=idx>>6, cc=idx&63;
      l[cc][rr] = f2bf(w[((size_t)h*512 + d0+rr)*64 + cc]);
    }
    __syncthreads();
    for(int kk=0;kk<16;kk++){
      int idx=kk*256+tid, rr=idx>>6, cc=idx&63;
      wt[((size_t)h*64+rr)*512 + d0+cc] = l[rr][cc];
    }
  } else if(bx<256){
    int lb=bx-192, r0=(lb>>3)*64, c0=(lb&7)*64;
    for(int kk=0;kk<16;kk++){
      int idx=kk*256+tid, rr=idx>>6, cc=idx&63;
      l[cc][rr] = f2bf(wo[(size_t)(r0+rr)*512 + c0+cc]);
    }
    __syncthreads();
    for(int kk=0;kk<16;kk++){
      int idx=kk*256+tid, rr=idx>>6, cc=idx&63;
      wot[(size_t)(c0+rr)*512 + r0+cc] = l[rr][cc];
    }
  } else if(bx<264){
    size_t base=(size_t)(bx-256)*32768;
    for(int kk=0;kk<128;kk++) wob[base+kk*256+tid]=f2bf(wo[base+kk*256+tid]);
  } else {
    size_t base=(size_t)(bx-264)*32768;
    for(int kk=0;kk<128;kk++) tvwb[base+kk*256+tid]=f2bf(tvw[base+kk*256+tid]);
  }
}

// ---------------- 3. transposes (4096x512) ----------------
__global__ __launch_bounds__(256) void k_trans_b(const short* __restrict__ in,
    short* __restrict__ outt){
  __shared__ short l[64][66];
  int r0=blockIdx.x<<6, c0=blockIdx.y<<6, tid=threadIdx.x;
  for(int kk=0;kk<16;kk++){
    int idx=kk*256+tid, rr=idx>>6, cc=idx&63;
    l[cc][rr]=in[(size_t)(r0+rr)*512 + c0+cc];
  }
  __syncthreads();
  for(int kk=0;kk<16;kk++){
    int idx=kk*256+tid, rr=idx>>6, cc=idx&63;
    outt[(size_t)(c0+rr)*4096 + r0+cc]=l[rr][cc];
  }
}
__global__ __launch_bounds__(256) void k_trans_f(const float* __restrict__ in,
    short* __restrict__ outn, short* __restrict__ outt){
  __shared__ short l[64][66];
  int r0=blockIdx.x<<6, c0=blockIdx.y<<6, tid=threadIdx.x;
  for(int kk=0;kk<16;kk++){
    int idx=kk*256+tid, rr=idx>>6, cc=idx&63;
    short v=f2bf(in[(size_t)(r0+rr)*512 + c0+cc]);
    outn[(size_t)(r0+rr)*512 + c0+cc]=v;
    l[cc][rr]=v;
  }
  __syncthreads();
  for(int kk=0;kk<16;kk++){
    int idx=kk*256+tid, rr=idx>>6, cc=idx&63;
    outt[(size_t)(c0+rr)*4096 + r0+cc]=l[rr][cc];
  }
}

// ---------------- 4. QKV projection (MFMA) ----------------
__global__ __launch_bounds__(256) void k_gemm_qkv(const short* __restrict__ tb,
    const short* __restrict__ wqt, const short* __restrict__ wkt, const short* __restrict__ wvt,
    short* __restrict__ qh, short* __restrict__ kh, short* __restrict__ vh,
    short* __restrict__ qt, short* __restrict__ kt, short* __restrict__ vt){
  __shared__ __attribute__((aligned(16))) short as[64][LBK], bs[64][LBK];
  int r0=blockIdx.x<<6, ct=blockIdx.y, which=ct>>3, h=ct&7;
  const short* Bt=(which==0?wqt:which==1?wkt:wvt)+(size_t)h*32768;
  f32x4 acc[4];
  #pragma unroll
  for(int nb=0;nb<4;nb++) acc[nb]=(f32x4){0.f,0.f,0.f,0.f};
  gemm64(tb+(size_t)r0*512, 512, Bt, 512, 8, as, bs, acc);
  short* on=(which==0?qh:which==1?kh:vh);
  short* ot=(which==0?qt:which==1?kt:vt);
  int tid=threadIdx.x, w=tid>>6, lane=tid&63, lg=lane>>4, ln=lane&15;
  size_t bh=(size_t)(r0>>11)*8+h;
  int n0=(r0&2047)+w*16+lg*4;
  #pragma unroll
  for(int nb=0;nb<4;nb++){
    int e=nb*16+ln;
    short4 s4;
    s4.x=f2bf(acc[nb][0]); s4.y=f2bf(acc[nb][1]);
    s4.z=f2bf(acc[nb][2]); s4.w=f2bf(acc[nb][3]);
    on[(bh*2048+n0  )*64+e]=s4.x;
    on[(bh*2048+n0+1)*64+e]=s4.y;
    on[(bh*2048+n0+2)*64+e]=s4.z;
    on[(bh*2048+n0+3)*64+e]=s4.w;
    *(short4*)&ot[(bh*64+e)*2048+n0]=s4;
  }
}

// ---------------- 5. flash attention forward (un-paired, 1 tile/block) ----------------
// grid (16 bh, 32 q); tile it = q<16 ? 31-q : q-16 so co-resident block pairs sum to 33 iters
__global__ __launch_bounds__(256) void k_fa_fwd(const short* __restrict__ qh,
    const short* __restrict__ kh, const short* __restrict__ vt,
    float* __restrict__ outb, float* __restrict__ lse){
  int bh = blockIdx.x, qq = blockIdx.y;
  int it = (qq<16)? (31-qq) : (qq-16);
  int b = bh>>3, h = bh&7;
  int i0 = it<<6;
  const short* qhb = qh + (size_t)bh*N_*DH_;
  const short* khb = kh + (size_t)bh*N_*DH_;
  const short* vtb = vt + (size_t)bh*DH_*N_;
  __shared__ __attribute__((aligned(16))) short ks[64][LBK];
  __shared__ __attribute__((aligned(16))) short vts[64][LBK];
  __shared__ __attribute__((aligned(16))) float ps[4][16][68];
  int tid=threadIdx.x, w=tid>>6, lane=tid&63;
  int lg=lane>>4, ln=lane&15;
  bf16x8 aq[2];
  #pragma unroll
  for(int s=0;s<2;s++)
    aq[s] = *(const bf16x8*)&qhb[(size_t)(i0+w*16+ln)*DH_ + 32*s + lg*8];
  f32x4 acc[4];
  float mrow[4], lrow[4];
  #pragma unroll
  for(int nb=0;nb<4;nb++) acc[nb]=(f32x4){0.f,0.f,0.f,0.f};
  #pragma unroll
  for(int r=0;r<4;r++){ mrow[r]=-FLT_MAX; lrow[r]=0.f; }
  for(int jt=0;jt<=it;++jt){
    int j0 = jt<<6;
    __syncthreads();
    stage64(khb + (size_t)j0*DH_, DH_, ks, tid);
    stage64(vtb + j0, N_, vts, tid);
    __syncthreads();
    f32x4 sv[4];
    #pragma unroll
    for(int nb=0;nb<4;nb++){
      f32x4 z = {0.f,0.f,0.f,0.f};
      #pragma unroll
      for(int s=0;s<2;s++){
        bf16x8 bk = *(const bf16x8*)&ks[nb*16+ln][32*s + lg*8];
        z = MFMA_B16(aq[s], bk, z);
      }
      sv[nb]=z;
    }
    int iiB = i0 + w*16 + lg*4;
    #pragma unroll
    for(int r=0;r<4;r++){
      int ii = iiB + r;
      float srow[4]; float mx = -FLT_MAX;
      #pragma unroll
      for(int nb=0;nb<4;nb++){
        float x = sv[nb][r]*SCALE_F;
        if(j0+nb*16+ln > ii) x = -FLT_MAX;
        srow[nb]=x; mx=fmaxf(mx,x);
      }
      mx=fmaxf(mx,__shfl_xor(mx,1)); mx=fmaxf(mx,__shfl_xor(mx,2));
      mx=fmaxf(mx,__shfl_xor(mx,4)); mx=fmaxf(mx,__shfl_xor(mx,8));
      float mn = fmaxf(mrow[r], mx);
      float rs = 0.f;
      #pragma unroll
      for(int nb=0;nb<4;nb++){
        float pv = __expf(srow[nb]-mn);
        ps[w][lg*4+r][ln+16*nb]=pv; rs+=pv;
      }
      rs+=__shfl_xor(rs,1); rs+=__shfl_xor(rs,2);
      rs+=__shfl_xor(rs,4); rs+=__shfl_xor(rs,8);
      float corr = __expf(mrow[r]-mn);
      lrow[r]=lrow[r]*corr+rs; mrow[r]=mn;
      #pragma unroll
      for(int nb=0;nb<4;nb++) acc[nb][r]*=corr;
    }
    lds_fence();
    #pragma unroll
    for(int nb=0;nb<4;nb++){
      #pragma unroll
      for(int s=0;s<2;s++){
        bf16x8 pa = cvt8(&ps[w][ln][32*s + lg*8]);
        bf16x8 bv = *(const bf16x8*)&vts[nb*16+ln][32*s + lg*8];
        acc[nb] = MFMA_B16(pa, bv, acc[nb]);
      }
    }
    lds_fence();
  }
  #pragma unroll
  for(int r=0;r<4;r++){
    int ii = i0 + w*16 + lg*4 + r;
    float inv = 1.f/lrow[r];
    #pragma unroll
    for(int nb=0;nb<4;nb++)
      outb[((size_t)(b*N_+ii))*D_ + h*DH_ + nb*16+ln] = acc[nb][r]*inv;
    if(ln==0) lse[(size_t)bh*N_ + ii] = mrow[r] + logf(lrow[r]);
  }
}

// ---------------- 6. pred = obb @ wot^T (MFMA), f32 out ----------------
__global__ __launch_bounds__(256) void k_gemm_pred(const short* __restrict__ obb,
    const short* __restrict__ wot, float* __restrict__ pred){
  __shared__ __attribute__((aligned(16))) short as[64][LBK], bs[64][LBK];
  int r0=blockIdx.x<<6, c0=blockIdx.y<<6;
  f32x4 acc[4];
  #pragma unroll
  for(int nb=0;nb<4;nb++) acc[nb]=(f32x4){0.f,0.f,0.f,0.f};
  gemm64(obb+(size_t)r0*512, 512, wot+(size_t)c0*512, 512, 8, as, bs, acc);
  int tid=threadIdx.x, w=tid>>6, lane=tid&63, lg=lane>>4, ln=lane&15;
  int row=r0+w*16+lg*4;
  #pragma unroll
  for(int nb=0;nb<4;nb++)
    #pragma unroll
    for(int r=0;r<4;r++)
      pred[(size_t)(row+r)*512 + c0+nb*16+ln]=acc[nb][r];
}

// ---------------- 7. tv = tb(shift+1) @ tvwb^T ----------------
__global__ __launch_bounds__(256) void k_gemm_tv(const short* __restrict__ tb,
    const short* __restrict__ tvwb, float* __restrict__ er){
  __shared__ __attribute__((aligned(16))) short as[64][LBK], bs[64][LBK];
  int r0=blockIdx.x<<6, c0=blockIdx.y<<6;
  f32x4 acc[4];
  #pragma unroll
  for(int nb=0;nb<4;nb++) acc[nb]=(f32x4){0.f,0.f,0.f,0.f};
  gemm64(tb+(size_t)(r0+1)*512, 512, tvwb+(size_t)c0*512, 512, 8, as, bs, acc);
  int tid=threadIdx.x, w=tid>>6, lane=tid&63, lg=lane>>4, ln=lane&15;
  int row=r0+w*16+lg*4;
  #pragma unroll
  for(int nb=0;nb<4;nb++)
    #pragma unroll
    for(int r=0;r<4;r++){
      float v=(((row+r)&2047)==2047)?0.f:acc[nb][r];
      er[(size_t)(row+r)*512 + c0+nb*16+ln]=v;
    }
}

// ---------------- 8. layernorm target + lr + error ----------------
__global__ __launch_bounds__(256) void k_lnerr(float* __restrict__ er,
    const short* __restrict__ tb, const float* __restrict__ pred,
    const float* __restrict__ lrw){
  int kr = blockIdx.x;
  int b = kr/NM_, n = kr-b*NM_;
  size_t row=(size_t)b*2048+n;
  float* tv = er + row*512;
  const short* tok = tb + row*512;
  const float* pr  = pred + row*512;
  int tid=threadIdx.x;
  float v0=tv[tid], v1=tv[tid+256];
  float s1=v0+v1, s2=v0*v0+v1*v1;
  float s3=bf2f(tok[tid])*lrw[tid] + bf2f(tok[tid+256])*lrw[tid+256];
  s1=wred64(s1); s2=wred64(s2); s3=wred64(s3);
  __shared__ float r1[4],r2[4],r3[4];
  if((tid&63)==0){ int w=tid>>6; r1[w]=s1; r2[w]=s2; r3[w]=s3; }
  __syncthreads();
  float S1=r1[0]+r1[1]+r1[2]+r1[3];
  float S2=r2[0]+r2[1]+r2[2]+r2[3];
  float S3=r3[0]+r3[1]+r3[2]+r3[3];
  float mu  = S1*(1.f/512.f);
  float var = S2*(1.f/512.f) - mu*mu;
  float rstd= rsqrtf(var + 1e-5f);
  float lr  = 0.01f/(1.f+__expf(-S3));
  tv[tid]     = ((v0-mu)*rstd - pr[tid])*lr;
  tv[tid+256] = ((v1-mu)*rstd - pr[tid+256])*lr;
}

// ---------------- 9. dout = erb @ wob^T (MFMA) -> doh + dot bf16 ----------------
__global__ __launch_bounds__(256) void k_gemm_dout(const short* __restrict__ erb,
    const short* __restrict__ wob, short* __restrict__ doh, short* __restrict__ dot){
  __shared__ __attribute__((aligned(16))) short as[64][LBK], bs[64][LBK];
  int r0=blockIdx.x<<6, h=blockIdx.y;
  f32x4 acc[4];
  #pragma unroll
  for(int nb=0;nb<4;nb++) acc[nb]=(f32x4){0.f,0.f,0.f,0.f};
  gemm64(erb+(size_t)r0*512, 512, wob+(size_t)h*32768, 512, 8, as, bs, acc);
  int tid=threadIdx.x, w=tid>>6, lane=tid&63, lg=lane>>4, ln=lane&15;
  size_t bh=(size_t)(r0>>11)*8+h;
  int n0=(r0&2047)+w*16+lg*4;
  #pragma unroll
  for(int nb=0;nb<4;nb++){
    int e=nb*16+ln;
    short4 s4;
    s4.x=f2bf(acc[nb][0]); s4.y=f2bf(acc[nb][1]);
    s4.z=f2bf(acc[nb][2]); s4.w=f2bf(acc[nb][3]);
    doh[(bh*2048+n0  )*64+e]=s4.x;
    doh[(bh*2048+n0+1)*64+e]=s4.y;
    doh[(bh*2048+n0+2)*64+e]=s4.z;
    doh[(bh*2048+n0+3)*64+e]=s4.w;
    *(short4*)&dot[(bh*64+e)*2048+n0]=s4;
  }
}

// ---------------- 10. delta = sum_e dout*out ----------------
__global__ __launch_bounds__(256) void k_delta(const short* __restrict__ doh,
    const short* __restrict__ obb, float* __restrict__ delta){
  int rid = blockIdx.x*4 + (threadIdx.x>>6);
  int lane = threadIdx.x&63;
  if(rid >= B_*H_*NM_) return;
  int b = rid/(H_*NM_); int rem = rid - b*H_*NM_;
  int h = rem/NM_; int i = rem - h*NM_;
  float v = bf2f(doh[((size_t)(b*H_+h)*N_ + i)*DH_ + lane])
          * bf2f(obb[((size_t)(b*N_+i))*D_ + h*DH_ + lane]);
  v = wred64(v);
  if(lane==0) delta[((size_t)(b*H_+h))*N_ + i] = v;
}

// ---------------- 11. flash backward dq (un-paired) -> dqt bf16 ----------------
__global__ __launch_bounds__(256) void k_fa_dq(const short* __restrict__ qh,
    const short* __restrict__ kh, const short* __restrict__ vh,
    const short* __restrict__ kt, const short* __restrict__ doh,
    const float* __restrict__ lse, const float* __restrict__ delta,
    short* __restrict__ dqt){
  int bh = blockIdx.x, qq = blockIdx.y;
  int it = (qq<16)? (31-qq) : (qq-16);
  int i0 = it<<6;
  const short* qhb = qh + (size_t)bh*N_*DH_;
  const short* khb = kh + (size_t)bh*N_*DH_;
  const short* vhb = vh + (size_t)bh*N_*DH_;
  const short* ktb = kt + (size_t)bh*DH_*N_;
  const short* dohb= doh+ (size_t)bh*N_*DH_;
  __shared__ __attribute__((aligned(16))) short ks[64][LBK], vs[64][LBK], kts[64][LBK];
  __shared__ __attribute__((aligned(16))) float ps[4][16][68];
  int tid=threadIdx.x, w=tid>>6, lane=tid&63, lg=lane>>4, ln=lane&15;
  bf16x8 aq[2], ad[2];
  float Lr[4], dl[4];
  #pragma unroll
  for(int s=0;s<2;s++){
    aq[s]=*(const bf16x8*)&qhb[(size_t)(i0+w*16+ln)*DH_+32*s+lg*8];
    ad[s]=*(const bf16x8*)&dohb[(size_t)(i0+w*16+ln)*DH_+32*s+lg*8];
  }
  #pragma unroll
  for(int r=0;r<4;r++){
    int ii=i0+w*16+lg*4+r;
    Lr[r]=lse[(size_t)bh*N_+ii];
    dl[r]=(ii<NM_)?delta[(size_t)bh*N_+ii]:0.f;
  }
  f32x4 acc[4];
  #pragma unroll
  for(int nb=0;nb<4;nb++) acc[nb]=(f32x4){0.f,0.f,0.f,0.f};
  for(int jt=0;jt<=it;++jt){
    int j0=jt<<6;
    __syncthreads();
    stage64(khb+(size_t)j0*DH_, DH_, ks, tid);
    stage64(vhb+(size_t)j0*DH_, DH_, vs, tid);
    stage64(ktb+j0, N_, kts, tid);
    __syncthreads();
    f32x4 sv[4], dav[4];
    #pragma unroll
    for(int nb=0;nb<4;nb++){
      f32x4 z={0.f,0.f,0.f,0.f}, zd={0.f,0.f,0.f,0.f};
      #pragma unroll
      for(int s=0;s<2;s++){
        bf16x8 bk=*(const bf16x8*)&ks[nb*16+ln][32*s+lg*8];
        bf16x8 bv=*(const bf16x8*)&vs[nb*16+ln][32*s+lg*8];
        z = MFMA_B16(aq[s], bk, z);
        zd= MFMA_B16(ad[s], bv, zd);
      }
      sv[nb]=z; dav[nb]=zd;
    }
    #pragma unroll
    for(int r=0;r<4;r++){
      int ii=i0+w*16+lg*4+r;
      #pragma unroll
      for(int nb=0;nb<4;nb++){
        int jj=j0+nb*16+ln;
        float pv=__expf(sv[nb][r]*SCALE_F - Lr[r]);
        float dsv=SCALE_F*pv*(dav[nb][r]-dl[r]);
        if(jj>ii || ii>=NM_ || jj>=NM_) dsv=0.f;
        ps[w][lg*4+r][ln+16*nb]=dsv;
      }
    }
    lds_fence();
    #pragma unroll
    for(int nb=0;nb<4;nb++){
      #pragma unroll
      for(int s=0;s<2;s++){
        bf16x8 pa = cvt8(&ps[w][ln][32*s+lg*8]);
        bf16x8 bk = *(const bf16x8*)&kts[nb*16+ln][32*s+lg*8];
        acc[nb]=MFMA_B16(pa,bk,acc[nb]);
      }
    }
    lds_fence();
  }
  #pragma unroll
  for(int nb=0;nb<4;nb++){
    short4 s4;
    s4.x=f2bf(acc[nb][0]); s4.y=f2bf(acc[nb][1]);
    s4.z=f2bf(acc[nb][2]); s4.w=f2bf(acc[nb][3]);
    *(short4*)&dqt[((size_t)bh*64 + nb*16+ln)*2048 + i0+w*16+lg*4]=s4;
  }
}

// ---------------- 12. flash backward dk,dv (un-paired) -> dkt,dvt bf16 ----------------
__global__ __launch_bounds__(256) void k_fa_dkv(const short* __restrict__ kh,
    const short* __restrict__ vh, const short* __restrict__ qh,
    const short* __restrict__ qt, const short* __restrict__ doh,
    const short* __restrict__ dot,
    const float* __restrict__ lse, const float* __restrict__ delta,
    short* __restrict__ dkt, short* __restrict__ dvt){
  int bh = blockIdx.x, qq = blockIdx.y;
  int jt = (qq<16)? qq : (47-qq);
  int j0 = jt<<6;
  const short* khb = kh + (size_t)bh*N_*DH_;
  const short* vhb = vh + (size_t)bh*N_*DH_;
  const short* qhb = qh + (size_t)bh*N_*DH_;
  const short* qtb = qt + (size_t)bh*DH_*N_;
  const short* dohb= doh+ (size_t)bh*N_*DH_;
  const short* dotb= dot+ (size_t)bh*DH_*N_;
  __shared__ __attribute__((aligned(16))) short qs[64][LBK], dos[64][LBK], qts[64][LBK], dots[64][LBK];
  __shared__ __attribute__((aligned(16))) float ps[4][16][68];
  __shared__ float Ls[64], dls[64];
  int tid=threadIdx.x, w=tid>>6, lane=tid&63, lg=lane>>4, ln=lane&15;
  bf16x8 akf[2], avf[2];
  #pragma unroll
  for(int s=0;s<2;s++){
    akf[s]=*(const bf16x8*)&khb[(size_t)(j0+w*16+ln)*DH_+32*s+lg*8];
    avf[s]=*(const bf16x8*)&vhb[(size_t)(j0+w*16+ln)*DH_+32*s+lg*8];
  }
  f32x4 accv[4], acck[4];
  #pragma unroll
  for(int nb=0;nb<4;nb++){
    accv[nb]=(f32x4){0.f,0.f,0.f,0.f};
    acck[nb]=(f32x4){0.f,0.f,0.f,0.f};
  }
  for(int it=jt; it<32; ++it){
    int i0=it<<6;
    __syncthreads();
    stage64(qhb+(size_t)i0*DH_, DH_, qs, tid);
    stage64(dohb+(size_t)i0*DH_, DH_, dos, tid);
    stage64(qtb+i0, N_, qts, tid);
    stage64(dotb+i0, N_, dots, tid);
    if(tid<64){
      int ii=i0+tid;
      Ls[tid]=lse[(size_t)bh*N_+ii];
      dls[tid]=(ii<NM_)?delta[(size_t)bh*N_+ii]:0.f;
    }
    __syncthreads();
    f32x4 sv[4], dav[4];
    #pragma unroll
    for(int nb=0;nb<4;nb++){
      f32x4 z={0.f,0.f,0.f,0.f}, zd={0.f,0.f,0.f,0.f};
      #pragma unroll
      for(int s=0;s<2;s++){
        bf16x8 bq=*(const bf16x8*)&qs[nb*16+ln][32*s+lg*8];
        bf16x8 bd=*(const bf16x8*)&dos[nb*16+ln][32*s+lg*8];
        z = MFMA_B16(akf[s], bq, z);
        zd= MFMA_B16(avf[s], bd, zd);
      }
      sv[nb]=z; dav[nb]=zd;
    }
    float dsk[4][4];
    #pragma unroll
    for(int nb=0;nb<4;nb++){
      float Lc=Ls[nb*16+ln], dlc=dls[nb*16+ln];
      int ii=i0+nb*16+ln;
      #pragma unroll
      for(int r=0;r<4;r++){
        int jj=j0+w*16+lg*4+r;
        float pv=__expf(sv[nb][r]*SCALE_F - Lc);
        bool msk=(jj>ii)||(ii>=NM_)||(jj>=NM_);
        if(msk) pv=0.f;
        ps[w][lg*4+r][ln+16*nb]=pv;
        dsk[nb][r]= msk?0.f: SCALE_F*pv*(dav[nb][r]-dlc);
      }
    }
    lds_fence();
    #pragma unroll
    for(int nb=0;nb<4;nb++){
      #pragma unroll
      for(int s=0;s<2;s++){
        bf16x8 pa = cvt8(&ps[w][ln][32*s+lg*8]);
        bf16x8 bd = *(const bf16x8*)&dots[nb*16+ln][32*s+lg*8];
        accv[nb]=MFMA_B16(pa,bd,accv[nb]);
      }
    }
    lds_fence();
    #pragma unroll
    for(int nb=0;nb<4;nb++)
      #pragma unroll
      for(int r=0;r<4;r++)
        ps[w][lg*4+r][ln+16*nb]=dsk[nb][r];
    lds_fence();
    #pragma unroll
    for(int nb=0;nb<4;nb++){
      #pragma unroll
      for(int s=0;s<2;s++){
        bf16x8 pa = cvt8(&ps[w][ln][32*s+lg*8]);
        bf16x8 bq = *(const bf16x8*)&qts[nb*16+ln][32*s+lg*8];
        acck[nb]=MFMA_B16(pa,bq,acck[nb]);
      }
    }
    lds_fence();
  }
  #pragma unroll
  for(int nb=0;nb<4;nb++){
    int e=nb*16+ln, n0=j0+w*16+lg*4;
    short4 s4;
    s4.x=f2bf(accv[nb][0]); s4.y=f2bf(accv[nb][1]);
    s4.z=f2bf(accv[nb][2]); s4.w=f2bf(accv[nb][3]);
    *(short4*)&dvt[((size_t)bh*64+e)*2048 + n0]=s4;
    s4.x=f2bf(acck[nb][0]); s4.y=f2bf(acck[nb][1]);
    s4.z=f2bf(acck[nb][2]); s4.w=f2bf(acck[nb][3]);
    *(short4*)&dkt[((size_t)bh*64+e)*2048 + n0]=s4;
  }
}

// ---------------- 13. weight grads (MFMA, split-K=8) ----------------
__global__ __launch_bounds__(256) void k_gemm_wgq(const short* __restrict__ tt,
    const short* __restrict__ g, float* __restrict__ par){
  __shared__ __attribute__((aligned(16))) short as[64][LBK], bs[64][LBK];
  int dt=blockIdx.x, h=blockIdx.y, sp=blockIdx.z;
  int b=sp>>2, n0b=(sp&3)*512;
  f32x4 acc[4];
  #pragma unroll
  for(int nb=0;nb<4;nb++) acc[nb]=(f32x4){0.f,0.f,0.f,0.f};
  gemm64(tt + (size_t)(dt*64)*4096 + sp*512, 4096,
         g  + ((size_t)(b*8+h)*64)*2048 + n0b, 2048, 8, as, bs, acc);
  int tid=threadIdx.x, w=tid>>6, lane=tid&63, lg=lane>>4, ln=lane&15;
  int row=w*16+lg*4;
  #pragma unroll
  for(int nb=0;nb<4;nb++)
    #pragma unroll
    for(int r=0;r<4;r++)
      par[(size_t)sp*262144 + (size_t)h*32768 + (size_t)(dt*64+row+r)*64 + nb*16+ln]=acc[nb][r];
}

__global__ __launch_bounds__(256) void k_gemm_wgo(const short* __restrict__ outt,
    const short* __restrict__ ert, float* __restrict__ par){
  __shared__ __attribute__((aligned(16))) short as[64][LBK], bs[64][LBK];
  int ct=blockIdx.x, h=blockIdx.y, sp=blockIdx.z;
  f32x4 acc[4];
  #pragma unroll
  for(int nb=0;nb<4;nb++) acc[nb]=(f32x4){0.f,0.f,0.f,0.f};
  gemm64(outt + (size_t)(h*64)*4096 + sp*512, 4096,
         ert  + (size_t)(ct*64)*4096 + sp*512, 4096, 8, as, bs, acc);
  int tid=threadIdx.x, w=tid>>6, lane=tid&63, lg=lane>>4, ln=lane&15;
  int row=w*16+lg*4;
  #pragma unroll
  for(int nb=0;nb<4;nb++)
    #pragma unroll
    for(int r=0;r<4;r++)
      par[(size_t)sp*262144 + (size_t)h*32768 + (size_t)(row+r)*512 + ct*64+nb*16+ln]=acc[nb][r];
}

__global__ __launch_bounds__(256) void k_wred_direct(const float* __restrict__ par,
    float* __restrict__ dst){
  int idx = blockIdx.x*256 + threadIdx.x;
  float s=0.f;
  #pragma unroll
  for(int sp=0;sp<8;sp++) s += par[(size_t)sp*262144 + idx];
  dst[idx]=s;
}
__global__ __launch_bounds__(256) void k_wred_xv(const float* __restrict__ par,
    float* __restrict__ X0){
  int idx = blockIdx.x*256 + threadIdx.x;
  float s=0.f;
  #pragma unroll
  for(int sp=0;sp<8;sp++) s += par[(size_t)sp*262144 + idx];
  int h=idx>>15, rem=idx&32767, d=rem>>6, e=rem&63;
  X0[(size_t)h*32768 + (size_t)e*512 + d]=s;
}
__global__ __launch_bounds__(256) void k_wred_xo(const float* __restrict__ par,
    float* __restrict__ X0){
  int idx = blockIdx.x*256 + threadIdx.x;
  float s=0.f;
  #pragma unroll
  for(int sp=0;sp<8;sp++) s += par[(size_t)sp*262144 + idx];
  X0[262144 + idx]=s;
}

// ---------------- 14. Newton-Schulz (f32) ----------------
#define LP 66
__global__ __launch_bounds__(256) void k_ns_scale(float* __restrict__ X){
  float* Xm = X + (size_t)blockIdx.x*32768;
  int tid=threadIdx.x;
  float ss=0.f;
  for(int i=tid;i<32768;i+=256){ float v=Xm[i]; ss+=v*v; }
  ss=wred64(ss);
  __shared__ float r[4];
  if((tid&63)==0) r[tid>>6]=ss;
  __syncthreads();
  float tot=r[0]+r[1]+r[2]+r[3];
  float sc = 1.f/fmaxf(sqrtf(tot), 1e-7f);
  for(int i=tid;i<32768;i+=256) Xm[i]*=sc;
}
__global__ __launch_bounds__(256) void k_ns_A(const float* __restrict__ X,
    float* __restrict__ A){
  const float* Xm = X + (size_t)blockIdx.x*32768;
  __shared__ float xs[64][LP];
  int tid=threadIdx.x, ty=tid>>4, tx=tid&15;
  float acc[4][4]={{0}};
  for(int d0=0;d0<512;d0+=64){
    __syncthreads();
    for(int kk=0;kk<16;kk++){
      int idx=kk*256+tid; int rr=idx>>6, cc=idx&63;
      xs[rr][cc]=Xm[(size_t)rr*512 + d0+cc];
    }
    __syncthreads();
    for(int kk=0;kk<64;kk++){
      float a[4], bb[4];
      #pragma unroll
      for(int r=0;r<4;r++) a[r]=xs[ty*4+r][kk];
      #pragma unroll
      for(int c=0;c<4;c++) bb[c]=xs[tx+16*c][kk];
      #pragma unroll
      for(int r=0;r<4;r++)
        #pragma unroll
        for(int c=0;c<4;c++) acc[r][c]+=a[r]*bb[c];
    }
  }
  #pragma unroll
  for(int r=0;r<4;r++)
    #pragma unroll
    for(int c=0;c<4;c++)
      A[(size_t)blockIdx.x*4096 + (size_t)(ty*4+r)*64 + tx+16*c]=acc[r][c];
}
__global__ __launch_bounds__(256) void k_ns_B(const float* __restrict__ A,
    float* __restrict__ Bm){
  __shared__ float as[64][LP];
  int tid=threadIdx.x, ty=tid>>4, tx=tid&15;
  for(int kk=0;kk<16;kk++){
    int idx=kk*256+tid; int rr=idx>>6, cc=idx&63;
    as[rr][cc]=A[(size_t)blockIdx.x*4096 + rr*64 + cc];
  }
  __syncthreads();
  float acc[4][4]={{0}};
  for(int kk=0;kk<64;kk++){
    float a[4], bb[4];
    #pragma unroll
    for(int r=0;r<4;r++) a[r]=as[ty*4+r][kk];
    #pragma unroll
    for(int c=0;c<4;c++) bb[c]=as[kk][tx+16*c];
    #pragma unroll
    for(int r=0;r<4;r++)
      #pragma unroll
      for(int c=0;c<4;c++) acc[r][c]+=a[r]*bb[c];
  }
  #pragma unroll
  for(int r=0;r<4;r++)
    #pragma unroll
    for(int c=0;c<4;c++)
      Bm[(size_t)blockIdx.x*4096 + (size_t)(ty*4+r)*64 + tx+16*c]
        = -4.775f*as[ty*4+r][tx+16*c] + 2.0315f*acc[r][c];
}
__global__ __launch_bounds__(256) void k_ns_update(const float* __restrict__ Xold,
    const float* __restrict__ Bm, float* __restrict__ Xnew){
  int ct=blockIdx.x, m=blockIdx.y;
  __shared__ float bs[64][LP], xs[64][LP];
  int tid=threadIdx.x, ty=tid>>4, tx=tid&15;
  for(int kk=0;kk<16;kk++){
    int idx=kk*256+tid; int rr=idx>>6, cc=idx&63;
    bs[rr][cc]=Bm[(size_t)m*4096 + rr*64 + cc];
    xs[rr][cc]=Xold[(size_t)m*32768 + (size_t)rr*512 + ct*64+cc];
  }
  __syncthreads();
  float acc[4][4]={{0}};
  for(int kk=0;kk<64;kk++){
    float a[4], bb[4];
    #pragma unroll
    for(int r=0;r<4;r++) a[r]=bs[ty*4+r][kk];
    #pragma unroll
    for(int c=0;c<4;c++) bb[c]=xs[kk][tx+16*c];
    #pragma unroll
    for(int r=0;r<4;r++)
      #pragma unroll
      for(int c=0;c<4;c++) acc[r][c]+=a[r]*bb[c];
  }
  #pragma unroll
  for(int r=0;r<4;r++)
    #pragma unroll
    for(int c=0;c<4;c++)
      Xnew[(size_t)m*32768 + (size_t)(ty*4+r)*512 + ct*64+tx+16*c]
        = 3.4445f*xs[ty*4+r][tx+16*c] + acc[r][c];
}
__global__ __launch_bounds__(256) void k_ns_final(const float* __restrict__ X,
    float* __restrict__ dwv, float* __restrict__ dwo){
  int idx = blockIdx.x*256 + threadIdx.x;
  int m = idx>>15, rem = idx&32767, e = rem>>9, d = rem&511;
  float v = X[idx];
  if(m<8) dwv[(size_t)m*32768 + (size_t)d*64 + e] = v;
  else    dwo[(size_t)(m-8)*32768 + (size_t)e*512 + d] = v;
}

// ---------------- launch ----------------
extern "C" void kernel_launch(void* const* d_in, const int* in_sizes, int n_in,
                              void* d_out, int out_size, void* d_ws, size_t ws_size,
                              hipStream_t stream) {
  const float* tokens=(const float*)d_in[0];
  const float* rmsw =(const float*)d_in[1];
  const float* wq   =(const float*)d_in[2];
  const float* wk   =(const float*)d_in[3];
  const float* wv   =(const float*)d_in[4];
  const float* wo   =(const float*)d_in[5];
  const float* lrw  =(const float*)d_in[6];
  const float* tvw  =(const float*)d_in[7];
  float* out = (float*)d_out;
  float* ws  = (float*)d_ws;

  short* tb   = (short*)(ws);            // [4160][512] bf16 (pad rows zero)
  short* tt   = (short*)(ws + 1064960);  // [512][4096]
  short* qh   = (short*)(ws + 2113536);  // [16bh][2048][64]
  short* kh   = (short*)(ws + 3162112);
  short* vh   = (short*)(ws + 4210688);
  short* qt   = (short*)(ws + 5259264);  // [16bh][64][2048]
  short* kt   = (short*)(ws + 6307840);
  short* vt   = (short*)(ws + 7356416);
  float* ob_  = ws + 8404992;            // f32 [4096][512]; er_ aliases after trans
  float* er_  = ws + 8404992;
  short* obb  = (short*)(ws + 10502144); // bf16 [4096][512]
  short* outt = (short*)(ws + 11550720); // bf16 [512][4096]
  short* erb  = (short*)(ws + 12599296);
  short* ert  = (short*)(ws + 13647872);
  short* doh  = (short*)(ws + 14696448); // [16bh][2048][64]
  short* dot  = (short*)(ws + 15745024); // [16bh][64][2048]
  float* par_ = ws + 14696448;           // aliases doh+dot (dead before wgrad)
  short* dqt  = (short*)(ws + 16793600); // [16bh][64][2048]
  short* dkt  = (short*)(ws + 17842176);
  short* dvt  = (short*)(ws + 18890752);
  short* wqt  = (short*)(ws + 19939328); // [8h][64][512]
  short* wkt  = (short*)(ws + 20070400);
  short* wvt  = (short*)(ws + 20201472);
  short* wob  = (short*)(ws + 20332544); // [512 he][512 d]
  short* wot  = (short*)(ws + 20463616); // [512 d][512 he]
  short* tvwb = (short*)(ws + 20594688); // [512 o][512 d]
  float* lse_ = ws + 20725760;
  float* dlt_ = ws + 20758528;
  float* X0_  = ws + 20791296;
  float* X1_  = ws + 21315584;
  float* Am_  = ws + 21839872;
  float* Bm_  = ws + 21905408;

  float* OUT_PRED = out;
  float* OUT_DWQ  = out + 2097152;
  float* OUT_DWK  = out + 2359296;
  float* OUT_DWV  = out + 2621440;
  float* OUT_DWO  = out + 2883584;

  k_rmsnorm<<<4160,256,0,stream>>>(tokens, rmsw, tb);
  k_wprep<<<272,256,0,stream>>>(wq,wk,wv,wo,tvw, wqt,wkt,wvt,wob,wot,tvwb);
  k_gemm_qkv<<<dim3(64,24),256,0,stream>>>(tb, wqt,wkt,wvt, qh,kh,vh, qt,kt,vt);
  k_fa_fwd<<<dim3(16,32),256,0,stream>>>(qh, kh, vt, ob_, lse_);
  k_trans_f<<<dim3(64,8),256,0,stream>>>(ob_, obb, outt);
  k_gemm_pred<<<dim3(64,8),256,0,stream>>>(obb, wot, OUT_PRED);

  if(out_size < 3145728) return;   // forward-only variant

  k_trans_b<<<dim3(64,8),256,0,stream>>>(tb, tt);
  k_gemm_tv<<<dim3(64,8),256,0,stream>>>(tb, tvwb, er_);
  k_lnerr<<<4094,256,0,stream>>>(er_, tb, OUT_PRED, lrw);
  k_trans_f<<<dim3(64,8),256,0,stream>>>(er_, erb, ert);
  k_gemm_dout<<<dim3(64,8),256,0,stream>>>(erb, wob, doh, dot);
  k_delta<<<8188,256,0,stream>>>(doh, obb, dlt_);
  k_fa_dq<<<dim3(16,32),256,0,stream>>>(qh, kh, vh, kt, doh, lse_, dlt_, dqt);
  k_fa_dkv<<<dim3(16,32),256,0,stream>>>(kh, vh, qh, qt, doh, dot, lse_, dlt_, dkt, dvt);

  k_gemm_wgq<<<dim3(8,8,8),256,0,stream>>>(tt, dqt, par_);
  k_wred_direct<<<1024,256,0,stream>>>(par_, OUT_DWQ);
  k_gemm_wgq<<<dim3(8,8,8),256,0,stream>>>(tt, dkt, par_);
  k_wred_direct<<<1024,256,0,stream>>>(par_, OUT_DWK);
  k_gemm_wgq<<<dim3(8,8,8),256,0,stream>>>(tt, dvt, par_);
  k_wred_xv<<<1024,256,0,stream>>>(par_, X0_);
  k_gemm_wgo<<<dim3(8,8,8),256,0,stream>>>(outt, ert, par_);
  k_wred_xo<<<1024,256,0,stream>>>(par_, X0_);

  k_ns_scale<<<16,256,0,stream>>>(X0_);
  float* xa = X0_; float* xb = X1_;
  for(int itr=0; itr<5; ++itr){
    k_ns_A<<<16,256,0,stream>>>(xa, Am_);
    k_ns_B<<<16,256,0,stream>>>(Am_, Bm_);
    k_ns_update<<<dim3(8,16),256,0,stream>>>(xa, Bm_, xb);
    float* tmp = xa; xa = xb; xb = tmp;
  }
  k_ns_final<<<2048,256,0,stream>>>(xa, OUT_DWV, OUT_DWO);
}

// Round 6
// 521.096 us; speedup vs baseline: 5.3677x; 1.0652x over previous
//
#include <hip/hip_runtime.h>
#include <float.h>
#include <math.h>

// ---------------- problem constants ----------------
#define B_   2
#define N_   2048
#define D_   512
#define H_   8
#define DH_  64
#define NM_  2047            // n-1
#define SCALE_F 0.125f       // 64^-0.5
#define LBK 72               // LDS row pad (bf16 tiles), 144B: 16B-aligned rows

typedef __attribute__((ext_vector_type(8))) short bf16x8;
typedef __attribute__((ext_vector_type(4))) float f32x4;
#define MFMA_B16(a,b,c) __builtin_amdgcn_mfma_f32_16x16x32_bf16(a,b,c,0,0,0)

__device__ __forceinline__ short f2bf(float f){
  unsigned u = __float_as_uint(f);
  unsigned r = u + 0x7fffu + ((u>>16)&1u);
  return (short)(r>>16);
}
__device__ __forceinline__ float bf2f(short s){
  return __uint_as_float(((unsigned)(unsigned short)s)<<16);
}
__device__ __forceinline__ void lds_fence(){
  asm volatile("s_waitcnt lgkmcnt(0)" ::: "memory");
  __builtin_amdgcn_sched_barrier(0);
}
// load a 64x64 bf16 tile into regs (2 int4 per thread); pairs with twrite
__device__ __forceinline__ void tload(const short* __restrict__ src, size_t stride,
                                      int tid, int4& r0, int4& r1){
  int rr = tid>>2, cc = (tid&3)<<4;
  r0 = *(const int4*)&src[(size_t)rr*stride + cc];
  r1 = *(const int4*)&src[(size_t)rr*stride + cc + 8];
}
__device__ __forceinline__ void twrite(short (*dst)[LBK], int tid,
                                       const int4& r0, const int4& r1){
  int rr = tid>>2, cc = (tid&3)<<4;
  *(int4*)&dst[rr][cc]   = r0;
  *(int4*)&dst[rr][cc+8] = r1;
}
__device__ __forceinline__ float wred64(float v){
  #pragma unroll
  for(int off=32; off; off>>=1) v += __shfl_down(v, off, 64);
  return v;
}

// 64x64 MFMA GEMM mainloop with register-prefetch double buffering (2-phase):
// loads for tile kt+1 issue before compute of tile kt.
__device__ __forceinline__ void gemm64(const short* __restrict__ A, size_t lda,
    const short* __restrict__ Bt, size_t ldb, int nk,
    short (*as)[LBK], short (*bs)[LBK], f32x4* acc){
  int tid=threadIdx.x, w=tid>>6, lane=tid&63, lg=lane>>4, ln=lane&15;
  int4 a0,a1,b0,b1;
  tload(A, lda, tid, a0,a1);
  tload(Bt, ldb, tid, b0,b1);
  for(int kt=0;kt<nk;++kt){
    __syncthreads();
    twrite(as, tid, a0,a1);
    twrite(bs, tid, b0,b1);
    if(kt+1<nk){
      tload(A +(size_t)(kt+1)*64, lda, tid, a0,a1);
      tload(Bt+(size_t)(kt+1)*64, ldb, tid, b0,b1);
    }
    __syncthreads();
    #pragma unroll
    for(int s=0;s<2;s++){
      bf16x8 a = *(const bf16x8*)&as[w*16+ln][32*s+lg*8];
      #pragma unroll
      for(int nb=0;nb<4;nb++){
        bf16x8 b = *(const bf16x8*)&bs[nb*16+ln][32*s+lg*8];
        acc[nb]=MFMA_B16(a,b,acc[nb]);
      }
    }
  }
}

// ---------------- 1. RMSNorm -> tb (bf16, padded to 4160 rows) ----------------
__global__ __launch_bounds__(256) void k_rmsnorm(const float* __restrict__ tok,
    const float* __restrict__ w, short* __restrict__ tb){
  int row = blockIdx.x;
  int tid = threadIdx.x;
  if(row>=4096){ tb[(size_t)row*D_+tid]=0; tb[(size_t)row*D_+tid+256]=0; return; }
  const float* x = tok + (size_t)row*D_;
  float v0 = x[tid], v1 = x[tid+256];
  float s = v0*v0 + v1*v1;
  s = wred64(s);
  __shared__ float red[4];
  if((tid&63)==0) red[tid>>6] = s;
  __syncthreads();
  float tot = red[0]+red[1]+red[2]+red[3];
  float sc = rsqrtf(tot*(1.f/512.f) + 1.1920929e-7f);
  tb[(size_t)row*D_+tid]     = f2bf(v0*sc*w[tid]);
  tb[(size_t)row*D_+tid+256] = f2bf(v1*sc*w[tid+256]);
}

// ---------------- 2. weight prep ----------------
__global__ __launch_bounds__(256) void k_wprep(const float* __restrict__ wq,
    const float* __restrict__ wk, const float* __restrict__ wv,
    const float* __restrict__ wo, const float* __restrict__ tvw,
    short* __restrict__ wqt, short* __restrict__ wkt, short* __restrict__ wvt,
    short* __restrict__ wob, short* __restrict__ wot, short* __restrict__ tvwb){
  __shared__ short l[64][66];
  int bx=blockIdx.x, tid=threadIdx.x;
  if(bx<192){
    const float* w = (bx<64)? wq : (bx<128)? wk : wv;
    short* wt      = (bx<64)? wqt: (bx<128)? wkt: wvt;
    int lb=bx&63, h=lb>>3, d0=(lb&7)*64;
    for(int kk=0;kk<16;kk++){
      int idx=kk*256+tid, rr=idx>>6, cc=idx&63;
      l[cc][rr] = f2bf(w[((size_t)h*512 + d0+rr)*64 + cc]);
    }
    __syncthreads();
    for(int kk=0;kk<16;kk++){
      int idx=kk*256+tid, rr=idx>>6, cc=idx&63;
      wt[((size_t)h*64+rr)*512 + d0+cc] = l[rr][cc];
    }
  } else if(bx<256){
    int lb=bx-192, r0=(lb>>3)*64, c0=(lb&7)*64;
    for(int kk=0;kk<16;kk++){
      int idx=kk*256+tid, rr=idx>>6, cc=idx&63;
      l[cc][rr] = f2bf(wo[(size_t)(r0+rr)*512 + c0+cc]);
    }
    __syncthreads();
    for(int kk=0;kk<16;kk++){
      int idx=kk*256+tid, rr=idx>>6, cc=idx&63;
      wot[(size_t)(c0+rr)*512 + r0+cc] = l[rr][cc];
    }
  } else if(bx<264){
    size_t base=(size_t)(bx-256)*32768;
    for(int kk=0;kk<128;kk++) wob[base+kk*256+tid]=f2bf(wo[base+kk*256+tid]);
  } else {
    size_t base=(size_t)(bx-264)*32768;
    for(int kk=0;kk<128;kk++) tvwb[base+kk*256+tid]=f2bf(tvw[base+kk*256+tid]);
  }
}

// ---------------- 3. transposes (4096x512) ----------------
__global__ __launch_bounds__(256) void k_trans_b(const short* __restrict__ in,
    short* __restrict__ outt){
  __shared__ short l[64][66];
  int r0=blockIdx.x<<6, c0=blockIdx.y<<6, tid=threadIdx.x;
  for(int kk=0;kk<16;kk++){
    int idx=kk*256+tid, rr=idx>>6, cc=idx&63;
    l[cc][rr]=in[(size_t)(r0+rr)*512 + c0+cc];
  }
  __syncthreads();
  for(int kk=0;kk<16;kk++){
    int idx=kk*256+tid, rr=idx>>6, cc=idx&63;
    outt[(size_t)(c0+rr)*4096 + r0+cc]=l[rr][cc];
  }
}
__global__ __launch_bounds__(256) void k_trans_f(const float* __restrict__ in,
    short* __restrict__ outn, short* __restrict__ outt){
  __shared__ short l[64][66];
  int r0=blockIdx.x<<6, c0=blockIdx.y<<6, tid=threadIdx.x;
  for(int kk=0;kk<16;kk++){
    int idx=kk*256+tid, rr=idx>>6, cc=idx&63;
    short v=f2bf(in[(size_t)(r0+rr)*512 + c0+cc]);
    outn[(size_t)(r0+rr)*512 + c0+cc]=v;
    l[cc][rr]=v;
  }
  __syncthreads();
  for(int kk=0;kk<16;kk++){
    int idx=kk*256+tid, rr=idx>>6, cc=idx&63;
    outt[(size_t)(c0+rr)*4096 + r0+cc]=l[rr][cc];
  }
}

// ---------------- 4. QKV projection (MFMA) ----------------
__global__ __launch_bounds__(256) void k_gemm_qkv(const short* __restrict__ tb,
    const short* __restrict__ wqt, const short* __restrict__ wkt, const short* __restrict__ wvt,
    short* __restrict__ qh, short* __restrict__ kh, short* __restrict__ vh,
    short* __restrict__ qt, short* __restrict__ kt, short* __restrict__ vt){
  __shared__ __attribute__((aligned(16))) short as[64][LBK], bs[64][LBK];
  int r0=blockIdx.x<<6, ct=blockIdx.y, which=ct>>3, h=ct&7;
  const short* Bt=(which==0?wqt:which==1?wkt:wvt)+(size_t)h*32768;
  f32x4 acc[4];
  #pragma unroll
  for(int nb=0;nb<4;nb++) acc[nb]=(f32x4){0.f,0.f,0.f,0.f};
  gemm64(tb+(size_t)r0*512, 512, Bt, 512, 8, as, bs, acc);
  short* on=(which==0?qh:which==1?kh:vh);
  short* ot=(which==0?qt:which==1?kt:vt);
  int tid=threadIdx.x, w=tid>>6, lane=tid&63, lg=lane>>4, ln=lane&15;
  size_t bh=(size_t)(r0>>11)*8+h;
  int n0=(r0&2047)+w*16+lg*4;
  #pragma unroll
  for(int nb=0;nb<4;nb++){
    int e=nb*16+ln;
    short4 s4;
    s4.x=f2bf(acc[nb][0]); s4.y=f2bf(acc[nb][1]);
    s4.z=f2bf(acc[nb][2]); s4.w=f2bf(acc[nb][3]);
    on[(bh*2048+n0  )*64+e]=s4.x;
    on[(bh*2048+n0+1)*64+e]=s4.y;
    on[(bh*2048+n0+2)*64+e]=s4.z;
    on[(bh*2048+n0+3)*64+e]=s4.w;
    *(short4*)&ot[(bh*64+e)*2048+n0]=s4;
  }
}

// ---------------- 5. flash attention forward (prefetch + bf16 P) ----------------
__global__ __launch_bounds__(256) void k_fa_fwd(const short* __restrict__ qh,
    const short* __restrict__ kh, const short* __restrict__ vt,
    float* __restrict__ outb, float* __restrict__ lse){
  int bh = blockIdx.x, qq = blockIdx.y;
  int it = (qq<16)? (31-qq) : (qq-16);
  int b = bh>>3, h = bh&7;
  int i0 = it<<6;
  const short* qhb = qh + (size_t)bh*N_*DH_;
  const short* khb = kh + (size_t)bh*N_*DH_;
  const short* vtb = vt + (size_t)bh*DH_*N_;
  __shared__ __attribute__((aligned(16))) short ks[64][LBK], vts[64][LBK];
  __shared__ __attribute__((aligned(16))) short psb[4][16][LBK];
  int tid=threadIdx.x, w=tid>>6, lane=tid&63, lg=lane>>4, ln=lane&15;
  bf16x8 aq[2];
  #pragma unroll
  for(int s=0;s<2;s++)
    aq[s] = *(const bf16x8*)&qhb[(size_t)(i0+w*16+ln)*DH_ + 32*s + lg*8];
  f32x4 acc[4];
  float mrow[4], lrow[4];
  #pragma unroll
  for(int nb=0;nb<4;nb++) acc[nb]=(f32x4){0.f,0.f,0.f,0.f};
  #pragma unroll
  for(int r=0;r<4;r++){ mrow[r]=-FLT_MAX; lrow[r]=0.f; }
  int4 ka0,ka1,va0,va1;
  tload(khb, DH_, tid, ka0,ka1);
  tload(vtb, N_, tid, va0,va1);
  for(int jt=0;jt<=it;++jt){
    int j0 = jt<<6;
    __syncthreads();
    twrite(ks, tid, ka0,ka1);
    twrite(vts, tid, va0,va1);
    if(jt<it){
      tload(khb+(size_t)(jt+1)*64*DH_, DH_, tid, ka0,ka1);
      tload(vtb+(jt+1)*64, N_, tid, va0,va1);
    }
    __syncthreads();
    f32x4 sv[4];
    #pragma unroll
    for(int nb=0;nb<4;nb++){
      f32x4 z = {0.f,0.f,0.f,0.f};
      #pragma unroll
      for(int s=0;s<2;s++){
        bf16x8 bk = *(const bf16x8*)&ks[nb*16+ln][32*s + lg*8];
        z = MFMA_B16(aq[s], bk, z);
      }
      sv[nb]=z;
    }
    int iiB = i0 + w*16 + lg*4;
    #pragma unroll
    for(int r=0;r<4;r++){
      int ii = iiB + r;
      float srow[4]; float mx = -FLT_MAX;
      #pragma unroll
      for(int nb=0;nb<4;nb++){
        float x = sv[nb][r]*SCALE_F;
        if(j0+nb*16+ln > ii) x = -FLT_MAX;
        srow[nb]=x; mx=fmaxf(mx,x);
      }
      mx=fmaxf(mx,__shfl_xor(mx,1)); mx=fmaxf(mx,__shfl_xor(mx,2));
      mx=fmaxf(mx,__shfl_xor(mx,4)); mx=fmaxf(mx,__shfl_xor(mx,8));
      float mn = fmaxf(mrow[r], mx);
      float rs = 0.f;
      #pragma unroll
      for(int nb=0;nb<4;nb++){
        float pv = __expf(srow[nb]-mn);
        psb[w][lg*4+r][ln+16*nb]=f2bf(pv); rs+=pv;
      }
      rs+=__shfl_xor(rs,1); rs+=__shfl_xor(rs,2);
      rs+=__shfl_xor(rs,4); rs+=__shfl_xor(rs,8);
      float corr = __expf(mrow[r]-mn);
      lrow[r]=lrow[r]*corr+rs; mrow[r]=mn;
      #pragma unroll
      for(int nb=0;nb<4;nb++) acc[nb][r]*=corr;
    }
    lds_fence();
    #pragma unroll
    for(int nb=0;nb<4;nb++){
      #pragma unroll
      for(int s=0;s<2;s++){
        bf16x8 pa = *(const bf16x8*)&psb[w][ln][32*s + lg*8];
        bf16x8 bv = *(const bf16x8*)&vts[nb*16+ln][32*s + lg*8];
        acc[nb] = MFMA_B16(pa, bv, acc[nb]);
      }
    }
    lds_fence();
  }
  #pragma unroll
  for(int r=0;r<4;r++){
    int ii = i0 + w*16 + lg*4 + r;
    float inv = 1.f/lrow[r];
    #pragma unroll
    for(int nb=0;nb<4;nb++)
      outb[((size_t)(b*N_+ii))*D_ + h*DH_ + nb*16+ln] = acc[nb][r]*inv;
    if(ln==0) lse[(size_t)bh*N_ + ii] = mrow[r] + logf(lrow[r]);
  }
}

// ---------------- 6. pred = obb @ wot^T (MFMA), f32 out ----------------
__global__ __launch_bounds__(256) void k_gemm_pred(const short* __restrict__ obb,
    const short* __restrict__ wot, float* __restrict__ pred){
  __shared__ __attribute__((aligned(16))) short as[64][LBK], bs[64][LBK];
  int r0=blockIdx.x<<6, c0=blockIdx.y<<6;
  f32x4 acc[4];
  #pragma unroll
  for(int nb=0;nb<4;nb++) acc[nb]=(f32x4){0.f,0.f,0.f,0.f};
  gemm64(obb+(size_t)r0*512, 512, wot+(size_t)c0*512, 512, 8, as, bs, acc);
  int tid=threadIdx.x, w=tid>>6, lane=tid&63, lg=lane>>4, ln=lane&15;
  int row=r0+w*16+lg*4;
  #pragma unroll
  for(int nb=0;nb<4;nb++)
    #pragma unroll
    for(int r=0;r<4;r++)
      pred[(size_t)(row+r)*512 + c0+nb*16+ln]=acc[nb][r];
}

// ---------------- 7. tv = tb(shift+1) @ tvwb^T ----------------
__global__ __launch_bounds__(256) void k_gemm_tv(const short* __restrict__ tb,
    const short* __restrict__ tvwb, float* __restrict__ er){
  __shared__ __attribute__((aligned(16))) short as[64][LBK], bs[64][LBK];
  int r0=blockIdx.x<<6, c0=blockIdx.y<<6;
  f32x4 acc[4];
  #pragma unroll
  for(int nb=0;nb<4;nb++) acc[nb]=(f32x4){0.f,0.f,0.f,0.f};
  gemm64(tb+(size_t)(r0+1)*512, 512, tvwb+(size_t)c0*512, 512, 8, as, bs, acc);
  int tid=threadIdx.x, w=tid>>6, lane=tid&63, lg=lane>>4, ln=lane&15;
  int row=r0+w*16+lg*4;
  #pragma unroll
  for(int nb=0;nb<4;nb++)
    #pragma unroll
    for(int r=0;r<4;r++){
      float v=(((row+r)&2047)==2047)?0.f:acc[nb][r];
      er[(size_t)(row+r)*512 + c0+nb*16+ln]=v;
    }
}

// ---------------- 8. layernorm target + lr + error ----------------
__global__ __launch_bounds__(256) void k_lnerr(float* __restrict__ er,
    const short* __restrict__ tb, const float* __restrict__ pred,
    const float* __restrict__ lrw){
  int kr = blockIdx.x;
  int b = kr/NM_, n = kr-b*NM_;
  size_t row=(size_t)b*2048+n;
  float* tv = er + row*512;
  const short* tok = tb + row*512;
  const float* pr  = pred + row*512;
  int tid=threadIdx.x;
  float v0=tv[tid], v1=tv[tid+256];
  float s1=v0+v1, s2=v0*v0+v1*v1;
  float s3=bf2f(tok[tid])*lrw[tid] + bf2f(tok[tid+256])*lrw[tid+256];
  s1=wred64(s1); s2=wred64(s2); s3=wred64(s3);
  __shared__ float r1[4],r2[4],r3[4];
  if((tid&63)==0){ int w=tid>>6; r1[w]=s1; r2[w]=s2; r3[w]=s3; }
  __syncthreads();
  float S1=r1[0]+r1[1]+r1[2]+r1[3];
  float S2=r2[0]+r2[1]+r2[2]+r2[3];
  float S3=r3[0]+r3[1]+r3[2]+r3[3];
  float mu  = S1*(1.f/512.f);
  float var = S2*(1.f/512.f) - mu*mu;
  float rstd= rsqrtf(var + 1e-5f);
  float lr  = 0.01f/(1.f+__expf(-S3));
  tv[tid]     = ((v0-mu)*rstd - pr[tid])*lr;
  tv[tid+256] = ((v1-mu)*rstd - pr[tid+256])*lr;
}

// ---------------- 9. dout = erb @ wob^T (MFMA) -> doh + dot bf16 ----------------
__global__ __launch_bounds__(256) void k_gemm_dout(const short* __restrict__ erb,
    const short* __restrict__ wob, short* __restrict__ doh, short* __restrict__ dot){
  __shared__ __attribute__((aligned(16))) short as[64][LBK], bs[64][LBK];
  int r0=blockIdx.x<<6, h=blockIdx.y;
  f32x4 acc[4];
  #pragma unroll
  for(int nb=0;nb<4;nb++) acc[nb]=(f32x4){0.f,0.f,0.f,0.f};
  gemm64(erb+(size_t)r0*512, 512, wob+(size_t)h*32768, 512, 8, as, bs, acc);
  int tid=threadIdx.x, w=tid>>6, lane=tid&63, lg=lane>>4, ln=lane&15;
  size_t bh=(size_t)(r0>>11)*8+h;
  int n0=(r0&2047)+w*16+lg*4;
  #pragma unroll
  for(int nb=0;nb<4;nb++){
    int e=nb*16+ln;
    short4 s4;
    s4.x=f2bf(acc[nb][0]); s4.y=f2bf(acc[nb][1]);
    s4.z=f2bf(acc[nb][2]); s4.w=f2bf(acc[nb][3]);
    doh[(bh*2048+n0  )*64+e]=s4.x;
    doh[(bh*2048+n0+1)*64+e]=s4.y;
    doh[(bh*2048+n0+2)*64+e]=s4.z;
    doh[(bh*2048+n0+3)*64+e]=s4.w;
    *(short4*)&dot[(bh*64+e)*2048+n0]=s4;
  }
}

// ---------------- 10. delta = sum_e dout*out ----------------
__global__ __launch_bounds__(256) void k_delta(const short* __restrict__ doh,
    const short* __restrict__ obb, float* __restrict__ delta){
  int rid = blockIdx.x*4 + (threadIdx.x>>6);
  int lane = threadIdx.x&63;
  if(rid >= B_*H_*NM_) return;
  int b = rid/(H_*NM_); int rem = rid - b*H_*NM_;
  int h = rem/NM_; int i = rem - h*NM_;
  float v = bf2f(doh[((size_t)(b*H_+h)*N_ + i)*DH_ + lane])
          * bf2f(obb[((size_t)(b*N_+i))*D_ + h*DH_ + lane]);
  v = wred64(v);
  if(lane==0) delta[((size_t)(b*H_+h))*N_ + i] = v;
}

// ---------------- 11. flash backward dq (prefetch + bf16 dS) -> dqt bf16 ----------------
__global__ __launch_bounds__(256) void k_fa_dq(const short* __restrict__ qh,
    const short* __restrict__ kh, const short* __restrict__ vh,
    const short* __restrict__ kt, const short* __restrict__ doh,
    const float* __restrict__ lse, const float* __restrict__ delta,
    short* __restrict__ dqt){
  int bh = blockIdx.x, qq = blockIdx.y;
  int it = (qq<16)? (31-qq) : (qq-16);
  int i0 = it<<6;
  const short* qhb = qh + (size_t)bh*N_*DH_;
  const short* khb = kh + (size_t)bh*N_*DH_;
  const short* vhb = vh + (size_t)bh*N_*DH_;
  const short* ktb = kt + (size_t)bh*DH_*N_;
  const short* dohb= doh+ (size_t)bh*N_*DH_;
  __shared__ __attribute__((aligned(16))) short ks[64][LBK], vs[64][LBK], kts[64][LBK];
  __shared__ __attribute__((aligned(16))) short psb[4][16][LBK];
  int tid=threadIdx.x, w=tid>>6, lane=tid&63, lg=lane>>4, ln=lane&15;
  bf16x8 aq[2], ad[2];
  float Lr[4], dl[4];
  #pragma unroll
  for(int s=0;s<2;s++){
    aq[s]=*(const bf16x8*)&qhb[(size_t)(i0+w*16+ln)*DH_+32*s+lg*8];
    ad[s]=*(const bf16x8*)&dohb[(size_t)(i0+w*16+ln)*DH_+32*s+lg*8];
  }
  #pragma unroll
  for(int r=0;r<4;r++){
    int ii=i0+w*16+lg*4+r;
    Lr[r]=lse[(size_t)bh*N_+ii];
    dl[r]=(ii<NM_)?delta[(size_t)bh*N_+ii]:0.f;
  }
  f32x4 acc[4];
  #pragma unroll
  for(int nb=0;nb<4;nb++) acc[nb]=(f32x4){0.f,0.f,0.f,0.f};
  int4 ka0,ka1,va0,va1,ta0,ta1;
  tload(khb, DH_, tid, ka0,ka1);
  tload(vhb, DH_, tid, va0,va1);
  tload(ktb, N_, tid, ta0,ta1);
  for(int jt=0;jt<=it;++jt){
    int j0=jt<<6;
    __syncthreads();
    twrite(ks, tid, ka0,ka1);
    twrite(vs, tid, va0,va1);
    twrite(kts, tid, ta0,ta1);
    if(jt<it){
      tload(khb+(size_t)(jt+1)*64*DH_, DH_, tid, ka0,ka1);
      tload(vhb+(size_t)(jt+1)*64*DH_, DH_, tid, va0,va1);
      tload(ktb+(jt+1)*64, N_, tid, ta0,ta1);
    }
    __syncthreads();
    f32x4 sv[4], dav[4];
    #pragma unroll
    for(int nb=0;nb<4;nb++){
      f32x4 z={0.f,0.f,0.f,0.f}, zd={0.f,0.f,0.f,0.f};
      #pragma unroll
      for(int s=0;s<2;s++){
        bf16x8 bk=*(const bf16x8*)&ks[nb*16+ln][32*s+lg*8];
        bf16x8 bv=*(const bf16x8*)&vs[nb*16+ln][32*s+lg*8];
        z = MFMA_B16(aq[s], bk, z);
        zd= MFMA_B16(ad[s], bv, zd);
      }
      sv[nb]=z; dav[nb]=zd;
    }
    #pragma unroll
    for(int r=0;r<4;r++){
      int ii=i0+w*16+lg*4+r;
      #pragma unroll
      for(int nb=0;nb<4;nb++){
        int jj=j0+nb*16+ln;
        float pv=__expf(sv[nb][r]*SCALE_F - Lr[r]);
        float dsv=SCALE_F*pv*(dav[nb][r]-dl[r]);
        if(jj>ii || ii>=NM_ || jj>=NM_) dsv=0.f;
        psb[w][lg*4+r][ln+16*nb]=f2bf(dsv);
      }
    }
    lds_fence();
    #pragma unroll
    for(int nb=0;nb<4;nb++){
      #pragma unroll
      for(int s=0;s<2;s++){
        bf16x8 pa = *(const bf16x8*)&psb[w][ln][32*s+lg*8];
        bf16x8 bk = *(const bf16x8*)&kts[nb*16+ln][32*s+lg*8];
        acc[nb]=MFMA_B16(pa,bk,acc[nb]);
      }
    }
    lds_fence();
  }
  #pragma unroll
  for(int nb=0;nb<4;nb++){
    short4 s4;
    s4.x=f2bf(acc[nb][0]); s4.y=f2bf(acc[nb][1]);
    s4.z=f2bf(acc[nb][2]); s4.w=f2bf(acc[nb][3]);
    *(short4*)&dqt[((size_t)bh*64 + nb*16+ln)*2048 + i0+w*16+lg*4]=s4;
  }
}

// ---------------- 12. flash backward dk,dv (prefetch + bf16 P/dS, merged fence) ----------------
__global__ __launch_bounds__(256) void k_fa_dkv(const short* __restrict__ kh,
    const short* __restrict__ vh, const short* __restrict__ qh,
    const short* __restrict__ qt, const short* __restrict__ doh,
    const short* __restrict__ dot,
    const float* __restrict__ lse, const float* __restrict__ delta,
    short* __restrict__ dkt, short* __restrict__ dvt){
  int bh = blockIdx.x, qq = blockIdx.y;
  int jt = (qq<16)? qq : (47-qq);
  int j0 = jt<<6;
  const short* khb = kh + (size_t)bh*N_*DH_;
  const short* vhb = vh + (size_t)bh*N_*DH_;
  const short* qhb = qh + (size_t)bh*N_*DH_;
  const short* qtb = qt + (size_t)bh*DH_*N_;
  const short* dohb= doh+ (size_t)bh*N_*DH_;
  const short* dotb= dot+ (size_t)bh*DH_*N_;
  __shared__ __attribute__((aligned(16))) short qs[64][LBK], dos[64][LBK], qts[64][LBK], dots[64][LBK];
  __shared__ __attribute__((aligned(16))) short psv[4][16][LBK], psk[4][16][LBK];
  __shared__ float Ls[64], dls[64];
  int tid=threadIdx.x, w=tid>>6, lane=tid&63, lg=lane>>4, ln=lane&15;
  bf16x8 akf[2], avf[2];
  #pragma unroll
  for(int s=0;s<2;s++){
    akf[s]=*(const bf16x8*)&khb[(size_t)(j0+w*16+ln)*DH_+32*s+lg*8];
    avf[s]=*(const bf16x8*)&vhb[(size_t)(j0+w*16+ln)*DH_+32*s+lg*8];
  }
  f32x4 accv[4], acck[4];
  #pragma unroll
  for(int nb=0;nb<4;nb++){
    accv[nb]=(f32x4){0.f,0.f,0.f,0.f};
    acck[nb]=(f32x4){0.f,0.f,0.f,0.f};
  }
  int4 qa0,qa1,da0,da1,qta0,qta1,dta0,dta1;
  float Lnx=0.f, dlnx=0.f;
  {
    int ip=j0;
    tload(qhb+(size_t)ip*DH_, DH_, tid, qa0,qa1);
    tload(dohb+(size_t)ip*DH_, DH_, tid, da0,da1);
    tload(qtb+ip, N_, tid, qta0,qta1);
    tload(dotb+ip, N_, tid, dta0,dta1);
    if(tid<64){
      int ii=ip+tid;
      Lnx=lse[(size_t)bh*N_+ii];
      dlnx=(ii<NM_)?delta[(size_t)bh*N_+ii]:0.f;
    }
  }
  for(int it=jt; it<32; ++it){
    int i0=it<<6;
    __syncthreads();
    twrite(qs, tid, qa0,qa1);
    twrite(dos, tid, da0,da1);
    twrite(qts, tid, qta0,qta1);
    twrite(dots, tid, dta0,dta1);
    if(tid<64){ Ls[tid]=Lnx; dls[tid]=dlnx; }
    if(it<31){
      int i1=(it+1)<<6;
      tload(qhb+(size_t)i1*DH_, DH_, tid, qa0,qa1);
      tload(dohb+(size_t)i1*DH_, DH_, tid, da0,da1);
      tload(qtb+i1, N_, tid, qta0,qta1);
      tload(dotb+i1, N_, tid, dta0,dta1);
      if(tid<64){
        int ii=i1+tid;
        Lnx=lse[(size_t)bh*N_+ii];
        dlnx=(ii<NM_)?delta[(size_t)bh*N_+ii]:0.f;
      }
    }
    __syncthreads();
    f32x4 sv[4], dav[4];
    #pragma unroll
    for(int nb=0;nb<4;nb++){
      f32x4 z={0.f,0.f,0.f,0.f}, zd={0.f,0.f,0.f,0.f};
      #pragma unroll
      for(int s=0;s<2;s++){
        bf16x8 bq=*(const bf16x8*)&qs[nb*16+ln][32*s+lg*8];
        bf16x8 bd=*(const bf16x8*)&dos[nb*16+ln][32*s+lg*8];
        z = MFMA_B16(akf[s], bq, z);
        zd= MFMA_B16(avf[s], bd, zd);
      }
      sv[nb]=z; dav[nb]=zd;
    }
    #pragma unroll
    for(int nb=0;nb<4;nb++){
      float Lc=Ls[nb*16+ln], dlc=dls[nb*16+ln];
      int ii=i0+nb*16+ln;
      #pragma unroll
      for(int r=0;r<4;r++){
        int jj=j0+w*16+lg*4+r;
        float pv=__expf(sv[nb][r]*SCALE_F - Lc);
        bool msk=(jj>ii)||(ii>=NM_)||(jj>=NM_);
        if(msk) pv=0.f;
        float ds = msk?0.f: SCALE_F*pv*(dav[nb][r]-dlc);
        psv[w][lg*4+r][ln+16*nb]=f2bf(pv);
        psk[w][lg*4+r][ln+16*nb]=f2bf(ds);
      }
    }
    lds_fence();
    #pragma unroll
    for(int nb=0;nb<4;nb++){
      #pragma unroll
      for(int s=0;s<2;s++){
        bf16x8 pa = *(const bf16x8*)&psv[w][ln][32*s+lg*8];
        bf16x8 bd = *(const bf16x8*)&dots[nb*16+ln][32*s+lg*8];
        accv[nb]=MFMA_B16(pa,bd,accv[nb]);
        bf16x8 pk = *(const bf16x8*)&psk[w][ln][32*s+lg*8];
        bf16x8 bq = *(const bf16x8*)&qts[nb*16+ln][32*s+lg*8];
        acck[nb]=MFMA_B16(pk,bq,acck[nb]);
      }
    }
    lds_fence();
  }
  #pragma unroll
  for(int nb=0;nb<4;nb++){
    int e=nb*16+ln, n0=j0+w*16+lg*4;
    short4 s4;
    s4.x=f2bf(accv[nb][0]); s4.y=f2bf(accv[nb][1]);
    s4.z=f2bf(accv[nb][2]); s4.w=f2bf(accv[nb][3]);
    *(short4*)&dvt[((size_t)bh*64+e)*2048 + n0]=s4;
    s4.x=f2bf(acck[nb][0]); s4.y=f2bf(acck[nb][1]);
    s4.z=f2bf(acck[nb][2]); s4.w=f2bf(acck[nb][3]);
    *(short4*)&dkt[((size_t)bh*64+e)*2048 + n0]=s4;
  }
}

// ---------------- 13. weight grads (MFMA, split-K=8) ----------------
__global__ __launch_bounds__(256) void k_gemm_wgq(const short* __restrict__ tt,
    const short* __restrict__ g, float* __restrict__ par){
  __shared__ __attribute__((aligned(16))) short as[64][LBK], bs[64][LBK];
  int dt=blockIdx.x, h=blockIdx.y, sp=blockIdx.z;
  int b=sp>>2, n0b=(sp&3)*512;
  f32x4 acc[4];
  #pragma unroll
  for(int nb=0;nb<4;nb++) acc[nb]=(f32x4){0.f,0.f,0.f,0.f};
  gemm64(tt + (size_t)(dt*64)*4096 + sp*512, 4096,
         g  + ((size_t)(b*8+h)*64)*2048 + n0b, 2048, 8, as, bs, acc);
  int tid=threadIdx.x, w=tid>>6, lane=tid&63, lg=lane>>4, ln=lane&15;
  int row=w*16+lg*4;
  #pragma unroll
  for(int nb=0;nb<4;nb++)
    #pragma unroll
    for(int r=0;r<4;r++)
      par[(size_t)sp*262144 + (size_t)h*32768 + (size_t)(dt*64+row+r)*64 + nb*16+ln]=acc[nb][r];
}

__global__ __launch_bounds__(256) void k_gemm_wgo(const short* __restrict__ outt,
    const short* __restrict__ ert, float* __restrict__ par){
  __shared__ __attribute__((aligned(16))) short as[64][LBK], bs[64][LBK];
  int ct=blockIdx.x, h=blockIdx.y, sp=blockIdx.z;
  f32x4 acc[4];
  #pragma unroll
  for(int nb=0;nb<4;nb++) acc[nb]=(f32x4){0.f,0.f,0.f,0.f};
  gemm64(outt + (size_t)(h*64)*4096 + sp*512, 4096,
         ert  + (size_t)(ct*64)*4096 + sp*512, 4096, 8, as, bs, acc);
  int tid=threadIdx.x, w=tid>>6, lane=tid&63, lg=lane>>4, ln=lane&15;
  int row=w*16+lg*4;
  #pragma unroll
  for(int nb=0;nb<4;nb++)
    #pragma unroll
    for(int r=0;r<4;r++)
      par[(size_t)sp*262144 + (size_t)h*32768 + (size_t)(row+r)*512 + ct*64+nb*16+ln]=acc[nb][r];
}

__global__ __launch_bounds__(256) void k_wred_direct(const float* __restrict__ par,
    float* __restrict__ dst){
  int idx = blockIdx.x*256 + threadIdx.x;
  float s=0.f;
  #pragma unroll
  for(int sp=0;sp<8;sp++) s += par[(size_t)sp*262144 + idx];
  dst[idx]=s;
}
__global__ __launch_bounds__(256) void k_wred_xv(const float* __restrict__ par,
    float* __restrict__ X0){
  int idx = blockIdx.x*256 + threadIdx.x;
  float s=0.f;
  #pragma unroll
  for(int sp=0;sp<8;sp++) s += par[(size_t)sp*262144 + idx];
  int h=idx>>15, rem=idx&32767, d=rem>>6, e=rem&63;
  X0[(size_t)h*32768 + (size_t)e*512 + d]=s;
}
__global__ __launch_bounds__(256) void k_wred_xo(const float* __restrict__ par,
    float* __restrict__ X0){
  int idx = blockIdx.x*256 + threadIdx.x;
  float s=0.f;
  #pragma unroll
  for(int sp=0;sp<8;sp++) s += par[(size_t)sp*262144 + idx];
  X0[262144 + idx]=s;
}

// ---------------- 14. Newton-Schulz (f32) ----------------
#define LP 66
__global__ __launch_bounds__(256) void k_ns_scale(float* __restrict__ X){
  float* Xm = X + (size_t)blockIdx.x*32768;
  int tid=threadIdx.x;
  float ss=0.f;
  for(int i=tid;i<32768;i+=256){ float v=Xm[i]; ss+=v*v; }
  ss=wred64(ss);
  __shared__ float r[4];
  if((tid&63)==0) r[tid>>6]=ss;
  __syncthreads();
  float tot=r[0]+r[1]+r[2]+r[3];
  float sc = 1.f/fmaxf(sqrtf(tot), 1e-7f);
  for(int i=tid;i<32768;i+=256) Xm[i]*=sc;
}
__global__ __launch_bounds__(256) void k_ns_A(const float* __restrict__ X,
    float* __restrict__ A){
  const float* Xm = X + (size_t)blockIdx.x*32768;
  __shared__ float xs[64][LP];
  int tid=threadIdx.x, ty=tid>>4, tx=tid&15;
  float acc[4][4]={{0}};
  for(int d0=0;d0<512;d0+=64){
    __syncthreads();
    for(int kk=0;kk<16;kk++){
      int idx=kk*256+tid; int rr=idx>>6, cc=idx&63;
      xs[rr][cc]=Xm[(size_t)rr*512 + d0+cc];
    }
    __syncthreads();
    for(int kk=0;kk<64;kk++){
      float a[4], bb[4];
      #pragma unroll
      for(int r=0;r<4;r++) a[r]=xs[ty*4+r][kk];
      #pragma unroll
      for(int c=0;c<4;c++) bb[c]=xs[tx+16*c][kk];
      #pragma unroll
      for(int r=0;r<4;r++)
        #pragma unroll
        for(int c=0;c<4;c++) acc[r][c]+=a[r]*bb[c];
    }
  }
  #pragma unroll
  for(int r=0;r<4;r++)
    #pragma unroll
    for(int c=0;c<4;c++)
      A[(size_t)blockIdx.x*4096 + (size_t)(ty*4+r)*64 + tx+16*c]=acc[r][c];
}
__global__ __launch_bounds__(256) void k_ns_B(const float* __restrict__ A,
    float* __restrict__ Bm){
  __shared__ float as[64][LP];
  int tid=threadIdx.x, ty=tid>>4, tx=tid&15;
  for(int kk=0;kk<16;kk++){
    int idx=kk*256+tid; int rr=idx>>6, cc=idx&63;
    as[rr][cc]=A[(size_t)blockIdx.x*4096 + rr*64 + cc];
  }
  __syncthreads();
  float acc[4][4]={{0}};
  for(int kk=0;kk<64;kk++){
    float a[4], bb[4];
    #pragma unroll
    for(int r=0;r<4;r++) a[r]=as[ty*4+r][kk];
    #pragma unroll
    for(int c=0;c<4;c++) bb[c]=as[kk][tx+16*c];
    #pragma unroll
    for(int r=0;r<4;r++)
      #pragma unroll
      for(int c=0;c<4;c++) acc[r][c]+=a[r]*bb[c];
  }
  #pragma unroll
  for(int r=0;r<4;r++)
    #pragma unroll
    for(int c=0;c<4;c++)
      Bm[(size_t)blockIdx.x*4096 + (size_t)(ty*4+r)*64 + tx+16*c]
        = -4.775f*as[ty*4+r][tx+16*c] + 2.0315f*acc[r][c];
}
__global__ __launch_bounds__(256) void k_ns_update(const float* __restrict__ Xold,
    const float* __restrict__ Bm, float* __restrict__ Xnew){
  int ct=blockIdx.x, m=blockIdx.y;
  __shared__ float bs[64][LP], xs[64][LP];
  int tid=threadIdx.x, ty=tid>>4, tx=tid&15;
  for(int kk=0;kk<16;kk++){
    int idx=kk*256+tid; int rr=idx>>6, cc=idx&63;
    bs[rr][cc]=Bm[(size_t)m*4096 + rr*64 + cc];
    xs[rr][cc]=Xold[(size_t)m*32768 + (size_t)rr*512 + ct*64+cc];
  }
  __syncthreads();
  float acc[4][4]={{0}};
  for(int kk=0;kk<64;kk++){
    float a[4], bb[4];
    #pragma unroll
    for(int r=0;r<4;r++) a[r]=bs[ty*4+r][kk];
    #pragma unroll
    for(int c=0;c<4;c++) bb[c]=xs[kk][tx+16*c];
    #pragma unroll
    for(int r=0;r<4;r++)
      #pragma unroll
      for(int c=0;c<4;c++) acc[r][c]+=a[r]*bb[c];
  }
  #pragma unroll
  for(int r=0;r<4;r++)
    #pragma unroll
    for(int c=0;c<4;c++)
      Xnew[(size_t)m*32768 + (size_t)(ty*4+r)*512 + ct*64+tx+16*c]
        = 3.4445f*xs[ty*4+r][tx+16*c] + acc[r][c];
}
__global__ __launch_bounds__(256) void k_ns_final(const float* __restrict__ X,
    float* __restrict__ dwv, float* __restrict__ dwo){
  int idx = blockIdx.x*256 + threadIdx.x;
  int m = idx>>15, rem = idx&32767, e = rem>>9, d = rem&511;
  float v = X[idx];
  if(m<8) dwv[(size_t)m*32768 + (size_t)d*64 + e] = v;
  else    dwo[(size_t)(m-8)*32768 + (size_t)e*512 + d] = v;
}

// ---------------- launch ----------------
extern "C" void kernel_launch(void* const* d_in, const int* in_sizes, int n_in,
                              void* d_out, int out_size, void* d_ws, size_t ws_size,
                              hipStream_t stream) {
  const float* tokens=(const float*)d_in[0];
  const float* rmsw =(const float*)d_in[1];
  const float* wq   =(const float*)d_in[2];
  const float* wk   =(const float*)d_in[3];
  const float* wv   =(const float*)d_in[4];
  const float* wo   =(const float*)d_in[5];
  const float* lrw  =(const float*)d_in[6];
  const float* tvw  =(const float*)d_in[7];
  float* out = (float*)d_out;
  float* ws  = (float*)d_ws;

  short* tb   = (short*)(ws);            // [4160][512] bf16 (pad rows zero)
  short* tt   = (short*)(ws + 1064960);  // [512][4096]
  short* qh   = (short*)(ws + 2113536);  // [16bh][2048][64]
  short* kh   = (short*)(ws + 3162112);
  short* vh   = (short*)(ws + 4210688);
  short* qt   = (short*)(ws + 5259264);  // [16bh][64][2048]
  short* kt   = (short*)(ws + 6307840);
  short* vt   = (short*)(ws + 7356416);
  float* ob_  = ws + 8404992;            // f32 [4096][512]; er_ aliases after trans
  float* er_  = ws + 8404992;
  short* obb  = (short*)(ws + 10502144); // bf16 [4096][512]
  short* outt = (short*)(ws + 11550720); // bf16 [512][4096]
  short* erb  = (short*)(ws + 12599296);
  short* ert  = (short*)(ws + 13647872);
  short* doh  = (short*)(ws + 14696448); // [16bh][2048][64]
  short* dot  = (short*)(ws + 15745024); // [16bh][64][2048]
  float* par_ = ws + 14696448;           // aliases doh+dot (dead before wgrad)
  short* dqt  = (short*)(ws + 16793600); // [16bh][64][2048]
  short* dkt  = (short*)(ws + 17842176);
  short* dvt  = (short*)(ws + 18890752);
  short* wqt  = (short*)(ws + 19939328); // [8h][64][512]
  short* wkt  = (short*)(ws + 20070400);
  short* wvt  = (short*)(ws + 20201472);
  short* wob  = (short*)(ws + 20332544); // [512 he][512 d]
  short* wot  = (short*)(ws + 20463616); // [512 d][512 he]
  short* tvwb = (short*)(ws + 20594688); // [512 o][512 d]
  float* lse_ = ws + 20725760;
  float* dlt_ = ws + 20758528;
  float* X0_  = ws + 20791296;
  float* X1_  = ws + 21315584;
  float* Am_  = ws + 21839872;
  float* Bm_  = ws + 21905408;

  float* OUT_PRED = out;
  float* OUT_DWQ  = out + 2097152;
  float* OUT_DWK  = out + 2359296;
  float* OUT_DWV  = out + 2621440;
  float* OUT_DWO  = out + 2883584;

  k_rmsnorm<<<4160,256,0,stream>>>(tokens, rmsw, tb);
  k_wprep<<<272,256,0,stream>>>(wq,wk,wv,wo,tvw, wqt,wkt,wvt,wob,wot,tvwb);
  k_gemm_qkv<<<dim3(64,24),256,0,stream>>>(tb, wqt,wkt,wvt, qh,kh,vh, qt,kt,vt);
  k_fa_fwd<<<dim3(16,32),256,0,stream>>>(qh, kh, vt, ob_, lse_);
  k_trans_f<<<dim3(64,8),256,0,stream>>>(ob_, obb, outt);
  k_gemm_pred<<<dim3(64,8),256,0,stream>>>(obb, wot, OUT_PRED);

  if(out_size < 3145728) return;   // forward-only variant

  k_trans_b<<<dim3(64,8),256,0,stream>>>(tb, tt);
  k_gemm_tv<<<dim3(64,8),256,0,stream>>>(tb, tvwb, er_);
  k_lnerr<<<4094,256,0,stream>>>(er_, tb, OUT_PRED, lrw);
  k_trans_f<<<dim3(64,8),256,0,stream>>>(er_, erb, ert);
  k_gemm_dout<<<dim3(64,8),256,0,stream>>>(erb, wob, doh, dot);
  k_delta<<<8188,256,0,stream>>>(doh, obb, dlt_);
  k_fa_dq<<<dim3(16,32),256,0,stream>>>(qh, kh, vh, kt, doh, lse_, dlt_, dqt);
  k_fa_dkv<<<dim3(16,32),256,0,stream>>>(kh, vh, qh, qt, doh, dot, lse_, dlt_, dkt, dvt);

  k_gemm_wgq<<<dim3(8,8,8),256,0,stream>>>(tt, dqt, par_);
  k_wred_direct<<<1024,256,0,stream>>>(par_, OUT_DWQ);
  k_gemm_wgq<<<dim3(8,8,8),256,0,stream>>>(tt, dkt, par_);
  k_wred_direct<<<1024,256,0,stream>>>(par_, OUT_DWK);
  k_gemm_wgq<<<dim3(8,8,8),256,0,stream>>>(tt, dvt, par_);
  k_wred_xv<<<1024,256,0,stream>>>(par_, X0_);
  k_gemm_wgo<<<dim3(8,8,8),256,0,stream>>>(outt, ert, par_);
  k_wred_xo<<<1024,256,0,stream>>>(par_, X0_);

  k_ns_scale<<<16,256,0,stream>>>(X0_);
  float* xa = X0_; float* xb = X1_;
  for(int itr=0; itr<5; ++itr){
    k_ns_A<<<16,256,0,stream>>>(xa, Am_);
    k_ns_B<<<16,256,0,stream>>>(Am_, Bm_);
    k_ns_update<<<dim3(8,16),256,0,stream>>>(xa, Bm_, xb);
    float* tmp = xa; xa = xb; xb = tmp;
  }
  k_ns_final<<<2048,256,0,stream>>>(xa, OUT_DWV, OUT_DWO);
}

// Round 7
// 511.287 us; speedup vs baseline: 5.4706x; 1.0192x over previous
//
#include <hip/hip_runtime.h>
#include <float.h>
#include <math.h>

// ---------------- problem constants ----------------
#define B_   2
#define N_   2048
#define D_   512
#define H_   8
#define DH_  64
#define NM_  2047            // n-1
#define SCALE_F 0.125f       // 64^-0.5
#define LBK 72               // LDS row pad (bf16 tiles), 144B: 16B-aligned rows

typedef __attribute__((ext_vector_type(8))) short bf16x8;
typedef __attribute__((ext_vector_type(4))) float f32x4;
#define MFMA_B16(a,b,c) __builtin_amdgcn_mfma_f32_16x16x32_bf16(a,b,c,0,0,0)

__device__ __forceinline__ short f2bf(float f){
  unsigned u = __float_as_uint(f);
  unsigned r = u + 0x7fffu + ((u>>16)&1u);
  return (short)(r>>16);
}
__device__ __forceinline__ float bf2f(short s){
  return __uint_as_float(((unsigned)(unsigned short)s)<<16);
}
__device__ __forceinline__ void lds_fence(){
  asm volatile("s_waitcnt lgkmcnt(0)" ::: "memory");
  __builtin_amdgcn_sched_barrier(0);
}
// load a 64x64 bf16 tile into regs (2 int4 per thread); pairs with twrite
__device__ __forceinline__ void tload(const short* __restrict__ src, size_t stride,
                                      int tid, int4& r0, int4& r1){
  int rr = tid>>2, cc = (tid&3)<<4;
  r0 = *(const int4*)&src[(size_t)rr*stride + cc];
  r1 = *(const int4*)&src[(size_t)rr*stride + cc + 8];
}
__device__ __forceinline__ void twrite(short (*dst)[LBK], int tid,
                                       const int4& r0, const int4& r1){
  int rr = tid>>2, cc = (tid&3)<<4;
  *(int4*)&dst[rr][cc]   = r0;
  *(int4*)&dst[rr][cc+8] = r1;
}
__device__ __forceinline__ float wred64(float v){
  #pragma unroll
  for(int off=32; off; off>>=1) v += __shfl_down(v, off, 64);
  return v;
}

// 64x64 MFMA GEMM mainloop with register-prefetch double buffering (2-phase)
__device__ __forceinline__ void gemm64(const short* __restrict__ A, size_t lda,
    const short* __restrict__ Bt, size_t ldb, int nk,
    short (*as)[LBK], short (*bs)[LBK], f32x4* acc){
  int tid=threadIdx.x, w=tid>>6, lane=tid&63, lg=lane>>4, ln=lane&15;
  int4 a0,a1,b0,b1;
  tload(A, lda, tid, a0,a1);
  tload(Bt, ldb, tid, b0,b1);
  for(int kt=0;kt<nk;++kt){
    __syncthreads();
    twrite(as, tid, a0,a1);
    twrite(bs, tid, b0,b1);
    if(kt+1<nk){
      tload(A +(size_t)(kt+1)*64, lda, tid, a0,a1);
      tload(Bt+(size_t)(kt+1)*64, ldb, tid, b0,b1);
    }
    __syncthreads();
    __builtin_amdgcn_s_setprio(1);
    #pragma unroll
    for(int s=0;s<2;s++){
      bf16x8 a = *(const bf16x8*)&as[w*16+ln][32*s+lg*8];
      #pragma unroll
      for(int nb=0;nb<4;nb++){
        bf16x8 b = *(const bf16x8*)&bs[nb*16+ln][32*s+lg*8];
        acc[nb]=MFMA_B16(a,b,acc[nb]);
      }
    }
    __builtin_amdgcn_s_setprio(0);
  }
}

// ---------------- 1. RMSNorm -> tb (bf16, padded to 4160 rows) ----------------
__global__ __launch_bounds__(256) void k_rmsnorm(const float* __restrict__ tok,
    const float* __restrict__ w, short* __restrict__ tb){
  int row = blockIdx.x;
  int tid = threadIdx.x;
  if(row>=4096){ tb[(size_t)row*D_+tid]=0; tb[(size_t)row*D_+tid+256]=0; return; }
  const float* x = tok + (size_t)row*D_;
  float v0 = x[tid], v1 = x[tid+256];
  float s = v0*v0 + v1*v1;
  s = wred64(s);
  __shared__ float red[4];
  if((tid&63)==0) red[tid>>6] = s;
  __syncthreads();
  float tot = red[0]+red[1]+red[2]+red[3];
  float sc = rsqrtf(tot*(1.f/512.f) + 1.1920929e-7f);
  tb[(size_t)row*D_+tid]     = f2bf(v0*sc*w[tid]);
  tb[(size_t)row*D_+tid+256] = f2bf(v1*sc*w[tid+256]);
}

// ---------------- 2. weight prep ----------------
__global__ __launch_bounds__(256) void k_wprep(const float* __restrict__ wq,
    const float* __restrict__ wk, const float* __restrict__ wv,
    const float* __restrict__ wo, const float* __restrict__ tvw,
    short* __restrict__ wqt, short* __restrict__ wkt, short* __restrict__ wvt,
    short* __restrict__ wob, short* __restrict__ wot, short* __restrict__ tvwb){
  __shared__ short l[64][66];
  int bx=blockIdx.x, tid=threadIdx.x;
  if(bx<192){
    const float* w = (bx<64)? wq : (bx<128)? wk : wv;
    short* wt      = (bx<64)? wqt: (bx<128)? wkt: wvt;
    int lb=bx&63, h=lb>>3, d0=(lb&7)*64;
    for(int kk=0;kk<16;kk++){
      int idx=kk*256+tid, rr=idx>>6, cc=idx&63;
      l[cc][rr] = f2bf(w[((size_t)h*512 + d0+rr)*64 + cc]);
    }
    __syncthreads();
    for(int kk=0;kk<16;kk++){
      int idx=kk*256+tid, rr=idx>>6, cc=idx&63;
      wt[((size_t)h*64+rr)*512 + d0+cc] = l[rr][cc];
    }
  } else if(bx<256){
    int lb=bx-192, r0=(lb>>3)*64, c0=(lb&7)*64;
    for(int kk=0;kk<16;kk++){
      int idx=kk*256+tid, rr=idx>>6, cc=idx&63;
      l[cc][rr] = f2bf(wo[(size_t)(r0+rr)*512 + c0+cc]);
    }
    __syncthreads();
    for(int kk=0;kk<16;kk++){
      int idx=kk*256+tid, rr=idx>>6, cc=idx&63;
      wot[(size_t)(c0+rr)*512 + r0+cc] = l[rr][cc];
    }
  } else if(bx<264){
    size_t base=(size_t)(bx-256)*32768;
    for(int kk=0;kk<128;kk++) wob[base+kk*256+tid]=f2bf(wo[base+kk*256+tid]);
  } else {
    size_t base=(size_t)(bx-264)*32768;
    for(int kk=0;kk<128;kk++) tvwb[base+kk*256+tid]=f2bf(tvw[base+kk*256+tid]);
  }
}

// ---------------- 3. transposes (4096x512) ----------------
__global__ __launch_bounds__(256) void k_trans_b(const short* __restrict__ in,
    short* __restrict__ outt){
  __shared__ short l[64][66];
  int r0=blockIdx.x<<6, c0=blockIdx.y<<6, tid=threadIdx.x;
  for(int kk=0;kk<16;kk++){
    int idx=kk*256+tid, rr=idx>>6, cc=idx&63;
    l[cc][rr]=in[(size_t)(r0+rr)*512 + c0+cc];
  }
  __syncthreads();
  for(int kk=0;kk<16;kk++){
    int idx=kk*256+tid, rr=idx>>6, cc=idx&63;
    outt[(size_t)(c0+rr)*4096 + r0+cc]=l[rr][cc];
  }
}
__global__ __launch_bounds__(256) void k_trans_f(const float* __restrict__ in,
    short* __restrict__ outn, short* __restrict__ outt){
  __shared__ short l[64][66];
  int r0=blockIdx.x<<6, c0=blockIdx.y<<6, tid=threadIdx.x;
  for(int kk=0;kk<16;kk++){
    int idx=kk*256+tid, rr=idx>>6, cc=idx&63;
    short v=f2bf(in[(size_t)(r0+rr)*512 + c0+cc]);
    outn[(size_t)(r0+rr)*512 + c0+cc]=v;
    l[cc][rr]=v;
  }
  __syncthreads();
  for(int kk=0;kk<16;kk++){
    int idx=kk*256+tid, rr=idx>>6, cc=idx&63;
    outt[(size_t)(c0+rr)*4096 + r0+cc]=l[rr][cc];
  }
}

// ---------------- 4. QKV projection (MFMA) ----------------
__global__ __launch_bounds__(256) void k_gemm_qkv(const short* __restrict__ tb,
    const short* __restrict__ wqt, const short* __restrict__ wkt, const short* __restrict__ wvt,
    short* __restrict__ qh, short* __restrict__ kh, short* __restrict__ vh,
    short* __restrict__ qt, short* __restrict__ kt, short* __restrict__ vt){
  __shared__ __attribute__((aligned(16))) short as[64][LBK], bs[64][LBK];
  int r0=blockIdx.x<<6, ct=blockIdx.y, which=ct>>3, h=ct&7;
  const short* Bt=(which==0?wqt:which==1?wkt:wvt)+(size_t)h*32768;
  f32x4 acc[4];
  #pragma unroll
  for(int nb=0;nb<4;nb++) acc[nb]=(f32x4){0.f,0.f,0.f,0.f};
  gemm64(tb+(size_t)r0*512, 512, Bt, 512, 8, as, bs, acc);
  short* on=(which==0?qh:which==1?kh:vh);
  short* ot=(which==0?qt:which==1?kt:vt);
  int tid=threadIdx.x, w=tid>>6, lane=tid&63, lg=lane>>4, ln=lane&15;
  size_t bh=(size_t)(r0>>11)*8+h;
  int n0=(r0&2047)+w*16+lg*4;
  #pragma unroll
  for(int nb=0;nb<4;nb++){
    int e=nb*16+ln;
    short4 s4;
    s4.x=f2bf(acc[nb][0]); s4.y=f2bf(acc[nb][1]);
    s4.z=f2bf(acc[nb][2]); s4.w=f2bf(acc[nb][3]);
    on[(bh*2048+n0  )*64+e]=s4.x;
    on[(bh*2048+n0+1)*64+e]=s4.y;
    on[(bh*2048+n0+2)*64+e]=s4.z;
    on[(bh*2048+n0+3)*64+e]=s4.w;
    *(short4*)&ot[(bh*64+e)*2048+n0]=s4;
  }
}

// ---------------- 5. flash attention forward (prefetch + bf16 P) ----------------
__global__ __launch_bounds__(256) void k_fa_fwd(const short* __restrict__ qh,
    const short* __restrict__ kh, const short* __restrict__ vt,
    float* __restrict__ outb, float* __restrict__ lse){
  int bh = blockIdx.x, qq = blockIdx.y;
  int it = (qq<16)? (31-qq) : (qq-16);
  int b = bh>>3, h = bh&7;
  int i0 = it<<6;
  const short* qhb = qh + (size_t)bh*N_*DH_;
  const short* khb = kh + (size_t)bh*N_*DH_;
  const short* vtb = vt + (size_t)bh*DH_*N_;
  __shared__ __attribute__((aligned(16))) short ks[64][LBK], vts[64][LBK];
  __shared__ __attribute__((aligned(16))) short psb[4][16][LBK];
  int tid=threadIdx.x, w=tid>>6, lane=tid&63, lg=lane>>4, ln=lane&15;
  bf16x8 aq[2];
  #pragma unroll
  for(int s=0;s<2;s++)
    aq[s] = *(const bf16x8*)&qhb[(size_t)(i0+w*16+ln)*DH_ + 32*s + lg*8];
  f32x4 acc[4];
  float mrow[4], lrow[4];
  #pragma unroll
  for(int nb=0;nb<4;nb++) acc[nb]=(f32x4){0.f,0.f,0.f,0.f};
  #pragma unroll
  for(int r=0;r<4;r++){ mrow[r]=-FLT_MAX; lrow[r]=0.f; }
  int4 ka0,ka1,va0,va1;
  tload(khb, DH_, tid, ka0,ka1);
  tload(vtb, N_, tid, va0,va1);
  for(int jt=0;jt<=it;++jt){
    int j0 = jt<<6;
    __syncthreads();
    twrite(ks, tid, ka0,ka1);
    twrite(vts, tid, va0,va1);
    if(jt<it){
      tload(khb+(size_t)(jt+1)*64*DH_, DH_, tid, ka0,ka1);
      tload(vtb+(jt+1)*64, N_, tid, va0,va1);
    }
    __syncthreads();
    f32x4 sv[4];
    __builtin_amdgcn_s_setprio(1);
    #pragma unroll
    for(int nb=0;nb<4;nb++){
      f32x4 z = {0.f,0.f,0.f,0.f};
      #pragma unroll
      for(int s=0;s<2;s++){
        bf16x8 bk = *(const bf16x8*)&ks[nb*16+ln][32*s + lg*8];
        z = MFMA_B16(aq[s], bk, z);
      }
      sv[nb]=z;
    }
    __builtin_amdgcn_s_setprio(0);
    int iiB = i0 + w*16 + lg*4;
    #pragma unroll
    for(int r=0;r<4;r++){
      int ii = iiB + r;
      float srow[4]; float mx = -FLT_MAX;
      #pragma unroll
      for(int nb=0;nb<4;nb++){
        float x = sv[nb][r]*SCALE_F;
        if(j0+nb*16+ln > ii) x = -FLT_MAX;
        srow[nb]=x; mx=fmaxf(mx,x);
      }
      mx=fmaxf(mx,__shfl_xor(mx,1)); mx=fmaxf(mx,__shfl_xor(mx,2));
      mx=fmaxf(mx,__shfl_xor(mx,4)); mx=fmaxf(mx,__shfl_xor(mx,8));
      float mn = fmaxf(mrow[r], mx);
      float rs = 0.f;
      #pragma unroll
      for(int nb=0;nb<4;nb++){
        float pv = __expf(srow[nb]-mn);
        psb[w][lg*4+r][ln+16*nb]=f2bf(pv); rs+=pv;
      }
      rs+=__shfl_xor(rs,1); rs+=__shfl_xor(rs,2);
      rs+=__shfl_xor(rs,4); rs+=__shfl_xor(rs,8);
      float corr = __expf(mrow[r]-mn);
      lrow[r]=lrow[r]*corr+rs; mrow[r]=mn;
      #pragma unroll
      for(int nb=0;nb<4;nb++) acc[nb][r]*=corr;
    }
    lds_fence();
    __builtin_amdgcn_s_setprio(1);
    #pragma unroll
    for(int nb=0;nb<4;nb++){
      #pragma unroll
      for(int s=0;s<2;s++){
        bf16x8 pa = *(const bf16x8*)&psb[w][ln][32*s + lg*8];
        bf16x8 bv = *(const bf16x8*)&vts[nb*16+ln][32*s + lg*8];
        acc[nb] = MFMA_B16(pa, bv, acc[nb]);
      }
    }
    __builtin_amdgcn_s_setprio(0);
    lds_fence();
  }
  #pragma unroll
  for(int r=0;r<4;r++){
    int ii = i0 + w*16 + lg*4 + r;
    float inv = 1.f/lrow[r];
    #pragma unroll
    for(int nb=0;nb<4;nb++)
      outb[((size_t)(b*N_+ii))*D_ + h*DH_ + nb*16+ln] = acc[nb][r]*inv;
    if(ln==0) lse[(size_t)bh*N_ + ii] = mrow[r] + logf(lrow[r]);
  }
}

// ---------------- 6. pred = obb @ wot^T (MFMA), f32 out ----------------
__global__ __launch_bounds__(256) void k_gemm_pred(const short* __restrict__ obb,
    const short* __restrict__ wot, float* __restrict__ pred){
  __shared__ __attribute__((aligned(16))) short as[64][LBK], bs[64][LBK];
  int r0=blockIdx.x<<6, c0=blockIdx.y<<6;
  f32x4 acc[4];
  #pragma unroll
  for(int nb=0;nb<4;nb++) acc[nb]=(f32x4){0.f,0.f,0.f,0.f};
  gemm64(obb+(size_t)r0*512, 512, wot+(size_t)c0*512, 512, 8, as, bs, acc);
  int tid=threadIdx.x, w=tid>>6, lane=tid&63, lg=lane>>4, ln=lane&15;
  int row=r0+w*16+lg*4;
  #pragma unroll
  for(int nb=0;nb<4;nb++)
    #pragma unroll
    for(int r=0;r<4;r++)
      pred[(size_t)(row+r)*512 + c0+nb*16+ln]=acc[nb][r];
}

// ---------------- 7. tv = tb(shift+1) @ tvwb^T ----------------
__global__ __launch_bounds__(256) void k_gemm_tv(const short* __restrict__ tb,
    const short* __restrict__ tvwb, float* __restrict__ er){
  __shared__ __attribute__((aligned(16))) short as[64][LBK], bs[64][LBK];
  int r0=blockIdx.x<<6, c0=blockIdx.y<<6;
  f32x4 acc[4];
  #pragma unroll
  for(int nb=0;nb<4;nb++) acc[nb]=(f32x4){0.f,0.f,0.f,0.f};
  gemm64(tb+(size_t)(r0+1)*512, 512, tvwb+(size_t)c0*512, 512, 8, as, bs, acc);
  int tid=threadIdx.x, w=tid>>6, lane=tid&63, lg=lane>>4, ln=lane&15;
  int row=r0+w*16+lg*4;
  #pragma unroll
  for(int nb=0;nb<4;nb++)
    #pragma unroll
    for(int r=0;r<4;r++){
      float v=(((row+r)&2047)==2047)?0.f:acc[nb][r];
      er[(size_t)(row+r)*512 + c0+nb*16+ln]=v;
    }
}

// ---------------- 8. layernorm target + lr + error ----------------
__global__ __launch_bounds__(256) void k_lnerr(float* __restrict__ er,
    const short* __restrict__ tb, const float* __restrict__ pred,
    const float* __restrict__ lrw){
  int kr = blockIdx.x;
  int b = kr/NM_, n = kr-b*NM_;
  size_t row=(size_t)b*2048+n;
  float* tv = er + row*512;
  const short* tok = tb + row*512;
  const float* pr  = pred + row*512;
  int tid=threadIdx.x;
  float v0=tv[tid], v1=tv[tid+256];
  float s1=v0+v1, s2=v0*v0+v1*v1;
  float s3=bf2f(tok[tid])*lrw[tid] + bf2f(tok[tid+256])*lrw[tid+256];
  s1=wred64(s1); s2=wred64(s2); s3=wred64(s3);
  __shared__ float r1[4],r2[4],r3[4];
  if((tid&63)==0){ int w=tid>>6; r1[w]=s1; r2[w]=s2; r3[w]=s3; }
  __syncthreads();
  float S1=r1[0]+r1[1]+r1[2]+r1[3];
  float S2=r2[0]+r2[1]+r2[2]+r2[3];
  float S3=r3[0]+r3[1]+r3[2]+r3[3];
  float mu  = S1*(1.f/512.f);
  float var = S2*(1.f/512.f) - mu*mu;
  float rstd= rsqrtf(var + 1e-5f);
  float lr  = 0.01f/(1.f+__expf(-S3));
  tv[tid]     = ((v0-mu)*rstd - pr[tid])*lr;
  tv[tid+256] = ((v1-mu)*rstd - pr[tid+256])*lr;
}

// ---------------- 9. dout = erb @ wob^T (MFMA) -> doh + dot bf16 ----------------
__global__ __launch_bounds__(256) void k_gemm_dout(const short* __restrict__ erb,
    const short* __restrict__ wob, short* __restrict__ doh, short* __restrict__ dot){
  __shared__ __attribute__((aligned(16))) short as[64][LBK], bs[64][LBK];
  int r0=blockIdx.x<<6, h=blockIdx.y;
  f32x4 acc[4];
  #pragma unroll
  for(int nb=0;nb<4;nb++) acc[nb]=(f32x4){0.f,0.f,0.f,0.f};
  gemm64(erb+(size_t)r0*512, 512, wob+(size_t)h*32768, 512, 8, as, bs, acc);
  int tid=threadIdx.x, w=tid>>6, lane=tid&63, lg=lane>>4, ln=lane&15;
  size_t bh=(size_t)(r0>>11)*8+h;
  int n0=(r0&2047)+w*16+lg*4;
  #pragma unroll
  for(int nb=0;nb<4;nb++){
    int e=nb*16+ln;
    short4 s4;
    s4.x=f2bf(acc[nb][0]); s4.y=f2bf(acc[nb][1]);
    s4.z=f2bf(acc[nb][2]); s4.w=f2bf(acc[nb][3]);
    doh[(bh*2048+n0  )*64+e]=s4.x;
    doh[(bh*2048+n0+1)*64+e]=s4.y;
    doh[(bh*2048+n0+2)*64+e]=s4.z;
    doh[(bh*2048+n0+3)*64+e]=s4.w;
    *(short4*)&dot[(bh*64+e)*2048+n0]=s4;
  }
}

// ---------------- 10. delta = sum_e dout*out ----------------
__global__ __launch_bounds__(256) void k_delta(const short* __restrict__ doh,
    const short* __restrict__ obb, float* __restrict__ delta){
  int rid = blockIdx.x*4 + (threadIdx.x>>6);
  int lane = threadIdx.x&63;
  if(rid >= B_*H_*NM_) return;
  int b = rid/(H_*NM_); int rem = rid - b*H_*NM_;
  int h = rem/NM_; int i = rem - h*NM_;
  float v = bf2f(doh[((size_t)(b*H_+h)*N_ + i)*DH_ + lane])
          * bf2f(obb[((size_t)(b*N_+i))*D_ + h*DH_ + lane]);
  v = wred64(v);
  if(lane==0) delta[((size_t)(b*H_+h))*N_ + i] = v;
}

// ---------------- 11. flash backward dq (2-way j-split) -> dqt + dqp1 ----------------
__global__ __launch_bounds__(256) void k_fa_dq(const short* __restrict__ qh,
    const short* __restrict__ kh, const short* __restrict__ vh,
    const short* __restrict__ kt, const short* __restrict__ doh,
    const float* __restrict__ lse, const float* __restrict__ delta,
    short* __restrict__ dqt, short* __restrict__ dqp1){
  int bh = blockIdx.x, it = blockIdx.y, half = blockIdx.z;
  int i0 = it<<6;
  const short* qhb = qh + (size_t)bh*N_*DH_;
  const short* khb = kh + (size_t)bh*N_*DH_;
  const short* vhb = vh + (size_t)bh*N_*DH_;
  const short* ktb = kt + (size_t)bh*DH_*N_;
  const short* dohb= doh+ (size_t)bh*N_*DH_;
  __shared__ __attribute__((aligned(16))) short ks[64][LBK], vs[64][LBK], kts[64][LBK];
  __shared__ __attribute__((aligned(16))) short psb[4][16][LBK];
  int tid=threadIdx.x, w=tid>>6, lane=tid&63, lg=lane>>4, ln=lane&15;
  bf16x8 aq[2], ad[2];
  float Lr[4], dl[4];
  #pragma unroll
  for(int s=0;s<2;s++){
    aq[s]=*(const bf16x8*)&qhb[(size_t)(i0+w*16+ln)*DH_+32*s+lg*8];
    ad[s]=*(const bf16x8*)&dohb[(size_t)(i0+w*16+ln)*DH_+32*s+lg*8];
  }
  #pragma unroll
  for(int r=0;r<4;r++){
    int ii=i0+w*16+lg*4+r;
    Lr[r]=lse[(size_t)bh*N_+ii];
    dl[r]=(ii<NM_)?delta[(size_t)bh*N_+ii]:0.f;
  }
  f32x4 acc[4];
  #pragma unroll
  for(int nb=0;nb<4;nb++) acc[nb]=(f32x4){0.f,0.f,0.f,0.f};
  int4 ka0,ka1,va0,va1,ta0,ta1;
  tload(khb+(size_t)half*64*DH_, DH_, tid, ka0,ka1);
  tload(vhb+(size_t)half*64*DH_, DH_, tid, va0,va1);
  tload(ktb+half*64, N_, tid, ta0,ta1);
  for(int jt=half;jt<=it;jt+=2){
    int j0=jt<<6;
    __syncthreads();
    twrite(ks, tid, ka0,ka1);
    twrite(vs, tid, va0,va1);
    twrite(kts, tid, ta0,ta1);
    if(jt+2<=it){
      tload(khb+(size_t)(jt+2)*64*DH_, DH_, tid, ka0,ka1);
      tload(vhb+(size_t)(jt+2)*64*DH_, DH_, tid, va0,va1);
      tload(ktb+(jt+2)*64, N_, tid, ta0,ta1);
    }
    __syncthreads();
    f32x4 sv[4], dav[4];
    __builtin_amdgcn_s_setprio(1);
    #pragma unroll
    for(int nb=0;nb<4;nb++){
      f32x4 z={0.f,0.f,0.f,0.f}, zd={0.f,0.f,0.f,0.f};
      #pragma unroll
      for(int s=0;s<2;s++){
        bf16x8 bk=*(const bf16x8*)&ks[nb*16+ln][32*s+lg*8];
        bf16x8 bv=*(const bf16x8*)&vs[nb*16+ln][32*s+lg*8];
        z = MFMA_B16(aq[s], bk, z);
        zd= MFMA_B16(ad[s], bv, zd);
      }
      sv[nb]=z; dav[nb]=zd;
    }
    __builtin_amdgcn_s_setprio(0);
    #pragma unroll
    for(int r=0;r<4;r++){
      int ii=i0+w*16+lg*4+r;
      #pragma unroll
      for(int nb=0;nb<4;nb++){
        int jj=j0+nb*16+ln;
        float pv=__expf(sv[nb][r]*SCALE_F - Lr[r]);
        float dsv=SCALE_F*pv*(dav[nb][r]-dl[r]);
        if(jj>ii || ii>=NM_ || jj>=NM_) dsv=0.f;
        psb[w][lg*4+r][ln+16*nb]=f2bf(dsv);
      }
    }
    lds_fence();
    __builtin_amdgcn_s_setprio(1);
    #pragma unroll
    for(int nb=0;nb<4;nb++){
      #pragma unroll
      for(int s=0;s<2;s++){
        bf16x8 pa = *(const bf16x8*)&psb[w][ln][32*s+lg*8];
        bf16x8 bk = *(const bf16x8*)&kts[nb*16+ln][32*s+lg*8];
        acc[nb]=MFMA_B16(pa,bk,acc[nb]);
      }
    }
    __builtin_amdgcn_s_setprio(0);
    lds_fence();
  }
  short* dst = half? dqp1 : dqt;
  #pragma unroll
  for(int nb=0;nb<4;nb++){
    short4 s4;
    s4.x=f2bf(acc[nb][0]); s4.y=f2bf(acc[nb][1]);
    s4.z=f2bf(acc[nb][2]); s4.w=f2bf(acc[nb][3]);
    *(short4*)&dst[((size_t)bh*64 + nb*16+ln)*2048 + i0+w*16+lg*4]=s4;
  }
}

// dqt += dqp1 (bf16, deterministic)
__global__ __launch_bounds__(256) void k_dqred(short* __restrict__ dqt,
    const short* __restrict__ dqp1){
  size_t i = ((size_t)blockIdx.x*256 + threadIdx.x)*8;
  int4 a = *(const int4*)&dqt[i];
  int4 b = *(const int4*)&dqp1[i];
  short* pa=(short*)&a; const short* pb=(const short*)&b;
  short out[8];
  #pragma unroll
  for(int k=0;k<8;k++) out[k]=f2bf(bf2f(pa[k])+bf2f(pb[k]));
  *(int4*)&dqt[i] = *(int4*)out;
}

// ---------------- 12. flash backward dk,dv (2-way i-split) ----------------
__global__ __launch_bounds__(256) void k_fa_dkv(const short* __restrict__ kh,
    const short* __restrict__ vh, const short* __restrict__ qh,
    const short* __restrict__ qt, const short* __restrict__ doh,
    const short* __restrict__ dot,
    const float* __restrict__ lse, const float* __restrict__ delta,
    short* __restrict__ dkt, short* __restrict__ dvt,
    short* __restrict__ dkp1, short* __restrict__ dvp1){
  int bh = blockIdx.x, jt = blockIdx.y, half = blockIdx.z;
  int j0 = jt<<6;
  const short* khb = kh + (size_t)bh*N_*DH_;
  const short* vhb = vh + (size_t)bh*N_*DH_;
  const short* qhb = qh + (size_t)bh*N_*DH_;
  const short* qtb = qt + (size_t)bh*DH_*N_;
  const short* dohb= doh+ (size_t)bh*N_*DH_;
  const short* dotb= dot+ (size_t)bh*DH_*N_;
  __shared__ __attribute__((aligned(16))) short qs[64][LBK], dos[64][LBK], qts[64][LBK], dots[64][LBK];
  __shared__ __attribute__((aligned(16))) short psv[4][16][LBK], psk[4][16][LBK];
  __shared__ float Ls[64], dls[64];
  int tid=threadIdx.x, w=tid>>6, lane=tid&63, lg=lane>>4, ln=lane&15;
  bf16x8 akf[2], avf[2];
  #pragma unroll
  for(int s=0;s<2;s++){
    akf[s]=*(const bf16x8*)&khb[(size_t)(j0+w*16+ln)*DH_+32*s+lg*8];
    avf[s]=*(const bf16x8*)&vhb[(size_t)(j0+w*16+ln)*DH_+32*s+lg*8];
  }
  f32x4 accv[4], acck[4];
  #pragma unroll
  for(int nb=0;nb<4;nb++){
    accv[nb]=(f32x4){0.f,0.f,0.f,0.f};
    acck[nb]=(f32x4){0.f,0.f,0.f,0.f};
  }
  int it0 = jt + half;
  int4 qa0,qa1,da0,da1,qta0,qta1,dta0,dta1;
  float Lnx=0.f, dlnx=0.f;
  {
    int ip = (it0<32)? (it0<<6) : 0;    // clamp: zero-work block loads tile 0, unused
    tload(qhb+(size_t)ip*DH_, DH_, tid, qa0,qa1);
    tload(dohb+(size_t)ip*DH_, DH_, tid, da0,da1);
    tload(qtb+ip, N_, tid, qta0,qta1);
    tload(dotb+ip, N_, tid, dta0,dta1);
    if(tid<64){
      int ii=ip+tid;
      Lnx=lse[(size_t)bh*N_+ii];
      dlnx=(ii<NM_)?delta[(size_t)bh*N_+ii]:0.f;
    }
  }
  for(int it=it0; it<32; it+=2){
    int i0=it<<6;
    __syncthreads();
    twrite(qs, tid, qa0,qa1);
    twrite(dos, tid, da0,da1);
    twrite(qts, tid, qta0,qta1);
    twrite(dots, tid, dta0,dta1);
    if(tid<64){ Ls[tid]=Lnx; dls[tid]=dlnx; }
    if(it+2<32){
      int i1=(it+2)<<6;
      tload(qhb+(size_t)i1*DH_, DH_, tid, qa0,qa1);
      tload(dohb+(size_t)i1*DH_, DH_, tid, da0,da1);
      tload(qtb+i1, N_, tid, qta0,qta1);
      tload(dotb+i1, N_, tid, dta0,dta1);
      if(tid<64){
        int ii=i1+tid;
        Lnx=lse[(size_t)bh*N_+ii];
        dlnx=(ii<NM_)?delta[(size_t)bh*N_+ii]:0.f;
      }
    }
    __syncthreads();
    f32x4 sv[4], dav[4];
    __builtin_amdgcn_s_setprio(1);
    #pragma unroll
    for(int nb=0;nb<4;nb++){
      f32x4 z={0.f,0.f,0.f,0.f}, zd={0.f,0.f,0.f,0.f};
      #pragma unroll
      for(int s=0;s<2;s++){
        bf16x8 bq=*(const bf16x8*)&qs[nb*16+ln][32*s+lg*8];
        bf16x8 bd=*(const bf16x8*)&dos[nb*16+ln][32*s+lg*8];
        z = MFMA_B16(akf[s], bq, z);
        zd= MFMA_B16(avf[s], bd, zd);
      }
      sv[nb]=z; dav[nb]=zd;
    }
    __builtin_amdgcn_s_setprio(0);
    #pragma unroll
    for(int nb=0;nb<4;nb++){
      float Lc=Ls[nb*16+ln], dlc=dls[nb*16+ln];
      int ii=i0+nb*16+ln;
      #pragma unroll
      for(int r=0;r<4;r++){
        int jj=j0+w*16+lg*4+r;
        float pv=__expf(sv[nb][r]*SCALE_F - Lc);
        bool msk=(jj>ii)||(ii>=NM_)||(jj>=NM_);
        if(msk) pv=0.f;
        float ds = msk?0.f: SCALE_F*pv*(dav[nb][r]-dlc);
        psv[w][lg*4+r][ln+16*nb]=f2bf(pv);
        psk[w][lg*4+r][ln+16*nb]=f2bf(ds);
      }
    }
    lds_fence();
    __builtin_amdgcn_s_setprio(1);
    #pragma unroll
    for(int nb=0;nb<4;nb++){
      #pragma unroll
      for(int s=0;s<2;s++){
        bf16x8 pa = *(const bf16x8*)&psv[w][ln][32*s+lg*8];
        bf16x8 bd = *(const bf16x8*)&dots[nb*16+ln][32*s+lg*8];
        accv[nb]=MFMA_B16(pa,bd,accv[nb]);
        bf16x8 pk = *(const bf16x8*)&psk[w][ln][32*s+lg*8];
        bf16x8 bq = *(const bf16x8*)&qts[nb*16+ln][32*s+lg*8];
        acck[nb]=MFMA_B16(pk,bq,acck[nb]);
      }
    }
    __builtin_amdgcn_s_setprio(0);
    lds_fence();
  }
  short* dvd = half? dvp1 : dvt;
  short* dkd = half? dkp1 : dkt;
  #pragma unroll
  for(int nb=0;nb<4;nb++){
    int e=nb*16+ln, n0=j0+w*16+lg*4;
    short4 s4;
    s4.x=f2bf(accv[nb][0]); s4.y=f2bf(accv[nb][1]);
    s4.z=f2bf(accv[nb][2]); s4.w=f2bf(accv[nb][3]);
    *(short4*)&dvd[((size_t)bh*64+e)*2048 + n0]=s4;
    s4.x=f2bf(acck[nb][0]); s4.y=f2bf(acck[nb][1]);
    s4.z=f2bf(acck[nb][2]); s4.w=f2bf(acck[nb][3]);
    *(short4*)&dkd[((size_t)bh*64+e)*2048 + n0]=s4;
  }
}

// dkt += dkp1; dvt += dvp1
__global__ __launch_bounds__(256) void k_dkvred(short* __restrict__ dkt,
    short* __restrict__ dvt, const short* __restrict__ dkp1,
    const short* __restrict__ dvp1){
  int bid = blockIdx.x;
  short* dst; const short* src;
  if(bid<1024){ dst=dkt; src=dkp1; } else { dst=dvt; src=dvp1; bid-=1024; }
  size_t i = ((size_t)bid*256 + threadIdx.x)*8;
  int4 a = *(const int4*)&dst[i];
  int4 b = *(const int4*)&src[i];
  short* pa=(short*)&a; const short* pb=(const short*)&b;
  short out[8];
  #pragma unroll
  for(int k=0;k<8;k++) out[k]=f2bf(bf2f(pa[k])+bf2f(pb[k]));
  *(int4*)&dst[i] = *(int4*)out;
}

// ---------------- 13. weight grads (MFMA, split-K=8) ----------------
__global__ __launch_bounds__(256) void k_gemm_wgq(const short* __restrict__ tt,
    const short* __restrict__ g, float* __restrict__ par){
  __shared__ __attribute__((aligned(16))) short as[64][LBK], bs[64][LBK];
  int dt=blockIdx.x, h=blockIdx.y, sp=blockIdx.z;
  int b=sp>>2, n0b=(sp&3)*512;
  f32x4 acc[4];
  #pragma unroll
  for(int nb=0;nb<4;nb++) acc[nb]=(f32x4){0.f,0.f,0.f,0.f};
  gemm64(tt + (size_t)(dt*64)*4096 + sp*512, 4096,
         g  + ((size_t)(b*8+h)*64)*2048 + n0b, 2048, 8, as, bs, acc);
  int tid=threadIdx.x, w=tid>>6, lane=tid&63, lg=lane>>4, ln=lane&15;
  int row=w*16+lg*4;
  #pragma unroll
  for(int nb=0;nb<4;nb++)
    #pragma unroll
    for(int r=0;r<4;r++)
      par[(size_t)sp*262144 + (size_t)h*32768 + (size_t)(dt*64+row+r)*64 + nb*16+ln]=acc[nb][r];
}

__global__ __launch_bounds__(256) void k_gemm_wgo(const short* __restrict__ outt,
    const short* __restrict__ ert, float* __restrict__ par){
  __shared__ __attribute__((aligned(16))) short as[64][LBK], bs[64][LBK];
  int ct=blockIdx.x, h=blockIdx.y, sp=blockIdx.z;
  f32x4 acc[4];
  #pragma unroll
  for(int nb=0;nb<4;nb++) acc[nb]=(f32x4){0.f,0.f,0.f,0.f};
  gemm64(outt + (size_t)(h*64)*4096 + sp*512, 4096,
         ert  + (size_t)(ct*64)*4096 + sp*512, 4096, 8, as, bs, acc);
  int tid=threadIdx.x, w=tid>>6, lane=tid&63, lg=lane>>4, ln=lane&15;
  int row=w*16+lg*4;
  #pragma unroll
  for(int nb=0;nb<4;nb++)
    #pragma unroll
    for(int r=0;r<4;r++)
      par[(size_t)sp*262144 + (size_t)h*32768 + (size_t)(row+r)*512 + ct*64+nb*16+ln]=acc[nb][r];
}

__global__ __launch_bounds__(256) void k_wred_direct(const float* __restrict__ par,
    float* __restrict__ dst){
  int idx = blockIdx.x*256 + threadIdx.x;
  float s=0.f;
  #pragma unroll
  for(int sp=0;sp<8;sp++) s += par[(size_t)sp*262144 + idx];
  dst[idx]=s;
}
__global__ __launch_bounds__(256) void k_wred_xv(const float* __restrict__ par,
    float* __restrict__ X0){
  int idx = blockIdx.x*256 + threadIdx.x;
  float s=0.f;
  #pragma unroll
  for(int sp=0;sp<8;sp++) s += par[(size_t)sp*262144 + idx];
  int h=idx>>15, rem=idx&32767, d=rem>>6, e=rem&63;
  X0[(size_t)h*32768 + (size_t)e*512 + d]=s;
}
__global__ __launch_bounds__(256) void k_wred_xo(const float* __restrict__ par,
    float* __restrict__ X0){
  int idx = blockIdx.x*256 + threadIdx.x;
  float s=0.f;
  #pragma unroll
  for(int sp=0;sp<8;sp++) s += par[(size_t)sp*262144 + idx];
  X0[262144 + idx]=s;
}

// ---------------- 14. Newton-Schulz (f32) ----------------
#define LP 66
__global__ __launch_bounds__(256) void k_ns_scale(float* __restrict__ X){
  float* Xm = X + (size_t)blockIdx.x*32768;
  int tid=threadIdx.x;
  float ss=0.f;
  for(int i=tid;i<32768;i+=256){ float v=Xm[i]; ss+=v*v; }
  ss=wred64(ss);
  __shared__ float r[4];
  if((tid&63)==0) r[tid>>6]=ss;
  __syncthreads();
  float tot=r[0]+r[1]+r[2]+r[3];
  float sc = 1.f/fmaxf(sqrtf(tot), 1e-7f);
  for(int i=tid;i<32768;i+=256) Xm[i]*=sc;
}
__global__ __launch_bounds__(256) void k_ns_A(const float* __restrict__ X,
    float* __restrict__ A){
  const float* Xm = X + (size_t)blockIdx.x*32768;
  __shared__ float xs[64][LP];
  int tid=threadIdx.x, ty=tid>>4, tx=tid&15;
  float acc[4][4]={{0}};
  for(int d0=0;d0<512;d0+=64){
    __syncthreads();
    for(int kk=0;kk<16;kk++){
      int idx=kk*256+tid; int rr=idx>>6, cc=idx&63;
      xs[rr][cc]=Xm[(size_t)rr*512 + d0+cc];
    }
    __syncthreads();
    for(int kk=0;kk<64;kk++){
      float a[4], bb[4];
      #pragma unroll
      for(int r=0;r<4;r++) a[r]=xs[ty*4+r][kk];
      #pragma unroll
      for(int c=0;c<4;c++) bb[c]=xs[tx+16*c][kk];
      #pragma unroll
      for(int r=0;r<4;r++)
        #pragma unroll
        for(int c=0;c<4;c++) acc[r][c]+=a[r]*bb[c];
    }
  }
  #pragma unroll
  for(int r=0;r<4;r++)
    #pragma unroll
    for(int c=0;c<4;c++)
      A[(size_t)blockIdx.x*4096 + (size_t)(ty*4+r)*64 + tx+16*c]=acc[r][c];
}
__global__ __launch_bounds__(256) void k_ns_B(const float* __restrict__ A,
    float* __restrict__ Bm){
  __shared__ float as[64][LP];
  int tid=threadIdx.x, ty=tid>>4, tx=tid&15;
  for(int kk=0;kk<16;kk++){
    int idx=kk*256+tid; int rr=idx>>6, cc=idx&63;
    as[rr][cc]=A[(size_t)blockIdx.x*4096 + rr*64 + cc];
  }
  __syncthreads();
  float acc[4][4]={{0}};
  for(int kk=0;kk<64;kk++){
    float a[4], bb[4];
    #pragma unroll
    for(int r=0;r<4;r++) a[r]=as[ty*4+r][kk];
    #pragma unroll
    for(int c=0;c<4;c++) bb[c]=as[kk][tx+16*c];
    #pragma unroll
    for(int r=0;r<4;r++)
      #pragma unroll
      for(int c=0;c<4;c++) acc[r][c]+=a[r]*bb[c];
  }
  #pragma unroll
  for(int r=0;r<4;r++)
    #pragma unroll
    for(int c=0;c<4;c++)
      Bm[(size_t)blockIdx.x*4096 + (size_t)(ty*4+r)*64 + tx+16*c]
        = -4.775f*as[ty*4+r][tx+16*c] + 2.0315f*acc[r][c];
}
__global__ __launch_bounds__(256) void k_ns_update(const float* __restrict__ Xold,
    const float* __restrict__ Bm, float* __restrict__ Xnew){
  int ct=blockIdx.x, m=blockIdx.y;
  __shared__ float bs[64][LP], xs[64][LP];
  int tid=threadIdx.x, ty=tid>>4, tx=tid&15;
  for(int kk=0;kk<16;kk++){
    int idx=kk*256+tid; int rr=idx>>6, cc=idx&63;
    bs[rr][cc]=Bm[(size_t)m*4096 + rr*64 + cc];
    xs[rr][cc]=Xold[(size_t)m*32768 + (size_t)rr*512 + ct*64+cc];
  }
  __syncthreads();
  float acc[4][4]={{0}};
  for(int kk=0;kk<64;kk++){
    float a[4], bb[4];
    #pragma unroll
    for(int r=0;r<4;r++) a[r]=bs[ty*4+r][kk];
    #pragma unroll
    for(int c=0;c<4;c++) bb[c]=xs[kk][tx+16*c];
    #pragma unroll
    for(int r=0;r<4;r++)
      #pragma unroll
      for(int c=0;c<4;c++) acc[r][c]+=a[r]*bb[c];
  }
  #pragma unroll
  for(int r=0;r<4;r++)
    #pragma unroll
    for(int c=0;c<4;c++)
      Xnew[(size_t)m*32768 + (size_t)(ty*4+r)*512 + ct*64+tx+16*c]
        = 3.4445f*xs[ty*4+r][tx+16*c] + acc[r][c];
}
__global__ __launch_bounds__(256) void k_ns_final(const float* __restrict__ X,
    float* __restrict__ dwv, float* __restrict__ dwo){
  int idx = blockIdx.x*256 + threadIdx.x;
  int m = idx>>15, rem = idx&32767, e = rem>>9, d = rem&511;
  float v = X[idx];
  if(m<8) dwv[(size_t)m*32768 + (size_t)d*64 + e] = v;
  else    dwo[(size_t)(m-8)*32768 + (size_t)e*512 + d] = v;
}

// ---------------- launch ----------------
extern "C" void kernel_launch(void* const* d_in, const int* in_sizes, int n_in,
                              void* d_out, int out_size, void* d_ws, size_t ws_size,
                              hipStream_t stream) {
  const float* tokens=(const float*)d_in[0];
  const float* rmsw =(const float*)d_in[1];
  const float* wq   =(const float*)d_in[2];
  const float* wk   =(const float*)d_in[3];
  const float* wv   =(const float*)d_in[4];
  const float* wo   =(const float*)d_in[5];
  const float* lrw  =(const float*)d_in[6];
  const float* tvw  =(const float*)d_in[7];
  float* out = (float*)d_out;
  float* ws  = (float*)d_ws;

  short* tb   = (short*)(ws);            // [4160][512] bf16 (pad rows zero)
  short* tt   = (short*)(ws + 1064960);  // [512][4096]
  short* qh   = (short*)(ws + 2113536);  // [16bh][2048][64]
  short* kh   = (short*)(ws + 3162112);
  short* vh   = (short*)(ws + 4210688);
  short* qt   = (short*)(ws + 5259264);  // [16bh][64][2048]
  short* kt   = (short*)(ws + 6307840);
  short* vt   = (short*)(ws + 7356416);
  float* ob_  = ws + 8404992;            // f32 [4096][512]; er_ aliases; then partial bufs
  float* er_  = ws + 8404992;
  short* dqp1 = (short*)(ws + 8404992);  // 4MB partial (after er_ dead)
  short* dkp1 = (short*)(ws + 8404992);  // reuses dqp1 after dqred
  short* dvp1 = (short*)(ws + 9453568);  // next 4MB
  short* obb  = (short*)(ws + 10502144); // bf16 [4096][512]
  short* outt = (short*)(ws + 11550720); // bf16 [512][4096]
  short* erb  = (short*)(ws + 12599296);
  short* ert  = (short*)(ws + 13647872);
  short* doh  = (short*)(ws + 14696448); // [16bh][2048][64]
  short* dot  = (short*)(ws + 15745024); // [16bh][64][2048]
  float* par_ = ws + 14696448;           // aliases doh+dot (dead before wgrad)
  short* dqt  = (short*)(ws + 16793600); // [16bh][64][2048]
  short* dkt  = (short*)(ws + 17842176);
  short* dvt  = (short*)(ws + 18890752);
  short* wqt  = (short*)(ws + 19939328); // [8h][64][512]
  short* wkt  = (short*)(ws + 20070400);
  short* wvt  = (short*)(ws + 20201472);
  short* wob  = (short*)(ws + 20332544); // [512 he][512 d]
  short* wot  = (short*)(ws + 20463616); // [512 d][512 he]
  short* tvwb = (short*)(ws + 20594688); // [512 o][512 d]
  float* lse_ = ws + 20725760;
  float* dlt_ = ws + 20758528;
  float* X0_  = ws + 20791296;
  float* X1_  = ws + 21315584;
  float* Am_  = ws + 21839872;
  float* Bm_  = ws + 21905408;

  float* OUT_PRED = out;
  float* OUT_DWQ  = out + 2097152;
  float* OUT_DWK  = out + 2359296;
  float* OUT_DWV  = out + 2621440;
  float* OUT_DWO  = out + 2883584;

  k_rmsnorm<<<4160,256,0,stream>>>(tokens, rmsw, tb);
  k_wprep<<<272,256,0,stream>>>(wq,wk,wv,wo,tvw, wqt,wkt,wvt,wob,wot,tvwb);
  k_gemm_qkv<<<dim3(64,24),256,0,stream>>>(tb, wqt,wkt,wvt, qh,kh,vh, qt,kt,vt);
  k_fa_fwd<<<dim3(16,32),256,0,stream>>>(qh, kh, vt, ob_, lse_);
  k_trans_f<<<dim3(64,8),256,0,stream>>>(ob_, obb, outt);
  k_gemm_pred<<<dim3(64,8),256,0,stream>>>(obb, wot, OUT_PRED);

  if(out_size < 3145728) return;   // forward-only variant

  k_trans_b<<<dim3(64,8),256,0,stream>>>(tb, tt);
  k_gemm_tv<<<dim3(64,8),256,0,stream>>>(tb, tvwb, er_);
  k_lnerr<<<4094,256,0,stream>>>(er_, tb, OUT_PRED, lrw);
  k_trans_f<<<dim3(64,8),256,0,stream>>>(er_, erb, ert);
  k_gemm_dout<<<dim3(64,8),256,0,stream>>>(erb, wob, doh, dot);
  k_delta<<<8188,256,0,stream>>>(doh, obb, dlt_);
  k_fa_dq<<<dim3(16,32,2),256,0,stream>>>(qh, kh, vh, kt, doh, lse_, dlt_, dqt, dqp1);
  k_dqred<<<1024,256,0,stream>>>(dqt, dqp1);
  k_fa_dkv<<<dim3(16,32,2),256,0,stream>>>(kh, vh, qh, qt, doh, dot, lse_, dlt_,
                                           dkt, dvt, dkp1, dvp1);
  k_dkvred<<<2048,256,0,stream>>>(dkt, dvt, dkp1, dvp1);

  k_gemm_wgq<<<dim3(8,8,8),256,0,stream>>>(tt, dqt, par_);
  k_wred_direct<<<1024,256,0,stream>>>(par_, OUT_DWQ);
  k_gemm_wgq<<<dim3(8,8,8),256,0,stream>>>(tt, dkt, par_);
  k_wred_direct<<<1024,256,0,stream>>>(par_, OUT_DWK);
  k_gemm_wgq<<<dim3(8,8,8),256,0,stream>>>(tt, dvt, par_);
  k_wred_xv<<<1024,256,0,stream>>>(par_, X0_);
  k_gemm_wgo<<<dim3(8,8,8),256,0,stream>>>(outt, ert, par_);
  k_wred_xo<<<1024,256,0,stream>>>(par_, X0_);

  k_ns_scale<<<16,256,0,stream>>>(X0_);
  float* xa = X0_; float* xb = X1_;
  for(int itr=0; itr<5; ++itr){
    k_ns_A<<<16,256,0,stream>>>(xa, Am_);
    k_ns_B<<<16,256,0,stream>>>(Am_, Bm_);
    k_ns_update<<<dim3(8,16),256,0,stream>>>(xa, Bm_, xb);
    float* tmp = xa; xa = xb; xb = tmp;
  }
  k_ns_final<<<2048,256,0,stream>>>(xa, OUT_DWV, OUT_DWO);
}

// Round 8
// 318.551 us; speedup vs baseline: 8.7806x; 1.6050x over previous
//
#include <hip/hip_runtime.h>
#include <float.h>
#include <math.h>

// ---------------- problem constants ----------------
#define B_   2
#define N_   2048
#define D_   512
#define H_   8
#define DH_  64
#define NM_  2047            // n-1
#define SCALE_F 0.125f       // 64^-0.5
#define LBK 72               // LDS row pad (bf16 tiles), 144B: 16B-aligned rows

typedef __attribute__((ext_vector_type(8))) short bf16x8;
typedef __attribute__((ext_vector_type(4))) float f32x4;
#define MFMA_B16(a,b,c) __builtin_amdgcn_mfma_f32_16x16x32_bf16(a,b,c,0,0,0)

__device__ __forceinline__ short f2bf(float f){
  unsigned u = __float_as_uint(f);
  unsigned r = u + 0x7fffu + ((u>>16)&1u);
  return (short)(r>>16);
}
__device__ __forceinline__ float bf2f(short s){
  return __uint_as_float(((unsigned)(unsigned short)s)<<16);
}
__device__ __forceinline__ void lds_fence(){
  asm volatile("s_waitcnt lgkmcnt(0)" ::: "memory");
  __builtin_amdgcn_sched_barrier(0);
}
// load a 64x64 bf16 tile into regs (2 int4 per thread); pairs with twrite
__device__ __forceinline__ void tload(const short* __restrict__ src, size_t stride,
                                      int tid, int4& r0, int4& r1){
  int rr = tid>>2, cc = (tid&3)<<4;
  r0 = *(const int4*)&src[(size_t)rr*stride + cc];
  r1 = *(const int4*)&src[(size_t)rr*stride + cc + 8];
}
__device__ __forceinline__ void twrite(short (*dst)[LBK], int tid,
                                       const int4& r0, const int4& r1){
  int rr = tid>>2, cc = (tid&3)<<4;
  *(int4*)&dst[rr][cc]   = r0;
  *(int4*)&dst[rr][cc+8] = r1;
}
__device__ __forceinline__ float wred64(float v){
  #pragma unroll
  for(int off=32; off; off>>=1) v += __shfl_down(v, off, 64);
  return v;
}

// 64x64 MFMA GEMM mainloop with register-prefetch double buffering (2-phase)
__device__ __forceinline__ void gemm64(const short* __restrict__ A, size_t lda,
    const short* __restrict__ Bt, size_t ldb, int nk,
    short (*as)[LBK], short (*bs)[LBK], f32x4* acc){
  int tid=threadIdx.x, w=tid>>6, lane=tid&63, lg=lane>>4, ln=lane&15;
  int4 a0,a1,b0,b1;
  tload(A, lda, tid, a0,a1);
  tload(Bt, ldb, tid, b0,b1);
  for(int kt=0;kt<nk;++kt){
    __syncthreads();
    twrite(as, tid, a0,a1);
    twrite(bs, tid, b0,b1);
    if(kt+1<nk){
      tload(A +(size_t)(kt+1)*64, lda, tid, a0,a1);
      tload(Bt+(size_t)(kt+1)*64, ldb, tid, b0,b1);
    }
    __syncthreads();
    __builtin_amdgcn_s_setprio(1);
    #pragma unroll
    for(int s=0;s<2;s++){
      bf16x8 a = *(const bf16x8*)&as[w*16+ln][32*s+lg*8];
      #pragma unroll
      for(int nb=0;nb<4;nb++){
        bf16x8 b = *(const bf16x8*)&bs[nb*16+ln][32*s+lg*8];
        acc[nb]=MFMA_B16(a,b,acc[nb]);
      }
    }
    __builtin_amdgcn_s_setprio(0);
  }
}

// ---------------- 1. RMSNorm -> tb (bf16, padded to 4160 rows) ----------------
__global__ __launch_bounds__(256) void k_rmsnorm(const float* __restrict__ tok,
    const float* __restrict__ w, short* __restrict__ tb){
  int row = blockIdx.x;
  int tid = threadIdx.x;
  if(row>=4096){ tb[(size_t)row*D_+tid]=0; tb[(size_t)row*D_+tid+256]=0; return; }
  const float* x = tok + (size_t)row*D_;
  float v0 = x[tid], v1 = x[tid+256];
  float s = v0*v0 + v1*v1;
  s = wred64(s);
  __shared__ float red[4];
  if((tid&63)==0) red[tid>>6] = s;
  __syncthreads();
  float tot = red[0]+red[1]+red[2]+red[3];
  float sc = rsqrtf(tot*(1.f/512.f) + 1.1920929e-7f);
  tb[(size_t)row*D_+tid]     = f2bf(v0*sc*w[tid]);
  tb[(size_t)row*D_+tid+256] = f2bf(v1*sc*w[tid+256]);
}

// ---------------- 2. weight prep ----------------
__global__ __launch_bounds__(256) void k_wprep(const float* __restrict__ wq,
    const float* __restrict__ wk, const float* __restrict__ wv,
    const float* __restrict__ wo, const float* __restrict__ tvw,
    short* __restrict__ wqt, short* __restrict__ wkt, short* __restrict__ wvt,
    short* __restrict__ wob, short* __restrict__ wot, short* __restrict__ tvwb){
  __shared__ short l[64][66];
  int bx=blockIdx.x, tid=threadIdx.x;
  if(bx<192){
    const float* w = (bx<64)? wq : (bx<128)? wk : wv;
    short* wt      = (bx<64)? wqt: (bx<128)? wkt: wvt;
    int lb=bx&63, h=lb>>3, d0=(lb&7)*64;
    for(int kk=0;kk<16;kk++){
      int idx=kk*256+tid, rr=idx>>6, cc=idx&63;
      l[cc][rr] = f2bf(w[((size_t)h*512 + d0+rr)*64 + cc]);
    }
    __syncthreads();
    for(int kk=0;kk<16;kk++){
      int idx=kk*256+tid, rr=idx>>6, cc=idx&63;
      wt[((size_t)h*64+rr)*512 + d0+cc] = l[rr][cc];
    }
  } else if(bx<256){
    int lb=bx-192, r0=(lb>>3)*64, c0=(lb&7)*64;
    for(int kk=0;kk<16;kk++){
      int idx=kk*256+tid, rr=idx>>6, cc=idx&63;
      l[cc][rr] = f2bf(wo[(size_t)(r0+rr)*512 + c0+cc]);
    }
    __syncthreads();
    for(int kk=0;kk<16;kk++){
      int idx=kk*256+tid, rr=idx>>6, cc=idx&63;
      wot[(size_t)(c0+rr)*512 + r0+cc] = l[rr][cc];
    }
  } else if(bx<264){
    size_t base=(size_t)(bx-256)*32768;
    for(int kk=0;kk<128;kk++) wob[base+kk*256+tid]=f2bf(wo[base+kk*256+tid]);
  } else {
    size_t base=(size_t)(bx-264)*32768;
    for(int kk=0;kk<128;kk++) tvwb[base+kk*256+tid]=f2bf(tvw[base+kk*256+tid]);
  }
}

// ---------------- 3. transposes (4096x512) ----------------
__global__ __launch_bounds__(256) void k_trans_b(const short* __restrict__ in,
    short* __restrict__ outt){
  __shared__ short l[64][66];
  int r0=blockIdx.x<<6, c0=blockIdx.y<<6, tid=threadIdx.x;
  for(int kk=0;kk<16;kk++){
    int idx=kk*256+tid, rr=idx>>6, cc=idx&63;
    l[cc][rr]=in[(size_t)(r0+rr)*512 + c0+cc];
  }
  __syncthreads();
  for(int kk=0;kk<16;kk++){
    int idx=kk*256+tid, rr=idx>>6, cc=idx&63;
    outt[(size_t)(c0+rr)*4096 + r0+cc]=l[rr][cc];
  }
}
__global__ __launch_bounds__(256) void k_trans_f(const float* __restrict__ in,
    short* __restrict__ outn, short* __restrict__ outt){
  __shared__ short l[64][66];
  int r0=blockIdx.x<<6, c0=blockIdx.y<<6, tid=threadIdx.x;
  for(int kk=0;kk<16;kk++){
    int idx=kk*256+tid, rr=idx>>6, cc=idx&63;
    short v=f2bf(in[(size_t)(r0+rr)*512 + c0+cc]);
    outn[(size_t)(r0+rr)*512 + c0+cc]=v;
    l[cc][rr]=v;
  }
  __syncthreads();
  for(int kk=0;kk<16;kk++){
    int idx=kk*256+tid, rr=idx>>6, cc=idx&63;
    outt[(size_t)(c0+rr)*4096 + r0+cc]=l[rr][cc];
  }
}

// ---------------- 4. QKV projection (MFMA) ----------------
__global__ __launch_bounds__(256) void k_gemm_qkv(const short* __restrict__ tb,
    const short* __restrict__ wqt, const short* __restrict__ wkt, const short* __restrict__ wvt,
    short* __restrict__ qh, short* __restrict__ kh, short* __restrict__ vh,
    short* __restrict__ qt, short* __restrict__ kt, short* __restrict__ vt){
  __shared__ __attribute__((aligned(16))) short as[64][LBK], bs[64][LBK];
  int r0=blockIdx.x<<6, ct=blockIdx.y, which=ct>>3, h=ct&7;
  const short* Bt=(which==0?wqt:which==1?wkt:wvt)+(size_t)h*32768;
  f32x4 acc[4];
  #pragma unroll
  for(int nb=0;nb<4;nb++) acc[nb]=(f32x4){0.f,0.f,0.f,0.f};
  gemm64(tb+(size_t)r0*512, 512, Bt, 512, 8, as, bs, acc);
  short* on=(which==0?qh:which==1?kh:vh);
  short* ot=(which==0?qt:which==1?kt:vt);
  int tid=threadIdx.x, w=tid>>6, lane=tid&63, lg=lane>>4, ln=lane&15;
  size_t bh=(size_t)(r0>>11)*8+h;
  int n0=(r0&2047)+w*16+lg*4;
  #pragma unroll
  for(int nb=0;nb<4;nb++){
    int e=nb*16+ln;
    short4 s4;
    s4.x=f2bf(acc[nb][0]); s4.y=f2bf(acc[nb][1]);
    s4.z=f2bf(acc[nb][2]); s4.w=f2bf(acc[nb][3]);
    on[(bh*2048+n0  )*64+e]=s4.x;
    on[(bh*2048+n0+1)*64+e]=s4.y;
    on[(bh*2048+n0+2)*64+e]=s4.z;
    on[(bh*2048+n0+3)*64+e]=s4.w;
    *(short4*)&ot[(bh*64+e)*2048+n0]=s4;
  }
}

// ---------------- 5. flash attention forward (2-way j-split, partials) ----------------
// grid (16 bh, 32 q, 2 half); it = q<16 ? 31-q : q-16 (heavy blocks dispatch first)
__global__ __launch_bounds__(256) void k_fa_fwd(const short* __restrict__ qh,
    const short* __restrict__ kh, const short* __restrict__ vt,
    float* __restrict__ op0, float* __restrict__ op1, float* __restrict__ mlb){
  int bh = blockIdx.x, qq = blockIdx.y, half = blockIdx.z;
  int it = (qq<16)? (31-qq) : (qq-16);
  int i0 = it<<6;
  const short* qhb = qh + (size_t)bh*N_*DH_;
  const short* khb = kh + (size_t)bh*N_*DH_;
  const short* vtb = vt + (size_t)bh*DH_*N_;
  __shared__ __attribute__((aligned(16))) short ks[64][LBK], vts[64][LBK];
  __shared__ __attribute__((aligned(16))) short psb[4][16][LBK];
  int tid=threadIdx.x, w=tid>>6, lane=tid&63, lg=lane>>4, ln=lane&15;
  bf16x8 aq[2];
  #pragma unroll
  for(int s=0;s<2;s++)
    aq[s] = *(const bf16x8*)&qhb[(size_t)(i0+w*16+ln)*DH_ + 32*s + lg*8];
  f32x4 acc[4];
  float mrow[4], lrow[4];
  #pragma unroll
  for(int nb=0;nb<4;nb++) acc[nb]=(f32x4){0.f,0.f,0.f,0.f};
  #pragma unroll
  for(int r=0;r<4;r++){ mrow[r]=-FLT_MAX; lrow[r]=0.f; }
  int4 ka0,ka1,va0,va1;
  tload(khb+(size_t)half*64*DH_, DH_, tid, ka0,ka1);
  tload(vtb+half*64, N_, tid, va0,va1);
  for(int jt=half;jt<=it;jt+=2){
    int j0 = jt<<6;
    __syncthreads();
    twrite(ks, tid, ka0,ka1);
    twrite(vts, tid, va0,va1);
    if(jt+2<=it){
      tload(khb+(size_t)(jt+2)*64*DH_, DH_, tid, ka0,ka1);
      tload(vtb+(jt+2)*64, N_, tid, va0,va1);
    }
    __syncthreads();
    f32x4 sv[4];
    __builtin_amdgcn_s_setprio(1);
    #pragma unroll
    for(int nb=0;nb<4;nb++){
      f32x4 z = {0.f,0.f,0.f,0.f};
      #pragma unroll
      for(int s=0;s<2;s++){
        bf16x8 bk = *(const bf16x8*)&ks[nb*16+ln][32*s + lg*8];
        z = MFMA_B16(aq[s], bk, z);
      }
      sv[nb]=z;
    }
    __builtin_amdgcn_s_setprio(0);
    int iiB = i0 + w*16 + lg*4;
    #pragma unroll
    for(int r=0;r<4;r++){
      int ii = iiB + r;
      float srow[4]; float mx = -FLT_MAX;
      #pragma unroll
      for(int nb=0;nb<4;nb++){
        float x = sv[nb][r]*SCALE_F;
        if(j0+nb*16+ln > ii) x = -FLT_MAX;
        srow[nb]=x; mx=fmaxf(mx,x);
      }
      mx=fmaxf(mx,__shfl_xor(mx,1)); mx=fmaxf(mx,__shfl_xor(mx,2));
      mx=fmaxf(mx,__shfl_xor(mx,4)); mx=fmaxf(mx,__shfl_xor(mx,8));
      float mn = fmaxf(mrow[r], mx);
      float rs = 0.f;
      #pragma unroll
      for(int nb=0;nb<4;nb++){
        float pv = __expf(srow[nb]-mn);
        psb[w][lg*4+r][ln+16*nb]=f2bf(pv); rs+=pv;
      }
      rs+=__shfl_xor(rs,1); rs+=__shfl_xor(rs,2);
      rs+=__shfl_xor(rs,4); rs+=__shfl_xor(rs,8);
      float corr = __expf(mrow[r]-mn);
      lrow[r]=lrow[r]*corr+rs; mrow[r]=mn;
      #pragma unroll
      for(int nb=0;nb<4;nb++) acc[nb][r]*=corr;
    }
    lds_fence();
    __builtin_amdgcn_s_setprio(1);
    #pragma unroll
    for(int nb=0;nb<4;nb++){
      #pragma unroll
      for(int s=0;s<2;s++){
        bf16x8 pa = *(const bf16x8*)&psb[w][ln][32*s + lg*8];
        bf16x8 bv = *(const bf16x8*)&vts[nb*16+ln][32*s + lg*8];
        acc[nb] = MFMA_B16(pa, bv, acc[nb]);
      }
    }
    __builtin_amdgcn_s_setprio(0);
    lds_fence();
  }
  float* op   = half? op1 : op0;
  float* marr = mlb + half*65536;
  float* larr = marr + 32768;
  #pragma unroll
  for(int r=0;r<4;r++){
    int ii = i0 + w*16 + lg*4 + r;
    size_t row = (size_t)bh*2048 + ii;
    #pragma unroll
    for(int nb=0;nb<4;nb++)
      op[row*64 + nb*16+ln] = acc[nb][r];
    if(ln==0){ marr[row]=mrow[r]; larr[row]=lrow[r]; }
  }
}

// merge two softmax partials -> obb bf16 + lse
__global__ __launch_bounds__(256) void k_fa_merge(const float* __restrict__ op0,
    const float* __restrict__ op1, const float* __restrict__ mlb,
    short* __restrict__ obb, float* __restrict__ lse){
  int row = blockIdx.x*4 + (threadIdx.x>>6);
  int lane = threadIdx.x&63;
  float m0 = mlb[row],        l0 = mlb[32768+row];
  float m1 = mlb[65536+row],  l1 = mlb[98304+row];
  float m  = fmaxf(m0,m1);
  float c0 = __expf(m0-m), c1 = __expf(m1-m);
  float l  = l0*c0 + l1*c1;
  float o  = (op0[(size_t)row*64+lane]*c0 + op1[(size_t)row*64+lane]*c1)/l;
  int bh = row>>11, i = row&2047, b = bh>>3, h = bh&7;
  obb[((size_t)(b*2048+i))*512 + h*64 + lane] = f2bf(o);
  if(lane==0) lse[row] = m + logf(l);
}

// ---------------- 6. pred = obb @ wot^T (MFMA), f32 out ----------------
__global__ __launch_bounds__(256) void k_gemm_pred(const short* __restrict__ obb,
    const short* __restrict__ wot, float* __restrict__ pred){
  __shared__ __attribute__((aligned(16))) short as[64][LBK], bs[64][LBK];
  int r0=blockIdx.x<<6, c0=blockIdx.y<<6;
  f32x4 acc[4];
  #pragma unroll
  for(int nb=0;nb<4;nb++) acc[nb]=(f32x4){0.f,0.f,0.f,0.f};
  gemm64(obb+(size_t)r0*512, 512, wot+(size_t)c0*512, 512, 8, as, bs, acc);
  int tid=threadIdx.x, w=tid>>6, lane=tid&63, lg=lane>>4, ln=lane&15;
  int row=r0+w*16+lg*4;
  #pragma unroll
  for(int nb=0;nb<4;nb++)
    #pragma unroll
    for(int r=0;r<4;r++)
      pred[(size_t)(row+r)*512 + c0+nb*16+ln]=acc[nb][r];
}

// ---------------- 7. tv = tb(shift+1) @ tvwb^T ----------------
__global__ __launch_bounds__(256) void k_gemm_tv(const short* __restrict__ tb,
    const short* __restrict__ tvwb, float* __restrict__ er){
  __shared__ __attribute__((aligned(16))) short as[64][LBK], bs[64][LBK];
  int r0=blockIdx.x<<6, c0=blockIdx.y<<6;
  f32x4 acc[4];
  #pragma unroll
  for(int nb=0;nb<4;nb++) acc[nb]=(f32x4){0.f,0.f,0.f,0.f};
  gemm64(tb+(size_t)(r0+1)*512, 512, tvwb+(size_t)c0*512, 512, 8, as, bs, acc);
  int tid=threadIdx.x, w=tid>>6, lane=tid&63, lg=lane>>4, ln=lane&15;
  int row=r0+w*16+lg*4;
  #pragma unroll
  for(int nb=0;nb<4;nb++)
    #pragma unroll
    for(int r=0;r<4;r++){
      float v=(((row+r)&2047)==2047)?0.f:acc[nb][r];
      er[(size_t)(row+r)*512 + c0+nb*16+ln]=v;
    }
}

// ---------------- 8. layernorm target + lr + error ----------------
__global__ __launch_bounds__(256) void k_lnerr(float* __restrict__ er,
    const short* __restrict__ tb, const float* __restrict__ pred,
    const float* __restrict__ lrw){
  int kr = blockIdx.x;
  int b = kr/NM_, n = kr-b*NM_;
  size_t row=(size_t)b*2048+n;
  float* tv = er + row*512;
  const short* tok = tb + row*512;
  const float* pr  = pred + row*512;
  int tid=threadIdx.x;
  float v0=tv[tid], v1=tv[tid+256];
  float s1=v0+v1, s2=v0*v0+v1*v1;
  float s3=bf2f(tok[tid])*lrw[tid] + bf2f(tok[tid+256])*lrw[tid+256];
  s1=wred64(s1); s2=wred64(s2); s3=wred64(s3);
  __shared__ float r1[4],r2[4],r3[4];
  if((tid&63)==0){ int w=tid>>6; r1[w]=s1; r2[w]=s2; r3[w]=s3; }
  __syncthreads();
  float S1=r1[0]+r1[1]+r1[2]+r1[3];
  float S2=r2[0]+r2[1]+r2[2]+r2[3];
  float S3=r3[0]+r3[1]+r3[2]+r3[3];
  float mu  = S1*(1.f/512.f);
  float var = S2*(1.f/512.f) - mu*mu;
  float rstd= rsqrtf(var + 1e-5f);
  float lr  = 0.01f/(1.f+__expf(-S3));
  tv[tid]     = ((v0-mu)*rstd - pr[tid])*lr;
  tv[tid+256] = ((v1-mu)*rstd - pr[tid+256])*lr;
}

// ---------------- 9. dout = erb @ wob^T (MFMA) -> doh + dot bf16 ----------------
__global__ __launch_bounds__(256) void k_gemm_dout(const short* __restrict__ erb,
    const short* __restrict__ wob, short* __restrict__ doh, short* __restrict__ dot){
  __shared__ __attribute__((aligned(16))) short as[64][LBK], bs[64][LBK];
  int r0=blockIdx.x<<6, h=blockIdx.y;
  f32x4 acc[4];
  #pragma unroll
  for(int nb=0;nb<4;nb++) acc[nb]=(f32x4){0.f,0.f,0.f,0.f};
  gemm64(erb+(size_t)r0*512, 512, wob+(size_t)h*32768, 512, 8, as, bs, acc);
  int tid=threadIdx.x, w=tid>>6, lane=tid&63, lg=lane>>4, ln=lane&15;
  size_t bh=(size_t)(r0>>11)*8+h;
  int n0=(r0&2047)+w*16+lg*4;
  #pragma unroll
  for(int nb=0;nb<4;nb++){
    int e=nb*16+ln;
    short4 s4;
    s4.x=f2bf(acc[nb][0]); s4.y=f2bf(acc[nb][1]);
    s4.z=f2bf(acc[nb][2]); s4.w=f2bf(acc[nb][3]);
    doh[(bh*2048+n0  )*64+e]=s4.x;
    doh[(bh*2048+n0+1)*64+e]=s4.y;
    doh[(bh*2048+n0+2)*64+e]=s4.z;
    doh[(bh*2048+n0+3)*64+e]=s4.w;
    *(short4*)&dot[(bh*64+e)*2048+n0]=s4;
  }
}

// ---------------- 10. delta = sum_e dout*out ----------------
__global__ __launch_bounds__(256) void k_delta(const short* __restrict__ doh,
    const short* __restrict__ obb, float* __restrict__ delta){
  int rid = blockIdx.x*4 + (threadIdx.x>>6);
  int lane = threadIdx.x&63;
  if(rid >= B_*H_*NM_) return;
  int b = rid/(H_*NM_); int rem = rid - b*H_*NM_;
  int h = rem/NM_; int i = rem - h*NM_;
  float v = bf2f(doh[((size_t)(b*H_+h)*N_ + i)*DH_ + lane])
          * bf2f(obb[((size_t)(b*N_+i))*D_ + h*DH_ + lane]);
  v = wred64(v);
  if(lane==0) delta[((size_t)(b*H_+h))*N_ + i] = v;
}

// ---------------- 11. flash backward dq (2-way j-split) -> dqt + dqp1 ----------------
__global__ __launch_bounds__(256) void k_fa_dq(const short* __restrict__ qh,
    const short* __restrict__ kh, const short* __restrict__ vh,
    const short* __restrict__ kt, const short* __restrict__ doh,
    const float* __restrict__ lse, const float* __restrict__ delta,
    short* __restrict__ dqt, short* __restrict__ dqp1){
  int bh = blockIdx.x, it = blockIdx.y, half = blockIdx.z;
  int i0 = it<<6;
  const short* qhb = qh + (size_t)bh*N_*DH_;
  const short* khb = kh + (size_t)bh*N_*DH_;
  const short* vhb = vh + (size_t)bh*N_*DH_;
  const short* ktb = kt + (size_t)bh*DH_*N_;
  const short* dohb= doh+ (size_t)bh*N_*DH_;
  __shared__ __attribute__((aligned(16))) short ks[64][LBK], vs[64][LBK], kts[64][LBK];
  __shared__ __attribute__((aligned(16))) short psb[4][16][LBK];
  int tid=threadIdx.x, w=tid>>6, lane=tid&63, lg=lane>>4, ln=lane&15;
  bf16x8 aq[2], ad[2];
  float Lr[4], dl[4];
  #pragma unroll
  for(int s=0;s<2;s++){
    aq[s]=*(const bf16x8*)&qhb[(size_t)(i0+w*16+ln)*DH_+32*s+lg*8];
    ad[s]=*(const bf16x8*)&dohb[(size_t)(i0+w*16+ln)*DH_+32*s+lg*8];
  }
  #pragma unroll
  for(int r=0;r<4;r++){
    int ii=i0+w*16+lg*4+r;
    Lr[r]=lse[(size_t)bh*N_+ii];
    dl[r]=(ii<NM_)?delta[(size_t)bh*N_+ii]:0.f;
  }
  f32x4 acc[4];
  #pragma unroll
  for(int nb=0;nb<4;nb++) acc[nb]=(f32x4){0.f,0.f,0.f,0.f};
  int4 ka0,ka1,va0,va1,ta0,ta1;
  tload(khb+(size_t)half*64*DH_, DH_, tid, ka0,ka1);
  tload(vhb+(size_t)half*64*DH_, DH_, tid, va0,va1);
  tload(ktb+half*64, N_, tid, ta0,ta1);
  for(int jt=half;jt<=it;jt+=2){
    int j0=jt<<6;
    __syncthreads();
    twrite(ks, tid, ka0,ka1);
    twrite(vs, tid, va0,va1);
    twrite(kts, tid, ta0,ta1);
    if(jt+2<=it){
      tload(khb+(size_t)(jt+2)*64*DH_, DH_, tid, ka0,ka1);
      tload(vhb+(size_t)(jt+2)*64*DH_, DH_, tid, va0,va1);
      tload(ktb+(jt+2)*64, N_, tid, ta0,ta1);
    }
    __syncthreads();
    f32x4 sv[4], dav[4];
    __builtin_amdgcn_s_setprio(1);
    #pragma unroll
    for(int nb=0;nb<4;nb++){
      f32x4 z={0.f,0.f,0.f,0.f}, zd={0.f,0.f,0.f,0.f};
      #pragma unroll
      for(int s=0;s<2;s++){
        bf16x8 bk=*(const bf16x8*)&ks[nb*16+ln][32*s+lg*8];
        bf16x8 bv=*(const bf16x8*)&vs[nb*16+ln][32*s+lg*8];
        z = MFMA_B16(aq[s], bk, z);
        zd= MFMA_B16(ad[s], bv, zd);
      }
      sv[nb]=z; dav[nb]=zd;
    }
    __builtin_amdgcn_s_setprio(0);
    #pragma unroll
    for(int r=0;r<4;r++){
      int ii=i0+w*16+lg*4+r;
      #pragma unroll
      for(int nb=0;nb<4;nb++){
        int jj=j0+nb*16+ln;
        float pv=__expf(sv[nb][r]*SCALE_F - Lr[r]);
        float dsv=SCALE_F*pv*(dav[nb][r]-dl[r]);
        if(jj>ii || ii>=NM_ || jj>=NM_) dsv=0.f;
        psb[w][lg*4+r][ln+16*nb]=f2bf(dsv);
      }
    }
    lds_fence();
    __builtin_amdgcn_s_setprio(1);
    #pragma unroll
    for(int nb=0;nb<4;nb++){
      #pragma unroll
      for(int s=0;s<2;s++){
        bf16x8 pa = *(const bf16x8*)&psb[w][ln][32*s+lg*8];
        bf16x8 bk = *(const bf16x8*)&kts[nb*16+ln][32*s+lg*8];
        acc[nb]=MFMA_B16(pa,bk,acc[nb]);
      }
    }
    __builtin_amdgcn_s_setprio(0);
    lds_fence();
  }
  short* dst = half? dqp1 : dqt;
  #pragma unroll
  for(int nb=0;nb<4;nb++){
    short4 s4;
    s4.x=f2bf(acc[nb][0]); s4.y=f2bf(acc[nb][1]);
    s4.z=f2bf(acc[nb][2]); s4.w=f2bf(acc[nb][3]);
    *(short4*)&dst[((size_t)bh*64 + nb*16+ln)*2048 + i0+w*16+lg*4]=s4;
  }
}

// dqt += dqp1 (bf16, deterministic)
__global__ __launch_bounds__(256) void k_dqred(short* __restrict__ dqt,
    const short* __restrict__ dqp1){
  size_t i = ((size_t)blockIdx.x*256 + threadIdx.x)*8;
  int4 a = *(const int4*)&dqt[i];
  int4 b = *(const int4*)&dqp1[i];
  short* pa=(short*)&a; const short* pb=(const short*)&b;
  short out[8];
  #pragma unroll
  for(int k=0;k<8;k++) out[k]=f2bf(bf2f(pa[k])+bf2f(pb[k]));
  *(int4*)&dqt[i] = *(int4*)out;
}

// ---------------- 12. flash backward dk,dv (2-way i-split) ----------------
__global__ __launch_bounds__(256) void k_fa_dkv(const short* __restrict__ kh,
    const short* __restrict__ vh, const short* __restrict__ qh,
    const short* __restrict__ qt, const short* __restrict__ doh,
    const short* __restrict__ dot,
    const float* __restrict__ lse, const float* __restrict__ delta,
    short* __restrict__ dkt, short* __restrict__ dvt,
    short* __restrict__ dkp1, short* __restrict__ dvp1){
  int bh = blockIdx.x, jt = blockIdx.y, half = blockIdx.z;
  int j0 = jt<<6;
  const short* khb = kh + (size_t)bh*N_*DH_;
  const short* vhb = vh + (size_t)bh*N_*DH_;
  const short* qhb = qh + (size_t)bh*N_*DH_;
  const short* qtb = qt + (size_t)bh*DH_*N_;
  const short* dohb= doh+ (size_t)bh*N_*DH_;
  const short* dotb= dot+ (size_t)bh*DH_*N_;
  __shared__ __attribute__((aligned(16))) short qs[64][LBK], dos[64][LBK], qts[64][LBK], dots[64][LBK];
  __shared__ __attribute__((aligned(16))) short psv[4][16][LBK], psk[4][16][LBK];
  __shared__ float Ls[64], dls[64];
  int tid=threadIdx.x, w=tid>>6, lane=tid&63, lg=lane>>4, ln=lane&15;
  bf16x8 akf[2], avf[2];
  #pragma unroll
  for(int s=0;s<2;s++){
    akf[s]=*(const bf16x8*)&khb[(size_t)(j0+w*16+ln)*DH_+32*s+lg*8];
    avf[s]=*(const bf16x8*)&vhb[(size_t)(j0+w*16+ln)*DH_+32*s+lg*8];
  }
  f32x4 accv[4], acck[4];
  #pragma unroll
  for(int nb=0;nb<4;nb++){
    accv[nb]=(f32x4){0.f,0.f,0.f,0.f};
    acck[nb]=(f32x4){0.f,0.f,0.f,0.f};
  }
  int it0 = jt + half;
  int4 qa0,qa1,da0,da1,qta0,qta1,dta0,dta1;
  float Lnx=0.f, dlnx=0.f;
  {
    int ip = (it0<32)? (it0<<6) : 0;
    tload(qhb+(size_t)ip*DH_, DH_, tid, qa0,qa1);
    tload(dohb+(size_t)ip*DH_, DH_, tid, da0,da1);
    tload(qtb+ip, N_, tid, qta0,qta1);
    tload(dotb+ip, N_, tid, dta0,dta1);
    if(tid<64){
      int ii=ip+tid;
      Lnx=lse[(size_t)bh*N_+ii];
      dlnx=(ii<NM_)?delta[(size_t)bh*N_+ii]:0.f;
    }
  }
  for(int it=it0; it<32; it+=2){
    int i0=it<<6;
    __syncthreads();
    twrite(qs, tid, qa0,qa1);
    twrite(dos, tid, da0,da1);
    twrite(qts, tid, qta0,qta1);
    twrite(dots, tid, dta0,dta1);
    if(tid<64){ Ls[tid]=Lnx; dls[tid]=dlnx; }
    if(it+2<32){
      int i1=(it+2)<<6;
      tload(qhb+(size_t)i1*DH_, DH_, tid, qa0,qa1);
      tload(dohb+(size_t)i1*DH_, DH_, tid, da0,da1);
      tload(qtb+i1, N_, tid, qta0,qta1);
      tload(dotb+i1, N_, tid, dta0,dta1);
      if(tid<64){
        int ii=i1+tid;
        Lnx=lse[(size_t)bh*N_+ii];
        dlnx=(ii<NM_)?delta[(size_t)bh*N_+ii]:0.f;
      }
    }
    __syncthreads();
    f32x4 sv[4], dav[4];
    __builtin_amdgcn_s_setprio(1);
    #pragma unroll
    for(int nb=0;nb<4;nb++){
      f32x4 z={0.f,0.f,0.f,0.f}, zd={0.f,0.f,0.f,0.f};
      #pragma unroll
      for(int s=0;s<2;s++){
        bf16x8 bq=*(const bf16x8*)&qs[nb*16+ln][32*s+lg*8];
        bf16x8 bd=*(const bf16x8*)&dos[nb*16+ln][32*s+lg*8];
        z = MFMA_B16(akf[s], bq, z);
        zd= MFMA_B16(avf[s], bd, zd);
      }
      sv[nb]=z; dav[nb]=zd;
    }
    __builtin_amdgcn_s_setprio(0);
    #pragma unroll
    for(int nb=0;nb<4;nb++){
      float Lc=Ls[nb*16+ln], dlc=dls[nb*16+ln];
      int ii=i0+nb*16+ln;
      #pragma unroll
      for(int r=0;r<4;r++){
        int jj=j0+w*16+lg*4+r;
        float pv=__expf(sv[nb][r]*SCALE_F - Lc);
        bool msk=(jj>ii)||(ii>=NM_)||(jj>=NM_);
        if(msk) pv=0.f;
        float ds = msk?0.f: SCALE_F*pv*(dav[nb][r]-dlc);
        psv[w][lg*4+r][ln+16*nb]=f2bf(pv);
        psk[w][lg*4+r][ln+16*nb]=f2bf(ds);
      }
    }
    lds_fence();
    __builtin_amdgcn_s_setprio(1);
    #pragma unroll
    for(int nb=0;nb<4;nb++){
      #pragma unroll
      for(int s=0;s<2;s++){
        bf16x8 pa = *(const bf16x8*)&psv[w][ln][32*s+lg*8];
        bf16x8 bd = *(const bf16x8*)&dots[nb*16+ln][32*s+lg*8];
        accv[nb]=MFMA_B16(pa,bd,accv[nb]);
        bf16x8 pk = *(const bf16x8*)&psk[w][ln][32*s+lg*8];
        bf16x8 bq = *(const bf16x8*)&qts[nb*16+ln][32*s+lg*8];
        acck[nb]=MFMA_B16(pk,bq,acck[nb]);
      }
    }
    __builtin_amdgcn_s_setprio(0);
    lds_fence();
  }
  short* dvd = half? dvp1 : dvt;
  short* dkd = half? dkp1 : dkt;
  #pragma unroll
  for(int nb=0;nb<4;nb++){
    int e=nb*16+ln, n0=j0+w*16+lg*4;
    short4 s4;
    s4.x=f2bf(accv[nb][0]); s4.y=f2bf(accv[nb][1]);
    s4.z=f2bf(accv[nb][2]); s4.w=f2bf(accv[nb][3]);
    *(short4*)&dvd[((size_t)bh*64+e)*2048 + n0]=s4;
    s4.x=f2bf(acck[nb][0]); s4.y=f2bf(acck[nb][1]);
    s4.z=f2bf(acck[nb][2]); s4.w=f2bf(acck[nb][3]);
    *(short4*)&dkd[((size_t)bh*64+e)*2048 + n0]=s4;
  }
}

// dkt += dkp1; dvt += dvp1
__global__ __launch_bounds__(256) void k_dkvred(short* __restrict__ dkt,
    short* __restrict__ dvt, const short* __restrict__ dkp1,
    const short* __restrict__ dvp1){
  int bid = blockIdx.x;
  short* dst; const short* src;
  if(bid<1024){ dst=dkt; src=dkp1; } else { dst=dvt; src=dvp1; bid-=1024; }
  size_t i = ((size_t)bid*256 + threadIdx.x)*8;
  int4 a = *(const int4*)&dst[i];
  int4 b = *(const int4*)&src[i];
  short* pa=(short*)&a; const short* pb=(const short*)&b;
  short out[8];
  #pragma unroll
  for(int k=0;k<8;k++) out[k]=f2bf(bf2f(pa[k])+bf2f(pb[k]));
  *(int4*)&dst[i] = *(int4*)out;
}

// ---------------- 13. weight grads (MFMA, split-K=8) ----------------
__global__ __launch_bounds__(256) void k_gemm_wgq(const short* __restrict__ tt,
    const short* __restrict__ g, float* __restrict__ par){
  __shared__ __attribute__((aligned(16))) short as[64][LBK], bs[64][LBK];
  int dt=blockIdx.x, h=blockIdx.y, sp=blockIdx.z;
  int b=sp>>2, n0b=(sp&3)*512;
  f32x4 acc[4];
  #pragma unroll
  for(int nb=0;nb<4;nb++) acc[nb]=(f32x4){0.f,0.f,0.f,0.f};
  gemm64(tt + (size_t)(dt*64)*4096 + sp*512, 4096,
         g  + ((size_t)(b*8+h)*64)*2048 + n0b, 2048, 8, as, bs, acc);
  int tid=threadIdx.x, w=tid>>6, lane=tid&63, lg=lane>>4, ln=lane&15;
  int row=w*16+lg*4;
  #pragma unroll
  for(int nb=0;nb<4;nb++)
    #pragma unroll
    for(int r=0;r<4;r++)
      par[(size_t)sp*262144 + (size_t)h*32768 + (size_t)(dt*64+row+r)*64 + nb*16+ln]=acc[nb][r];
}

__global__ __launch_bounds__(256) void k_gemm_wgo(const short* __restrict__ outt,
    const short* __restrict__ ert, float* __restrict__ par){
  __shared__ __attribute__((aligned(16))) short as[64][LBK], bs[64][LBK];
  int ct=blockIdx.x, h=blockIdx.y, sp=blockIdx.z;
  f32x4 acc[4];
  #pragma unroll
  for(int nb=0;nb<4;nb++) acc[nb]=(f32x4){0.f,0.f,0.f,0.f};
  gemm64(outt + (size_t)(h*64)*4096 + sp*512, 4096,
         ert  + (size_t)(ct*64)*4096 + sp*512, 4096, 8, as, bs, acc);
  int tid=threadIdx.x, w=tid>>6, lane=tid&63, lg=lane>>4, ln=lane&15;
  int row=w*16+lg*4;
  #pragma unroll
  for(int nb=0;nb<4;nb++)
    #pragma unroll
    for(int r=0;r<4;r++)
      par[(size_t)sp*262144 + (size_t)h*32768 + (size_t)(row+r)*512 + ct*64+nb*16+ln]=acc[nb][r];
}

__global__ __launch_bounds__(256) void k_wred_direct(const float* __restrict__ par,
    float* __restrict__ dst){
  int idx = blockIdx.x*256 + threadIdx.x;
  float s=0.f;
  #pragma unroll
  for(int sp=0;sp<8;sp++) s += par[(size_t)sp*262144 + idx];
  dst[idx]=s;
}
__global__ __launch_bounds__(256) void k_wred_xv(const float* __restrict__ par,
    float* __restrict__ X0){
  int idx = blockIdx.x*256 + threadIdx.x;
  float s=0.f;
  #pragma unroll
  for(int sp=0;sp<8;sp++) s += par[(size_t)sp*262144 + idx];
  int h=idx>>15, rem=idx&32767, d=rem>>6, e=rem&63;
  X0[(size_t)h*32768 + (size_t)e*512 + d]=s;
}
__global__ __launch_bounds__(256) void k_wred_xo(const float* __restrict__ par,
    float* __restrict__ X0){
  int idx = blockIdx.x*256 + threadIdx.x;
  float s=0.f;
  #pragma unroll
  for(int sp=0;sp<8;sp++) s += par[(size_t)sp*262144 + idx];
  X0[262144 + idx]=s;
}

// ---------------- 14. Newton-Schulz fused (one kernel, 16 blocks) ----------------
// X kept in LDS bf16 (row-major + transposed). All matmuls via MFMA.
__global__ __launch_bounds__(256) void k_ns_fused(const float* __restrict__ X0,
    float* __restrict__ dwv, float* __restrict__ dwo){
  __shared__ __attribute__((aligned(16))) short Xl[64][520];
  __shared__ __attribute__((aligned(16))) short Xt[512][72];
  __shared__ __attribute__((aligned(16))) short Al[64][72];
  __shared__ __attribute__((aligned(16))) short Bl[64][72];
  __shared__ float red[4];
  int m = blockIdx.x, tid=threadIdx.x, w=tid>>6, lane=tid&63, lg=lane>>4, ln=lane&15;
  const float* Xg = X0 + (size_t)m*32768;
  // per-matrix frobenius norm (f32 exact)
  float ss=0.f;
  for(int kk=0;kk<128;kk++){ float v=Xg[kk*256+tid]; ss+=v*v; }
  ss=wred64(ss);
  if(lane==0) red[w]=ss;
  __syncthreads();
  float sc = 1.f/fmaxf(sqrtf(red[0]+red[1]+red[2]+red[3]), 1e-7f);
  for(int kk=0;kk<128;kk++){
    int idx=kk*256+tid; int rr=idx>>9, cc=idx&511;
    short v=f2bf(Xg[idx]*sc);
    Xl[rr][cc]=v; Xt[cc][rr]=v;
  }
  __syncthreads();
  for(int iter=0; iter<5; ++iter){
    // A = X X^T : wave w -> rows w*16..+15, cols 0..63
    f32x4 accA[4];
    #pragma unroll
    for(int nb=0;nb<4;nb++) accA[nb]=(f32x4){0.f,0.f,0.f,0.f};
    for(int kt=0;kt<8;kt++){
      #pragma unroll
      for(int s=0;s<2;s++){
        bf16x8 a = *(const bf16x8*)&Xl[w*16+ln][kt*64+32*s+lg*8];
        #pragma unroll
        for(int nb=0;nb<4;nb++){
          bf16x8 b = *(const bf16x8*)&Xl[nb*16+ln][kt*64+32*s+lg*8];
          accA[nb]=MFMA_B16(a,b,accA[nb]);
        }
      }
    }
    #pragma unroll
    for(int nb=0;nb<4;nb++)
      #pragma unroll
      for(int r=0;r<4;r++)
        Al[w*16+lg*4+r][nb*16+ln]=f2bf(accA[nb][r]);
    __syncthreads();
    // A2 = A*A (A symmetric)
    f32x4 acc2[4];
    #pragma unroll
    for(int nb=0;nb<4;nb++) acc2[nb]=(f32x4){0.f,0.f,0.f,0.f};
    #pragma unroll
    for(int s=0;s<2;s++){
      bf16x8 a = *(const bf16x8*)&Al[w*16+ln][32*s+lg*8];
      #pragma unroll
      for(int nb=0;nb<4;nb++){
        bf16x8 b = *(const bf16x8*)&Al[nb*16+ln][32*s+lg*8];
        acc2[nb]=MFMA_B16(a,b,acc2[nb]);
      }
    }
    // B = b*A + c*A2
    #pragma unroll
    for(int nb=0;nb<4;nb++)
      #pragma unroll
      for(int r=0;r<4;r++)
        Bl[w*16+lg*4+r][nb*16+ln]=f2bf(-4.775f*accA[nb][r] + 2.0315f*acc2[nb][r]);
    __syncthreads();
    // Xnew = a*X + B*X, two d-phases (phase ph covers d in [ph*256, ph*256+256))
    #pragma unroll
    for(int ph=0; ph<2; ++ph){
      f32x4 xn[4][4];
      #pragma unroll
      for(int c4=0;c4<4;c4++){
        int ct=ph*4+c4;
        #pragma unroll
        for(int nb=0;nb<4;nb++) xn[c4][nb]=(f32x4){0.f,0.f,0.f,0.f};
        #pragma unroll
        for(int s=0;s<2;s++){
          bf16x8 a = *(const bf16x8*)&Bl[w*16+ln][32*s+lg*8];
          #pragma unroll
          for(int nb=0;nb<4;nb++){
            bf16x8 b = *(const bf16x8*)&Xt[ct*64+nb*16+ln][32*s+lg*8];
            xn[c4][nb]=MFMA_B16(a,b,xn[c4][nb]);
          }
        }
        #pragma unroll
        for(int nb=0;nb<4;nb++)
          #pragma unroll
          for(int r=0;r<4;r++)
            xn[c4][nb][r] += 3.4445f*bf2f(Xl[w*16+lg*4+r][ct*64+nb*16+ln]);
      }
      __syncthreads();
      if(iter<4){
        #pragma unroll
        for(int c4=0;c4<4;c4++){
          int ct=ph*4+c4;
          #pragma unroll
          for(int nb=0;nb<4;nb++){
            int d=ct*64+nb*16+ln, row0=w*16+lg*4;
            short4 s4;
            s4.x=f2bf(xn[c4][nb][0]); s4.y=f2bf(xn[c4][nb][1]);
            s4.z=f2bf(xn[c4][nb][2]); s4.w=f2bf(xn[c4][nb][3]);
            Xl[row0  ][d]=s4.x; Xl[row0+1][d]=s4.y;
            Xl[row0+2][d]=s4.z; Xl[row0+3][d]=s4.w;
            *(short4*)&Xt[d][row0]=s4;
          }
        }
        __syncthreads();
      } else {
        // final iteration: write outputs directly (f32)
        #pragma unroll
        for(int c4=0;c4<4;c4++){
          int ct=ph*4+c4;
          #pragma unroll
          for(int nb=0;nb<4;nb++){
            int d=ct*64+nb*16+ln, row0=w*16+lg*4;
            #pragma unroll
            for(int r=0;r<4;r++){
              float v=xn[c4][nb][r];
              int e=row0+r;
              if(m<8) dwv[(size_t)m*32768 + (size_t)d*64 + e]=v;
              else    dwo[(size_t)(m-8)*32768 + (size_t)e*512 + d]=v;
            }
          }
        }
      }
    }
  }
}

// ---------------- launch ----------------
extern "C" void kernel_launch(void* const* d_in, const int* in_sizes, int n_in,
                              void* d_out, int out_size, void* d_ws, size_t ws_size,
                              hipStream_t stream) {
  const float* tokens=(const float*)d_in[0];
  const float* rmsw =(const float*)d_in[1];
  const float* wq   =(const float*)d_in[2];
  const float* wk   =(const float*)d_in[3];
  const float* wv   =(const float*)d_in[4];
  const float* wo   =(const float*)d_in[5];
  const float* lrw  =(const float*)d_in[6];
  const float* tvw  =(const float*)d_in[7];
  float* out = (float*)d_out;
  float* ws  = (float*)d_ws;

  short* tb   = (short*)(ws);            // [4160][512] bf16 (pad rows zero)
  short* tt   = (short*)(ws + 1064960);  // [512][4096]
  short* qh   = (short*)(ws + 2113536);  // [16bh][2048][64]
  short* kh   = (short*)(ws + 3162112);
  short* vh   = (short*)(ws + 4210688);
  short* qt   = (short*)(ws + 5259264);  // [16bh][64][2048]
  short* kt   = (short*)(ws + 6307840);
  short* vt   = (short*)(ws + 7356416);
  float* er_  = ws + 8404992;            // f32 [4096][512]
  float* op0  = ws + 8404992;            // fwd partial 0 (dead before er_)
  short* dqp1 = (short*)(ws + 8404992);  // bwd partials (after er_ dead)
  short* dkp1 = (short*)(ws + 8404992);
  short* dvp1 = (short*)(ws + 9453568);
  short* obb  = (short*)(ws + 10502144); // bf16 [4096][512]
  short* outt = (short*)(ws + 11550720); // bf16 [512][4096]
  short* erb  = (short*)(ws + 12599296);
  short* ert  = (short*)(ws + 13647872);
  short* doh  = (short*)(ws + 14696448); // [16bh][2048][64]
  short* dot  = (short*)(ws + 15745024); // [16bh][64][2048]
  float* par_ = ws + 14696448;           // aliases doh+dot (dead before wgrad)
  float* op1  = ws + 14696448;           // fwd partial 1 (dead before doh/dot)
  short* dqt  = (short*)(ws + 16793600); // [16bh][64][2048]
  float* mlb  = ws + 16793600;           // fwd m/l partials (dead before dqt)
  short* dkt  = (short*)(ws + 17842176);
  short* dvt  = (short*)(ws + 18890752);
  short* wqt  = (short*)(ws + 19939328); // [8h][64][512]
  short* wkt  = (short*)(ws + 20070400);
  short* wvt  = (short*)(ws + 20201472);
  short* wob  = (short*)(ws + 20332544); // [512 he][512 d]
  short* wot  = (short*)(ws + 20463616); // [512 d][512 he]
  short* tvwb = (short*)(ws + 20594688); // [512 o][512 d]
  float* lse_ = ws + 20725760;
  float* dlt_ = ws + 20758528;
  float* X0_  = ws + 20791296;

  float* OUT_PRED = out;
  float* OUT_DWQ  = out + 2097152;
  float* OUT_DWK  = out + 2359296;
  float* OUT_DWV  = out + 2621440;
  float* OUT_DWO  = out + 2883584;

  k_rmsnorm<<<4160,256,0,stream>>>(tokens, rmsw, tb);
  k_wprep<<<272,256,0,stream>>>(wq,wk,wv,wo,tvw, wqt,wkt,wvt,wob,wot,tvwb);
  k_gemm_qkv<<<dim3(64,24),256,0,stream>>>(tb, wqt,wkt,wvt, qh,kh,vh, qt,kt,vt);
  k_fa_fwd<<<dim3(16,32,2),256,0,stream>>>(qh, kh, vt, op0, op1, mlb);
  k_fa_merge<<<8192,256,0,stream>>>(op0, op1, mlb, obb, lse_);
  k_gemm_pred<<<dim3(64,8),256,0,stream>>>(obb, wot, OUT_PRED);

  if(out_size < 3145728) return;   // forward-only variant

  k_trans_b<<<dim3(64,8),256,0,stream>>>(tb, tt);
  k_gemm_tv<<<dim3(64,8),256,0,stream>>>(tb, tvwb, er_);
  k_lnerr<<<4094,256,0,stream>>>(er_, tb, OUT_PRED, lrw);
  k_trans_f<<<dim3(64,8),256,0,stream>>>(er_, erb, ert);
  k_gemm_dout<<<dim3(64,8),256,0,stream>>>(erb, wob, doh, dot);
  k_delta<<<8188,256,0,stream>>>(doh, obb, dlt_);
  k_fa_dq<<<dim3(16,32,2),256,0,stream>>>(qh, kh, vh, kt, doh, lse_, dlt_, dqt, dqp1);
  k_dqred<<<1024,256,0,stream>>>(dqt, dqp1);
  k_fa_dkv<<<dim3(16,32,2),256,0,stream>>>(kh, vh, qh, qt, doh, dot, lse_, dlt_,
                                           dkt, dvt, dkp1, dvp1);
  k_dkvred<<<2048,256,0,stream>>>(dkt, dvt, dkp1, dvp1);
  k_trans_b<<<dim3(64,8),256,0,stream>>>(obb, outt);

  k_gemm_wgq<<<dim3(8,8,8),256,0,stream>>>(tt, dqt, par_);
  k_wred_direct<<<1024,256,0,stream>>>(par_, OUT_DWQ);
  k_gemm_wgq<<<dim3(8,8,8),256,0,stream>>>(tt, dkt, par_);
  k_wred_direct<<<1024,256,0,stream>>>(par_, OUT_DWK);
  k_gemm_wgq<<<dim3(8,8,8),256,0,stream>>>(tt, dvt, par_);
  k_wred_xv<<<1024,256,0,stream>>>(par_, X0_);
  k_gemm_wgo<<<dim3(8,8,8),256,0,stream>>>(outt, ert, par_);
  k_wred_xo<<<1024,256,0,stream>>>(par_, X0_);

  k_ns_fused<<<16,256,0,stream>>>(X0_, OUT_DWV, OUT_DWO);
}

// Round 9
// 311.124 us; speedup vs baseline: 8.9902x; 1.0239x over previous
//
#include <hip/hip_runtime.h>
#include <float.h>
#include <math.h>

// ---------------- problem constants ----------------
#define B_   2
#define N_   2048
#define D_   512
#define H_   8
#define DH_  64
#define NM_  2047            // n-1
#define SCALE_F 0.125f       // 64^-0.5
#define LBK 72               // LDS row pad (bf16 tiles), 144B: 16B-aligned rows

typedef __attribute__((ext_vector_type(8))) short bf16x8;
typedef __attribute__((ext_vector_type(4))) float f32x4;
#define MFMA_B16(a,b,c) __builtin_amdgcn_mfma_f32_16x16x32_bf16(a,b,c,0,0,0)

__device__ __forceinline__ short f2bf(float f){
  unsigned u = __float_as_uint(f);
  unsigned r = u + 0x7fffu + ((u>>16)&1u);
  return (short)(r>>16);
}
__device__ __forceinline__ float bf2f(short s){
  return __uint_as_float(((unsigned)(unsigned short)s)<<16);
}
__device__ __forceinline__ void lds_fence(){
  asm volatile("s_waitcnt lgkmcnt(0)" ::: "memory");
  __builtin_amdgcn_sched_barrier(0);
}
// load a 64x64 bf16 tile into regs (2 int4 per thread); pairs with twrite
__device__ __forceinline__ void tload(const short* __restrict__ src, size_t stride,
                                      int tid, int4& r0, int4& r1){
  int rr = tid>>2, cc = (tid&3)<<4;
  r0 = *(const int4*)&src[(size_t)rr*stride + cc];
  r1 = *(const int4*)&src[(size_t)rr*stride + cc + 8];
}
__device__ __forceinline__ void twrite(short (*dst)[LBK], int tid,
                                       const int4& r0, const int4& r1){
  int rr = tid>>2, cc = (tid&3)<<4;
  *(int4*)&dst[rr][cc]   = r0;
  *(int4*)&dst[rr][cc+8] = r1;
}
__device__ __forceinline__ float wred64(float v){
  #pragma unroll
  for(int off=32; off; off>>=1) v += __shfl_down(v, off, 64);
  return v;
}

// 64x64 MFMA GEMM mainloop with register-prefetch double buffering (2-phase)
__device__ __forceinline__ void gemm64(const short* __restrict__ A, size_t lda,
    const short* __restrict__ Bt, size_t ldb, int nk,
    short (*as)[LBK], short (*bs)[LBK], f32x4* acc){
  int tid=threadIdx.x, w=tid>>6, lane=tid&63, lg=lane>>4, ln=lane&15;
  int4 a0,a1,b0,b1;
  tload(A, lda, tid, a0,a1);
  tload(Bt, ldb, tid, b0,b1);
  for(int kt=0;kt<nk;++kt){
    __syncthreads();
    twrite(as, tid, a0,a1);
    twrite(bs, tid, b0,b1);
    if(kt+1<nk){
      tload(A +(size_t)(kt+1)*64, lda, tid, a0,a1);
      tload(Bt+(size_t)(kt+1)*64, ldb, tid, b0,b1);
    }
    __syncthreads();
    __builtin_amdgcn_s_setprio(1);
    #pragma unroll
    for(int s=0;s<2;s++){
      bf16x8 a = *(const bf16x8*)&as[w*16+ln][32*s+lg*8];
      #pragma unroll
      for(int nb=0;nb<4;nb++){
        bf16x8 b = *(const bf16x8*)&bs[nb*16+ln][32*s+lg*8];
        acc[nb]=MFMA_B16(a,b,acc[nb]);
      }
    }
    __builtin_amdgcn_s_setprio(0);
  }
}

// ---------------- 1. RMSNorm -> tb (bf16, padded to 4160 rows) ----------------
__global__ __launch_bounds__(256) void k_rmsnorm(const float* __restrict__ tok,
    const float* __restrict__ w, short* __restrict__ tb){
  int row = blockIdx.x;
  int tid = threadIdx.x;
  if(row>=4096){ tb[(size_t)row*D_+tid]=0; tb[(size_t)row*D_+tid+256]=0; return; }
  const float* x = tok + (size_t)row*D_;
  float v0 = x[tid], v1 = x[tid+256];
  float s = v0*v0 + v1*v1;
  s = wred64(s);
  __shared__ float red[4];
  if((tid&63)==0) red[tid>>6] = s;
  __syncthreads();
  float tot = red[0]+red[1]+red[2]+red[3];
  float sc = rsqrtf(tot*(1.f/512.f) + 1.1920929e-7f);
  tb[(size_t)row*D_+tid]     = f2bf(v0*sc*w[tid]);
  tb[(size_t)row*D_+tid+256] = f2bf(v1*sc*w[tid+256]);
}

// ---------------- 2. weight prep ----------------
__global__ __launch_bounds__(256) void k_wprep(const float* __restrict__ wq,
    const float* __restrict__ wk, const float* __restrict__ wv,
    const float* __restrict__ wo, const float* __restrict__ tvw,
    short* __restrict__ wqt, short* __restrict__ wkt, short* __restrict__ wvt,
    short* __restrict__ wob, short* __restrict__ wot, short* __restrict__ tvwb){
  __shared__ short l[64][66];
  int bx=blockIdx.x, tid=threadIdx.x;
  if(bx<192){
    const float* w = (bx<64)? wq : (bx<128)? wk : wv;
    short* wt      = (bx<64)? wqt: (bx<128)? wkt: wvt;
    int lb=bx&63, h=lb>>3, d0=(lb&7)*64;
    for(int kk=0;kk<16;kk++){
      int idx=kk*256+tid, rr=idx>>6, cc=idx&63;
      l[cc][rr] = f2bf(w[((size_t)h*512 + d0+rr)*64 + cc]);
    }
    __syncthreads();
    for(int kk=0;kk<16;kk++){
      int idx=kk*256+tid, rr=idx>>6, cc=idx&63;
      wt[((size_t)h*64+rr)*512 + d0+cc] = l[rr][cc];
    }
  } else if(bx<256){
    int lb=bx-192, r0=(lb>>3)*64, c0=(lb&7)*64;
    for(int kk=0;kk<16;kk++){
      int idx=kk*256+tid, rr=idx>>6, cc=idx&63;
      l[cc][rr] = f2bf(wo[(size_t)(r0+rr)*512 + c0+cc]);
    }
    __syncthreads();
    for(int kk=0;kk<16;kk++){
      int idx=kk*256+tid, rr=idx>>6, cc=idx&63;
      wot[(size_t)(c0+rr)*512 + r0+cc] = l[rr][cc];
    }
  } else if(bx<264){
    size_t base=(size_t)(bx-256)*32768;
    for(int kk=0;kk<128;kk++) wob[base+kk*256+tid]=f2bf(wo[base+kk*256+tid]);
  } else {
    size_t base=(size_t)(bx-264)*32768;
    for(int kk=0;kk<128;kk++) tvwb[base+kk*256+tid]=f2bf(tvw[base+kk*256+tid]);
  }
}

// ---------------- 3. transposes (4096x512) ----------------
__global__ __launch_bounds__(256) void k_trans_b(const short* __restrict__ in,
    short* __restrict__ outt){
  __shared__ short l[64][66];
  int r0=blockIdx.x<<6, c0=blockIdx.y<<6, tid=threadIdx.x;
  for(int kk=0;kk<16;kk++){
    int idx=kk*256+tid, rr=idx>>6, cc=idx&63;
    l[cc][rr]=in[(size_t)(r0+rr)*512 + c0+cc];
  }
  __syncthreads();
  for(int kk=0;kk<16;kk++){
    int idx=kk*256+tid, rr=idx>>6, cc=idx&63;
    outt[(size_t)(c0+rr)*4096 + r0+cc]=l[rr][cc];
  }
}
__global__ __launch_bounds__(256) void k_trans_f(const float* __restrict__ in,
    short* __restrict__ outn, short* __restrict__ outt){
  __shared__ short l[64][66];
  int r0=blockIdx.x<<6, c0=blockIdx.y<<6, tid=threadIdx.x;
  for(int kk=0;kk<16;kk++){
    int idx=kk*256+tid, rr=idx>>6, cc=idx&63;
    short v=f2bf(in[(size_t)(r0+rr)*512 + c0+cc]);
    outn[(size_t)(r0+rr)*512 + c0+cc]=v;
    l[cc][rr]=v;
  }
  __syncthreads();
  for(int kk=0;kk<16;kk++){
    int idx=kk*256+tid, rr=idx>>6, cc=idx&63;
    outt[(size_t)(c0+rr)*4096 + r0+cc]=l[rr][cc];
  }
}

// ---------------- 4. QKV projection (MFMA) ----------------
__global__ __launch_bounds__(256) void k_gemm_qkv(const short* __restrict__ tb,
    const short* __restrict__ wqt, const short* __restrict__ wkt, const short* __restrict__ wvt,
    short* __restrict__ qh, short* __restrict__ kh, short* __restrict__ vh,
    short* __restrict__ qt, short* __restrict__ kt, short* __restrict__ vt){
  __shared__ __attribute__((aligned(16))) short as[64][LBK], bs[64][LBK];
  int r0=blockIdx.x<<6, ct=blockIdx.y, which=ct>>3, h=ct&7;
  const short* Bt=(which==0?wqt:which==1?wkt:wvt)+(size_t)h*32768;
  f32x4 acc[4];
  #pragma unroll
  for(int nb=0;nb<4;nb++) acc[nb]=(f32x4){0.f,0.f,0.f,0.f};
  gemm64(tb+(size_t)r0*512, 512, Bt, 512, 8, as, bs, acc);
  short* on=(which==0?qh:which==1?kh:vh);
  short* ot=(which==0?qt:which==1?kt:vt);
  int tid=threadIdx.x, w=tid>>6, lane=tid&63, lg=lane>>4, ln=lane&15;
  size_t bh=(size_t)(r0>>11)*8+h;
  int n0=(r0&2047)+w*16+lg*4;
  #pragma unroll
  for(int nb=0;nb<4;nb++){
    int e=nb*16+ln;
    short4 s4;
    s4.x=f2bf(acc[nb][0]); s4.y=f2bf(acc[nb][1]);
    s4.z=f2bf(acc[nb][2]); s4.w=f2bf(acc[nb][3]);
    on[(bh*2048+n0  )*64+e]=s4.x;
    on[(bh*2048+n0+1)*64+e]=s4.y;
    on[(bh*2048+n0+2)*64+e]=s4.z;
    on[(bh*2048+n0+3)*64+e]=s4.w;
    *(short4*)&ot[(bh*64+e)*2048+n0]=s4;
  }
}

// ---------------- 5. flash attention forward (2-way j-split, partials) ----------------
__global__ __launch_bounds__(256) void k_fa_fwd(const short* __restrict__ qh,
    const short* __restrict__ kh, const short* __restrict__ vt,
    float* __restrict__ op0, float* __restrict__ op1, float* __restrict__ mlb){
  int bh = blockIdx.x, qq = blockIdx.y, half = blockIdx.z;
  int it = (qq<16)? (31-qq) : (qq-16);
  int i0 = it<<6;
  const short* qhb = qh + (size_t)bh*N_*DH_;
  const short* khb = kh + (size_t)bh*N_*DH_;
  const short* vtb = vt + (size_t)bh*DH_*N_;
  __shared__ __attribute__((aligned(16))) short ks[64][LBK], vts[64][LBK];
  __shared__ __attribute__((aligned(16))) short psb[4][16][LBK];
  int tid=threadIdx.x, w=tid>>6, lane=tid&63, lg=lane>>4, ln=lane&15;
  bf16x8 aq[2];
  #pragma unroll
  for(int s=0;s<2;s++)
    aq[s] = *(const bf16x8*)&qhb[(size_t)(i0+w*16+ln)*DH_ + 32*s + lg*8];
  f32x4 acc[4];
  float mrow[4], lrow[4];
  #pragma unroll
  for(int nb=0;nb<4;nb++) acc[nb]=(f32x4){0.f,0.f,0.f,0.f};
  #pragma unroll
  for(int r=0;r<4;r++){ mrow[r]=-FLT_MAX; lrow[r]=0.f; }
  int4 ka0,ka1,va0,va1;
  tload(khb+(size_t)half*64*DH_, DH_, tid, ka0,ka1);
  tload(vtb+half*64, N_, tid, va0,va1);
  for(int jt=half;jt<=it;jt+=2){
    int j0 = jt<<6;
    bool diag = (jt==it);
    __syncthreads();
    twrite(ks, tid, ka0,ka1);
    twrite(vts, tid, va0,va1);
    if(jt+2<=it){
      tload(khb+(size_t)(jt+2)*64*DH_, DH_, tid, ka0,ka1);
      tload(vtb+(jt+2)*64, N_, tid, va0,va1);
    }
    __syncthreads();
    f32x4 sv[4];
    __builtin_amdgcn_s_setprio(1);
    #pragma unroll
    for(int nb=0;nb<4;nb++){
      f32x4 z = {0.f,0.f,0.f,0.f};
      #pragma unroll
      for(int s=0;s<2;s++){
        bf16x8 bk = *(const bf16x8*)&ks[nb*16+ln][32*s + lg*8];
        z = MFMA_B16(aq[s], bk, z);
      }
      sv[nb]=z;
    }
    __builtin_amdgcn_s_setprio(0);
    int iiB = i0 + w*16 + lg*4;
    #pragma unroll
    for(int r=0;r<4;r++){
      int ii = iiB + r;
      float srow[4]; float mx = -FLT_MAX;
      if(diag){
        #pragma unroll
        for(int nb=0;nb<4;nb++){
          float x = sv[nb][r]*SCALE_F;
          if(j0+nb*16+ln > ii) x = -FLT_MAX;
          srow[nb]=x; mx=fmaxf(mx,x);
        }
      } else {
        #pragma unroll
        for(int nb=0;nb<4;nb++){
          float x = sv[nb][r]*SCALE_F;
          srow[nb]=x; mx=fmaxf(mx,x);
        }
      }
      mx=fmaxf(mx,__shfl_xor(mx,1)); mx=fmaxf(mx,__shfl_xor(mx,2));
      mx=fmaxf(mx,__shfl_xor(mx,4)); mx=fmaxf(mx,__shfl_xor(mx,8));
      float mn = fmaxf(mrow[r], mx);
      float rs = 0.f;
      #pragma unroll
      for(int nb=0;nb<4;nb++){
        float pv = __expf(srow[nb]-mn);
        psb[w][lg*4+r][ln+16*nb]=f2bf(pv); rs+=pv;
      }
      rs+=__shfl_xor(rs,1); rs+=__shfl_xor(rs,2);
      rs+=__shfl_xor(rs,4); rs+=__shfl_xor(rs,8);
      float corr = __expf(mrow[r]-mn);
      lrow[r]=lrow[r]*corr+rs; mrow[r]=mn;
      #pragma unroll
      for(int nb=0;nb<4;nb++) acc[nb][r]*=corr;
    }
    lds_fence();
    __builtin_amdgcn_s_setprio(1);
    #pragma unroll
    for(int nb=0;nb<4;nb++){
      #pragma unroll
      for(int s=0;s<2;s++){
        bf16x8 pa = *(const bf16x8*)&psb[w][ln][32*s + lg*8];
        bf16x8 bv = *(const bf16x8*)&vts[nb*16+ln][32*s + lg*8];
        acc[nb] = MFMA_B16(pa, bv, acc[nb]);
      }
    }
    __builtin_amdgcn_s_setprio(0);
    lds_fence();
  }
  float* op   = half? op1 : op0;
  float* marr = mlb + half*65536;
  float* larr = marr + 32768;
  #pragma unroll
  for(int r=0;r<4;r++){
    int ii = i0 + w*16 + lg*4 + r;
    size_t row = (size_t)bh*2048 + ii;
    #pragma unroll
    for(int nb=0;nb<4;nb++)
      op[row*64 + nb*16+ln] = acc[nb][r];
    if(ln==0){ marr[row]=mrow[r]; larr[row]=lrow[r]; }
  }
}

// merge two softmax partials -> obb bf16 + lse
__global__ __launch_bounds__(256) void k_fa_merge(const float* __restrict__ op0,
    const float* __restrict__ op1, const float* __restrict__ mlb,
    short* __restrict__ obb, float* __restrict__ lse){
  int row = blockIdx.x*4 + (threadIdx.x>>6);
  int lane = threadIdx.x&63;
  float m0 = mlb[row],        l0 = mlb[32768+row];
  float m1 = mlb[65536+row],  l1 = mlb[98304+row];
  float m  = fmaxf(m0,m1);
  float c0 = __expf(m0-m), c1 = __expf(m1-m);
  float l  = l0*c0 + l1*c1;
  float o  = (op0[(size_t)row*64+lane]*c0 + op1[(size_t)row*64+lane]*c1)/l;
  int bh = row>>11, i = row&2047, b = bh>>3, h = bh&7;
  obb[((size_t)(b*2048+i))*512 + h*64 + lane] = f2bf(o);
  if(lane==0) lse[row] = m + logf(l);
}

// ---------------- 6. pred = obb @ wot^T (MFMA), f32 out ----------------
__global__ __launch_bounds__(256) void k_gemm_pred(const short* __restrict__ obb,
    const short* __restrict__ wot, float* __restrict__ pred){
  __shared__ __attribute__((aligned(16))) short as[64][LBK], bs[64][LBK];
  int r0=blockIdx.x<<6, c0=blockIdx.y<<6;
  f32x4 acc[4];
  #pragma unroll
  for(int nb=0;nb<4;nb++) acc[nb]=(f32x4){0.f,0.f,0.f,0.f};
  gemm64(obb+(size_t)r0*512, 512, wot+(size_t)c0*512, 512, 8, as, bs, acc);
  int tid=threadIdx.x, w=tid>>6, lane=tid&63, lg=lane>>4, ln=lane&15;
  int row=r0+w*16+lg*4;
  #pragma unroll
  for(int nb=0;nb<4;nb++)
    #pragma unroll
    for(int r=0;r<4;r++)
      pred[(size_t)(row+r)*512 + c0+nb*16+ln]=acc[nb][r];
}

// ---------------- 7. tv = tb(shift+1) @ tvwb^T ----------------
__global__ __launch_bounds__(256) void k_gemm_tv(const short* __restrict__ tb,
    const short* __restrict__ tvwb, float* __restrict__ er){
  __shared__ __attribute__((aligned(16))) short as[64][LBK], bs[64][LBK];
  int r0=blockIdx.x<<6, c0=blockIdx.y<<6;
  f32x4 acc[4];
  #pragma unroll
  for(int nb=0;nb<4;nb++) acc[nb]=(f32x4){0.f,0.f,0.f,0.f};
  gemm64(tb+(size_t)(r0+1)*512, 512, tvwb+(size_t)c0*512, 512, 8, as, bs, acc);
  int tid=threadIdx.x, w=tid>>6, lane=tid&63, lg=lane>>4, ln=lane&15;
  int row=r0+w*16+lg*4;
  #pragma unroll
  for(int nb=0;nb<4;nb++)
    #pragma unroll
    for(int r=0;r<4;r++){
      float v=(((row+r)&2047)==2047)?0.f:acc[nb][r];
      er[(size_t)(row+r)*512 + c0+nb*16+ln]=v;
    }
}

// ---------------- 8. layernorm target + lr + error ----------------
__global__ __launch_bounds__(256) void k_lnerr(float* __restrict__ er,
    const short* __restrict__ tb, const float* __restrict__ pred,
    const float* __restrict__ lrw){
  int kr = blockIdx.x;
  int b = kr/NM_, n = kr-b*NM_;
  size_t row=(size_t)b*2048+n;
  float* tv = er + row*512;
  const short* tok = tb + row*512;
  const float* pr  = pred + row*512;
  int tid=threadIdx.x;
  float v0=tv[tid], v1=tv[tid+256];
  float s1=v0+v1, s2=v0*v0+v1*v1;
  float s3=bf2f(tok[tid])*lrw[tid] + bf2f(tok[tid+256])*lrw[tid+256];
  s1=wred64(s1); s2=wred64(s2); s3=wred64(s3);
  __shared__ float r1[4],r2[4],r3[4];
  if((tid&63)==0){ int w=tid>>6; r1[w]=s1; r2[w]=s2; r3[w]=s3; }
  __syncthreads();
  float S1=r1[0]+r1[1]+r1[2]+r1[3];
  float S2=r2[0]+r2[1]+r2[2]+r2[3];
  float S3=r3[0]+r3[1]+r3[2]+r3[3];
  float mu  = S1*(1.f/512.f);
  float var = S2*(1.f/512.f) - mu*mu;
  float rstd= rsqrtf(var + 1e-5f);
  float lr  = 0.01f/(1.f+__expf(-S3));
  tv[tid]     = ((v0-mu)*rstd - pr[tid])*lr;
  tv[tid+256] = ((v1-mu)*rstd - pr[tid+256])*lr;
}

// ---------------- 9. dout = erb @ wob^T (MFMA) -> doh + dot bf16 ----------------
__global__ __launch_bounds__(256) void k_gemm_dout(const short* __restrict__ erb,
    const short* __restrict__ wob, short* __restrict__ doh, short* __restrict__ dot){
  __shared__ __attribute__((aligned(16))) short as[64][LBK], bs[64][LBK];
  int r0=blockIdx.x<<6, h=blockIdx.y;
  f32x4 acc[4];
  #pragma unroll
  for(int nb=0;nb<4;nb++) acc[nb]=(f32x4){0.f,0.f,0.f,0.f};
  gemm64(erb+(size_t)r0*512, 512, wob+(size_t)h*32768, 512, 8, as, bs, acc);
  int tid=threadIdx.x, w=tid>>6, lane=tid&63, lg=lane>>4, ln=lane&15;
  size_t bh=(size_t)(r0>>11)*8+h;
  int n0=(r0&2047)+w*16+lg*4;
  #pragma unroll
  for(int nb=0;nb<4;nb++){
    int e=nb*16+ln;
    short4 s4;
    s4.x=f2bf(acc[nb][0]); s4.y=f2bf(acc[nb][1]);
    s4.z=f2bf(acc[nb][2]); s4.w=f2bf(acc[nb][3]);
    doh[(bh*2048+n0  )*64+e]=s4.x;
    doh[(bh*2048+n0+1)*64+e]=s4.y;
    doh[(bh*2048+n0+2)*64+e]=s4.z;
    doh[(bh*2048+n0+3)*64+e]=s4.w;
    *(short4*)&dot[(bh*64+e)*2048+n0]=s4;
  }
}

// ---------------- 10. delta = sum_e dout*out ----------------
__global__ __launch_bounds__(256) void k_delta(const short* __restrict__ doh,
    const short* __restrict__ obb, float* __restrict__ delta){
  int rid = blockIdx.x*4 + (threadIdx.x>>6);
  int lane = threadIdx.x&63;
  if(rid >= B_*H_*NM_) return;
  int b = rid/(H_*NM_); int rem = rid - b*H_*NM_;
  int h = rem/NM_; int i = rem - h*NM_;
  float v = bf2f(doh[((size_t)(b*H_+h)*N_ + i)*DH_ + lane])
          * bf2f(obb[((size_t)(b*N_+i))*D_ + h*DH_ + lane]);
  v = wred64(v);
  if(lane==0) delta[((size_t)(b*H_+h))*N_ + i] = v;
}

// ---------------- 11. flash backward dq (2-way j-split) -> dqt + dqp1 ----------------
__global__ __launch_bounds__(256) void k_fa_dq(const short* __restrict__ qh,
    const short* __restrict__ kh, const short* __restrict__ vh,
    const short* __restrict__ kt, const short* __restrict__ doh,
    const float* __restrict__ lse, const float* __restrict__ delta,
    short* __restrict__ dqt, short* __restrict__ dqp1){
  int bh = blockIdx.x, it = blockIdx.y, half = blockIdx.z;
  int i0 = it<<6;
  const short* qhb = qh + (size_t)bh*N_*DH_;
  const short* khb = kh + (size_t)bh*N_*DH_;
  const short* vhb = vh + (size_t)bh*N_*DH_;
  const short* ktb = kt + (size_t)bh*DH_*N_;
  const short* dohb= doh+ (size_t)bh*N_*DH_;
  __shared__ __attribute__((aligned(16))) short ks[64][LBK], vs[64][LBK], kts[64][LBK];
  __shared__ __attribute__((aligned(16))) short psb[4][16][LBK];
  int tid=threadIdx.x, w=tid>>6, lane=tid&63, lg=lane>>4, ln=lane&15;
  bf16x8 aq[2], ad[2];
  float Lr[4], dl[4];
  #pragma unroll
  for(int s=0;s<2;s++){
    aq[s]=*(const bf16x8*)&qhb[(size_t)(i0+w*16+ln)*DH_+32*s+lg*8];
    ad[s]=*(const bf16x8*)&dohb[(size_t)(i0+w*16+ln)*DH_+32*s+lg*8];
  }
  #pragma unroll
  for(int r=0;r<4;r++){
    int ii=i0+w*16+lg*4+r;
    Lr[r]=lse[(size_t)bh*N_+ii];
    dl[r]=(ii<NM_)?delta[(size_t)bh*N_+ii]:0.f;
  }
  f32x4 acc[4];
  #pragma unroll
  for(int nb=0;nb<4;nb++) acc[nb]=(f32x4){0.f,0.f,0.f,0.f};
  int4 ka0,ka1,va0,va1,ta0,ta1;
  tload(khb+(size_t)half*64*DH_, DH_, tid, ka0,ka1);
  tload(vhb+(size_t)half*64*DH_, DH_, tid, va0,va1);
  tload(ktb+half*64, N_, tid, ta0,ta1);
  for(int jt=half;jt<=it;jt+=2){
    int j0=jt<<6;
    bool msk_needed = (jt==it) || (it==31);
    __syncthreads();
    twrite(ks, tid, ka0,ka1);
    twrite(vs, tid, va0,va1);
    twrite(kts, tid, ta0,ta1);
    if(jt+2<=it){
      tload(khb+(size_t)(jt+2)*64*DH_, DH_, tid, ka0,ka1);
      tload(vhb+(size_t)(jt+2)*64*DH_, DH_, tid, va0,va1);
      tload(ktb+(jt+2)*64, N_, tid, ta0,ta1);
    }
    __syncthreads();
    f32x4 sv[4], dav[4];
    __builtin_amdgcn_s_setprio(1);
    #pragma unroll
    for(int nb=0;nb<4;nb++){
      f32x4 z={0.f,0.f,0.f,0.f}, zd={0.f,0.f,0.f,0.f};
      #pragma unroll
      for(int s=0;s<2;s++){
        bf16x8 bk=*(const bf16x8*)&ks[nb*16+ln][32*s+lg*8];
        bf16x8 bv=*(const bf16x8*)&vs[nb*16+ln][32*s+lg*8];
        z = MFMA_B16(aq[s], bk, z);
        zd= MFMA_B16(ad[s], bv, zd);
      }
      sv[nb]=z; dav[nb]=zd;
    }
    __builtin_amdgcn_s_setprio(0);
    if(msk_needed){
      #pragma unroll
      for(int r=0;r<4;r++){
        int ii=i0+w*16+lg*4+r;
        #pragma unroll
        for(int nb=0;nb<4;nb++){
          int jj=j0+nb*16+ln;
          float pv=__expf(sv[nb][r]*SCALE_F - Lr[r]);
          float dsv=SCALE_F*pv*(dav[nb][r]-dl[r]);
          if(jj>ii || ii>=NM_ || jj>=NM_) dsv=0.f;
          psb[w][lg*4+r][ln+16*nb]=f2bf(dsv);
        }
      }
    } else {
      #pragma unroll
      for(int r=0;r<4;r++)
        #pragma unroll
        for(int nb=0;nb<4;nb++){
          float pv=__expf(sv[nb][r]*SCALE_F - Lr[r]);
          psb[w][lg*4+r][ln+16*nb]=f2bf(SCALE_F*pv*(dav[nb][r]-dl[r]));
        }
    }
    lds_fence();
    __builtin_amdgcn_s_setprio(1);
    #pragma unroll
    for(int nb=0;nb<4;nb++){
      #pragma unroll
      for(int s=0;s<2;s++){
        bf16x8 pa = *(const bf16x8*)&psb[w][ln][32*s+lg*8];
        bf16x8 bk = *(const bf16x8*)&kts[nb*16+ln][32*s+lg*8];
        acc[nb]=MFMA_B16(pa,bk,acc[nb]);
      }
    }
    __builtin_amdgcn_s_setprio(0);
    lds_fence();
  }
  short* dst = half? dqp1 : dqt;
  #pragma unroll
  for(int nb=0;nb<4;nb++){
    short4 s4;
    s4.x=f2bf(acc[nb][0]); s4.y=f2bf(acc[nb][1]);
    s4.z=f2bf(acc[nb][2]); s4.w=f2bf(acc[nb][3]);
    *(short4*)&dst[((size_t)bh*64 + nb*16+ln)*2048 + i0+w*16+lg*4]=s4;
  }
}

// dqt += dqp1 (bf16, deterministic)
__global__ __launch_bounds__(256) void k_dqred(short* __restrict__ dqt,
    const short* __restrict__ dqp1){
  size_t i = ((size_t)blockIdx.x*256 + threadIdx.x)*8;
  int4 a = *(const int4*)&dqt[i];
  int4 b = *(const int4*)&dqp1[i];
  short* pa=(short*)&a; const short* pb=(const short*)&b;
  short out[8];
  #pragma unroll
  for(int k=0;k<8;k++) out[k]=f2bf(bf2f(pa[k])+bf2f(pb[k]));
  *(int4*)&dqt[i] = *(int4*)out;
}

// ---------------- 12. flash backward dk,dv (2-way i-split) ----------------
__global__ __launch_bounds__(256) void k_fa_dkv(const short* __restrict__ kh,
    const short* __restrict__ vh, const short* __restrict__ qh,
    const short* __restrict__ qt, const short* __restrict__ doh,
    const short* __restrict__ dot,
    const float* __restrict__ lse, const float* __restrict__ delta,
    short* __restrict__ dkt, short* __restrict__ dvt,
    short* __restrict__ dkp1, short* __restrict__ dvp1){
  int bh = blockIdx.x, jt = blockIdx.y, half = blockIdx.z;
  int j0 = jt<<6;
  const short* khb = kh + (size_t)bh*N_*DH_;
  const short* vhb = vh + (size_t)bh*N_*DH_;
  const short* qhb = qh + (size_t)bh*N_*DH_;
  const short* qtb = qt + (size_t)bh*DH_*N_;
  const short* dohb= doh+ (size_t)bh*N_*DH_;
  const short* dotb= dot+ (size_t)bh*DH_*N_;
  __shared__ __attribute__((aligned(16))) short qs[64][LBK], dos[64][LBK], qts[64][LBK], dots[64][LBK];
  __shared__ __attribute__((aligned(16))) short psv[4][16][LBK], psk[4][16][LBK];
  __shared__ float Ls[64], dls[64];
  int tid=threadIdx.x, w=tid>>6, lane=tid&63, lg=lane>>4, ln=lane&15;
  bf16x8 akf[2], avf[2];
  #pragma unroll
  for(int s=0;s<2;s++){
    akf[s]=*(const bf16x8*)&khb[(size_t)(j0+w*16+ln)*DH_+32*s+lg*8];
    avf[s]=*(const bf16x8*)&vhb[(size_t)(j0+w*16+ln)*DH_+32*s+lg*8];
  }
  f32x4 accv[4], acck[4];
  #pragma unroll
  for(int nb=0;nb<4;nb++){
    accv[nb]=(f32x4){0.f,0.f,0.f,0.f};
    acck[nb]=(f32x4){0.f,0.f,0.f,0.f};
  }
  int it0 = jt + half;
  int4 qa0,qa1,da0,da1,qta0,qta1,dta0,dta1;
  float Lnx=0.f, dlnx=0.f;
  {
    int ip = (it0<32)? (it0<<6) : 0;
    tload(qhb+(size_t)ip*DH_, DH_, tid, qa0,qa1);
    tload(dohb+(size_t)ip*DH_, DH_, tid, da0,da1);
    tload(qtb+ip, N_, tid, qta0,qta1);
    tload(dotb+ip, N_, tid, dta0,dta1);
    if(tid<64){
      int ii=ip+tid;
      Lnx=lse[(size_t)bh*N_+ii];
      dlnx=(ii<NM_)?delta[(size_t)bh*N_+ii]:0.f;
    }
  }
  for(int it=it0; it<32; it+=2){
    int i0=it<<6;
    bool msk_needed = (it==jt) || (it==31);
    __syncthreads();
    twrite(qs, tid, qa0,qa1);
    twrite(dos, tid, da0,da1);
    twrite(qts, tid, qta0,qta1);
    twrite(dots, tid, dta0,dta1);
    if(tid<64){ Ls[tid]=Lnx; dls[tid]=dlnx; }
    if(it+2<32){
      int i1=(it+2)<<6;
      tload(qhb+(size_t)i1*DH_, DH_, tid, qa0,qa1);
      tload(dohb+(size_t)i1*DH_, DH_, tid, da0,da1);
      tload(qtb+i1, N_, tid, qta0,qta1);
      tload(dotb+i1, N_, tid, dta0,dta1);
      if(tid<64){
        int ii=i1+tid;
        Lnx=lse[(size_t)bh*N_+ii];
        dlnx=(ii<NM_)?delta[(size_t)bh*N_+ii]:0.f;
      }
    }
    __syncthreads();
    f32x4 sv[4], dav[4];
    __builtin_amdgcn_s_setprio(1);
    #pragma unroll
    for(int nb=0;nb<4;nb++){
      f32x4 z={0.f,0.f,0.f,0.f}, zd={0.f,0.f,0.f,0.f};
      #pragma unroll
      for(int s=0;s<2;s++){
        bf16x8 bq=*(const bf16x8*)&qs[nb*16+ln][32*s+lg*8];
        bf16x8 bd=*(const bf16x8*)&dos[nb*16+ln][32*s+lg*8];
        z = MFMA_B16(akf[s], bq, z);
        zd= MFMA_B16(avf[s], bd, zd);
      }
      sv[nb]=z; dav[nb]=zd;
    }
    __builtin_amdgcn_s_setprio(0);
    if(msk_needed){
      #pragma unroll
      for(int nb=0;nb<4;nb++){
        float Lc=Ls[nb*16+ln], dlc=dls[nb*16+ln];
        int ii=i0+nb*16+ln;
        #pragma unroll
        for(int r=0;r<4;r++){
          int jj=j0+w*16+lg*4+r;
          float pv=__expf(sv[nb][r]*SCALE_F - Lc);
          bool msk=(jj>ii)||(ii>=NM_)||(jj>=NM_);
          if(msk) pv=0.f;
          float ds = msk?0.f: SCALE_F*pv*(dav[nb][r]-dlc);
          psv[w][lg*4+r][ln+16*nb]=f2bf(pv);
          psk[w][lg*4+r][ln+16*nb]=f2bf(ds);
        }
      }
    } else {
      #pragma unroll
      for(int nb=0;nb<4;nb++){
        float Lc=Ls[nb*16+ln], dlc=dls[nb*16+ln];
        #pragma unroll
        for(int r=0;r<4;r++){
          float pv=__expf(sv[nb][r]*SCALE_F - Lc);
          psv[w][lg*4+r][ln+16*nb]=f2bf(pv);
          psk[w][lg*4+r][ln+16*nb]=f2bf(SCALE_F*pv*(dav[nb][r]-dlc));
        }
      }
    }
    lds_fence();
    __builtin_amdgcn_s_setprio(1);
    #pragma unroll
    for(int nb=0;nb<4;nb++){
      #pragma unroll
      for(int s=0;s<2;s++){
        bf16x8 pa = *(const bf16x8*)&psv[w][ln][32*s+lg*8];
        bf16x8 bd = *(const bf16x8*)&dots[nb*16+ln][32*s+lg*8];
        accv[nb]=MFMA_B16(pa,bd,accv[nb]);
        bf16x8 pk = *(const bf16x8*)&psk[w][ln][32*s+lg*8];
        bf16x8 bq = *(const bf16x8*)&qts[nb*16+ln][32*s+lg*8];
        acck[nb]=MFMA_B16(pk,bq,acck[nb]);
      }
    }
    __builtin_amdgcn_s_setprio(0);
    lds_fence();
  }
  short* dvd = half? dvp1 : dvt;
  short* dkd = half? dkp1 : dkt;
  #pragma unroll
  for(int nb=0;nb<4;nb++){
    int e=nb*16+ln, n0=j0+w*16+lg*4;
    short4 s4;
    s4.x=f2bf(accv[nb][0]); s4.y=f2bf(accv[nb][1]);
    s4.z=f2bf(accv[nb][2]); s4.w=f2bf(accv[nb][3]);
    *(short4*)&dvd[((size_t)bh*64+e)*2048 + n0]=s4;
    s4.x=f2bf(acck[nb][0]); s4.y=f2bf(acck[nb][1]);
    s4.z=f2bf(acck[nb][2]); s4.w=f2bf(acck[nb][3]);
    *(short4*)&dkd[((size_t)bh*64+e)*2048 + n0]=s4;
  }
}

// dkt += dkp1; dvt += dvp1
__global__ __launch_bounds__(256) void k_dkvred(short* __restrict__ dkt,
    short* __restrict__ dvt, const short* __restrict__ dkp1,
    const short* __restrict__ dvp1){
  int bid = blockIdx.x;
  short* dst; const short* src;
  if(bid<1024){ dst=dkt; src=dkp1; } else { dst=dvt; src=dvp1; bid-=1024; }
  size_t i = ((size_t)bid*256 + threadIdx.x)*8;
  int4 a = *(const int4*)&dst[i];
  int4 b = *(const int4*)&src[i];
  short* pa=(short*)&a; const short* pb=(const short*)&b;
  short out[8];
  #pragma unroll
  for(int k=0;k<8;k++) out[k]=f2bf(bf2f(pa[k])+bf2f(pb[k]));
  *(int4*)&dst[i] = *(int4*)out;
}

// ---------------- 13. weight grads (MFMA, split-K=8) ----------------
__global__ __launch_bounds__(256) void k_gemm_wgq(const short* __restrict__ tt,
    const short* __restrict__ g, float* __restrict__ par){
  __shared__ __attribute__((aligned(16))) short as[64][LBK], bs[64][LBK];
  int dt=blockIdx.x, h=blockIdx.y, sp=blockIdx.z;
  int b=sp>>2, n0b=(sp&3)*512;
  f32x4 acc[4];
  #pragma unroll
  for(int nb=0;nb<4;nb++) acc[nb]=(f32x4){0.f,0.f,0.f,0.f};
  gemm64(tt + (size_t)(dt*64)*4096 + sp*512, 4096,
         g  + ((size_t)(b*8+h)*64)*2048 + n0b, 2048, 8, as, bs, acc);
  int tid=threadIdx.x, w=tid>>6, lane=tid&63, lg=lane>>4, ln=lane&15;
  int row=w*16+lg*4;
  #pragma unroll
  for(int nb=0;nb<4;nb++)
    #pragma unroll
    for(int r=0;r<4;r++)
      par[(size_t)sp*262144 + (size_t)h*32768 + (size_t)(dt*64+row+r)*64 + nb*16+ln]=acc[nb][r];
}

__global__ __launch_bounds__(256) void k_gemm_wgo(const short* __restrict__ outt,
    const short* __restrict__ ert, float* __restrict__ par){
  __shared__ __attribute__((aligned(16))) short as[64][LBK], bs[64][LBK];
  int ct=blockIdx.x, h=blockIdx.y, sp=blockIdx.z;
  f32x4 acc[4];
  #pragma unroll
  for(int nb=0;nb<4;nb++) acc[nb]=(f32x4){0.f,0.f,0.f,0.f};
  gemm64(outt + (size_t)(h*64)*4096 + sp*512, 4096,
         ert  + (size_t)(ct*64)*4096 + sp*512, 4096, 8, as, bs, acc);
  int tid=threadIdx.x, w=tid>>6, lane=tid&63, lg=lane>>4, ln=lane&15;
  int row=w*16+lg*4;
  #pragma unroll
  for(int nb=0;nb<4;nb++)
    #pragma unroll
    for(int r=0;r<4;r++)
      par[(size_t)sp*262144 + (size_t)h*32768 + (size_t)(row+r)*512 + ct*64+nb*16+ln]=acc[nb][r];
}

__global__ __launch_bounds__(256) void k_wred_direct(const float* __restrict__ par,
    float* __restrict__ dst){
  int idx = blockIdx.x*256 + threadIdx.x;
  float s=0.f;
  #pragma unroll
  for(int sp=0;sp<8;sp++) s += par[(size_t)sp*262144 + idx];
  dst[idx]=s;
}
__global__ __launch_bounds__(256) void k_wred_xv(const float* __restrict__ par,
    float* __restrict__ X0){
  int idx = blockIdx.x*256 + threadIdx.x;
  float s=0.f;
  #pragma unroll
  for(int sp=0;sp<8;sp++) s += par[(size_t)sp*262144 + idx];
  int h=idx>>15, rem=idx&32767, d=rem>>6, e=rem&63;
  X0[(size_t)h*32768 + (size_t)e*512 + d]=s;
}
__global__ __launch_bounds__(256) void k_wred_xo(const float* __restrict__ par,
    float* __restrict__ X0){
  int idx = blockIdx.x*256 + threadIdx.x;
  float s=0.f;
  #pragma unroll
  for(int sp=0;sp<8;sp++) s += par[(size_t)sp*262144 + idx];
  X0[262144 + idx]=s;
}

// ---------------- 14. Newton-Schulz fused (16 blocks x 1024 threads) ----------------
// 16 waves/block: wave w owns A-tile (w>>2, w&3) and X-update strip
// rows (w&3)*16..+16, cols (w>>2)*128..+128.
__global__ __launch_bounds__(1024) void k_ns_fused(const float* __restrict__ X0,
    float* __restrict__ dwv, float* __restrict__ dwo){
  __shared__ __attribute__((aligned(16))) short Xl[64][520];
  __shared__ __attribute__((aligned(16))) short Xt[512][72];
  __shared__ __attribute__((aligned(16))) short Al[64][72];
  __shared__ __attribute__((aligned(16))) short Bl[64][72];
  __shared__ float red[16];
  int m = blockIdx.x, tid=threadIdx.x, w=tid>>6, lane=tid&63, lg=lane>>4, ln=lane&15;
  int wr=w>>2, wc=w&3;
  const float* Xg = X0 + (size_t)m*32768;
  float ss=0.f;
  for(int kk=0;kk<32;kk++){ float v=Xg[kk*1024+tid]; ss+=v*v; }
  ss=wred64(ss);
  if(lane==0) red[w]=ss;
  __syncthreads();
  float tot=0.f;
  #pragma unroll
  for(int i=0;i<16;i++) tot+=red[i];
  float sc = 1.f/fmaxf(sqrtf(tot), 1e-7f);
  for(int kk=0;kk<32;kk++){
    int idx=kk*1024+tid; int rr=idx>>9, cc=idx&511;
    short v=f2bf(Xg[idx]*sc);
    Xl[rr][cc]=v; Xt[cc][rr]=v;
  }
  __syncthreads();
  for(int iter=0; iter<5; ++iter){
    // A = X X^T, tile (wr,wc), K=512 -> 16 MFMA
    f32x4 accA=(f32x4){0.f,0.f,0.f,0.f};
    #pragma unroll
    for(int kt=0;kt<16;kt++){
      bf16x8 a = *(const bf16x8*)&Xl[wr*16+ln][kt*32+lg*8];
      bf16x8 b = *(const bf16x8*)&Xl[wc*16+ln][kt*32+lg*8];
      accA=MFMA_B16(a,b,accA);
    }
    #pragma unroll
    for(int r=0;r<4;r++) Al[wr*16+lg*4+r][wc*16+ln]=f2bf(accA[r]);
    __syncthreads();
    // A2 = A*A (A symmetric), K=64 -> 2 MFMA
    f32x4 acc2=(f32x4){0.f,0.f,0.f,0.f};
    #pragma unroll
    for(int s=0;s<2;s++){
      bf16x8 a = *(const bf16x8*)&Al[wr*16+ln][32*s+lg*8];
      bf16x8 b = *(const bf16x8*)&Al[wc*16+ln][32*s+lg*8];
      acc2=MFMA_B16(a,b,acc2);
    }
    #pragma unroll
    for(int r=0;r<4;r++)
      Bl[wr*16+lg*4+r][wc*16+ln]=f2bf(-4.775f*accA[r] + 2.0315f*acc2[r]);
    __syncthreads();
    // Xnew = a*X + B*X : wave strip rows rg..+16, cols cg..+128
    int rg=(w&3)<<4, cg=(w>>2)<<7;
    f32x4 xn[8];
    #pragma unroll
    for(int nb=0;nb<8;nb++){
      xn[nb]=(f32x4){0.f,0.f,0.f,0.f};
      #pragma unroll
      for(int s=0;s<2;s++){
        bf16x8 a = *(const bf16x8*)&Bl[rg+ln][32*s+lg*8];
        bf16x8 b = *(const bf16x8*)&Xt[cg+nb*16+ln][32*s+lg*8];
        xn[nb]=MFMA_B16(a,b,xn[nb]);
      }
      #pragma unroll
      for(int r=0;r<4;r++)
        xn[nb][r] += 3.4445f*bf2f(Xl[rg+lg*4+r][cg+nb*16+ln]);
    }
    __syncthreads();
    if(iter<4){
      #pragma unroll
      for(int nb=0;nb<8;nb++){
        int d=cg+nb*16+ln, row0=rg+lg*4;
        short4 s4;
        s4.x=f2bf(xn[nb][0]); s4.y=f2bf(xn[nb][1]);
        s4.z=f2bf(xn[nb][2]); s4.w=f2bf(xn[nb][3]);
        Xl[row0  ][d]=s4.x; Xl[row0+1][d]=s4.y;
        Xl[row0+2][d]=s4.z; Xl[row0+3][d]=s4.w;
        *(short4*)&Xt[d][row0]=s4;
      }
      __syncthreads();
    } else {
      #pragma unroll
      for(int nb=0;nb<8;nb++){
        int d=cg+nb*16+ln, row0=rg+lg*4;
        #pragma unroll
        for(int r=0;r<4;r++){
          float v=xn[nb][r];
          int e=row0+r;
          if(m<8) dwv[(size_t)m*32768 + (size_t)d*64 + e]=v;
          else    dwo[(size_t)(m-8)*32768 + (size_t)e*512 + d]=v;
        }
      }
    }
  }
}

// ---------------- launch ----------------
extern "C" void kernel_launch(void* const* d_in, const int* in_sizes, int n_in,
                              void* d_out, int out_size, void* d_ws, size_t ws_size,
                              hipStream_t stream) {
  const float* tokens=(const float*)d_in[0];
  const float* rmsw =(const float*)d_in[1];
  const float* wq   =(const float*)d_in[2];
  const float* wk   =(const float*)d_in[3];
  const float* wv   =(const float*)d_in[4];
  const float* wo   =(const float*)d_in[5];
  const float* lrw  =(const float*)d_in[6];
  const float* tvw  =(const float*)d_in[7];
  float* out = (float*)d_out;
  float* ws  = (float*)d_ws;

  short* tb   = (short*)(ws);            // [4160][512] bf16 (pad rows zero)
  short* tt   = (short*)(ws + 1064960);  // [512][4096]
  short* qh   = (short*)(ws + 2113536);  // [16bh][2048][64]
  short* kh   = (short*)(ws + 3162112);
  short* vh   = (short*)(ws + 4210688);
  short* qt   = (short*)(ws + 5259264);  // [16bh][64][2048]
  short* kt   = (short*)(ws + 6307840);
  short* vt   = (short*)(ws + 7356416);
  float* er_  = ws + 8404992;            // f32 [4096][512]
  float* op0  = ws + 8404992;            // fwd partial 0 (dead before er_)
  short* dqp1 = (short*)(ws + 8404992);  // bwd partials (after er_ dead)
  short* dkp1 = (short*)(ws + 8404992);
  short* dvp1 = (short*)(ws + 9453568);
  short* obb  = (short*)(ws + 10502144); // bf16 [4096][512]
  short* outt = (short*)(ws + 11550720); // bf16 [512][4096]
  short* erb  = (short*)(ws + 12599296);
  short* ert  = (short*)(ws + 13647872);
  short* doh  = (short*)(ws + 14696448); // [16bh][2048][64]
  short* dot  = (short*)(ws + 15745024); // [16bh][64][2048]
  float* par_ = ws + 14696448;           // aliases doh+dot (dead before wgrad)
  float* op1  = ws + 14696448;           // fwd partial 1 (dead before doh/dot)
  short* dqt  = (short*)(ws + 16793600); // [16bh][64][2048]
  float* mlb  = ws + 16793600;           // fwd m/l partials (dead before dqt)
  short* dkt  = (short*)(ws + 17842176);
  short* dvt  = (short*)(ws + 18890752);
  short* wqt  = (short*)(ws + 19939328); // [8h][64][512]
  short* wkt  = (short*)(ws + 20070400);
  short* wvt  = (short*)(ws + 20201472);
  short* wob  = (short*)(ws + 20332544); // [512 he][512 d]
  short* wot  = (short*)(ws + 20463616); // [512 d][512 he]
  short* tvwb = (short*)(ws + 20594688); // [512 o][512 d]
  float* lse_ = ws + 20725760;
  float* dlt_ = ws + 20758528;
  float* X0_  = ws + 20791296;

  float* OUT_PRED = out;
  float* OUT_DWQ  = out + 2097152;
  float* OUT_DWK  = out + 2359296;
  float* OUT_DWV  = out + 2621440;
  float* OUT_DWO  = out + 2883584;

  k_rmsnorm<<<4160,256,0,stream>>>(tokens, rmsw, tb);
  k_wprep<<<272,256,0,stream>>>(wq,wk,wv,wo,tvw, wqt,wkt,wvt,wob,wot,tvwb);
  k_gemm_qkv<<<dim3(64,24),256,0,stream>>>(tb, wqt,wkt,wvt, qh,kh,vh, qt,kt,vt);
  k_fa_fwd<<<dim3(16,32,2),256,0,stream>>>(qh, kh, vt, op0, op1, mlb);
  k_fa_merge<<<8192,256,0,stream>>>(op0, op1, mlb, obb, lse_);
  k_gemm_pred<<<dim3(64,8),256,0,stream>>>(obb, wot, OUT_PRED);

  if(out_size < 3145728) return;   // forward-only variant

  k_trans_b<<<dim3(64,8),256,0,stream>>>(tb, tt);
  k_gemm_tv<<<dim3(64,8),256,0,stream>>>(tb, tvwb, er_);
  k_lnerr<<<4094,256,0,stream>>>(er_, tb, OUT_PRED, lrw);
  k_trans_f<<<dim3(64,8),256,0,stream>>>(er_, erb, ert);
  k_gemm_dout<<<dim3(64,8),256,0,stream>>>(erb, wob, doh, dot);
  k_delta<<<8188,256,0,stream>>>(doh, obb, dlt_);
  k_fa_dq<<<dim3(16,32,2),256,0,stream>>>(qh, kh, vh, kt, doh, lse_, dlt_, dqt, dqp1);
  k_dqred<<<1024,256,0,stream>>>(dqt, dqp1);
  k_fa_dkv<<<dim3(16,32,2),256,0,stream>>>(kh, vh, qh, qt, doh, dot, lse_, dlt_,
                                           dkt, dvt, dkp1, dvp1);
  k_dkvred<<<2048,256,0,stream>>>(dkt, dvt, dkp1, dvp1);
  k_trans_b<<<dim3(64,8),256,0,stream>>>(obb, outt);

  k_gemm_wgq<<<dim3(8,8,8),256,0,stream>>>(tt, dqt, par_);
  k_wred_direct<<<1024,256,0,stream>>>(par_, OUT_DWQ);
  k_gemm_wgq<<<dim3(8,8,8),256,0,stream>>>(tt, dkt, par_);
  k_wred_direct<<<1024,256,0,stream>>>(par_, OUT_DWK);
  k_gemm_wgq<<<dim3(8,8,8),256,0,stream>>>(tt, dvt, par_);
  k_wred_xv<<<1024,256,0,stream>>>(par_, X0_);
  k_gemm_wgo<<<dim3(8,8,8),256,0,stream>>>(outt, ert, par_);
  k_wred_xo<<<1024,256,0,stream>>>(par_, X0_);

  k_ns_fused<<<16,1024,0,stream>>>(X0_, OUT_DWV, OUT_DWO);
}